// Round 8
// baseline (556.590 us; speedup 1.0000x reference)
//
#include <hip/hip_runtime.h>
#include <hip/hip_bf16.h>

#define NN 100000
#define FF 500
#define HH 64
#define CC 40
#define EE 1000000
#define NB 782            // buckets per scale: ceil(100000/128)
#define NBK 2346          // 3*NB
#define NBLK_P 128        // partition blocks
#define M2 (NBK * NBLK_P) // 300288 counters

// ---------------------------------------------------------------------------
// GEMM: C[N][64] = (opt relu)(A[N][K]) @ B[K][64] + bias[64]
// OBF16: write output as bf16 (consumed by the gather).
// ---------------------------------------------------------------------------
template <int K, bool RELU, bool OBF16>
__global__ __launch_bounds__(256) void gemm_n64(
    const float* __restrict__ A,
    const float* __restrict__ B,
    const float* __restrict__ bias,
    void* __restrict__ Cv,
    int nrows)
{
    __shared__ float As[32][68];
    __shared__ float Bs[32][64];

    const int tid = threadIdx.x;
    const int tx = tid & 15;
    const int ty = tid >> 4;
    const int row0 = blockIdx.x * 64;

    float acc[4][4] = {{0.f, 0.f, 0.f, 0.f}, {0.f, 0.f, 0.f, 0.f},
                       {0.f, 0.f, 0.f, 0.f}, {0.f, 0.f, 0.f, 0.f}};

    const int r = tid >> 2;
    const int koff = (tid & 3) * 8;
    const bool rowok = (row0 + r) < nrows;

    for (int k0 = 0; k0 < K; k0 += 32) {
        float av[8];
        const float* ap = A + (size_t)(row0 + r) * K + (k0 + koff);
        if (rowok && ((K % 32 == 0) || (k0 + 32 <= K))) {
            float4 v0 = *(const float4*)(ap);
            float4 v1 = *(const float4*)(ap + 4);
            av[0] = v0.x; av[1] = v0.y; av[2] = v0.z; av[3] = v0.w;
            av[4] = v1.x; av[5] = v1.y; av[6] = v1.z; av[7] = v1.w;
        } else {
            #pragma unroll
            for (int j = 0; j < 8; ++j) {
                int kk = k0 + koff + j;
                av[j] = (rowok && kk < K) ? ap[j] : 0.f;
            }
        }
        if (RELU) {
            #pragma unroll
            for (int j = 0; j < 8; ++j) av[j] = fmaxf(av[j], 0.f);
        }
        #pragma unroll
        for (int j = 0; j < 8; ++j) As[koff + j][r] = av[j];

        {
            int flat = tid * 8;
            int kk = flat >> 6;
            int c = flat & 63;
            float4 b0, b1v;
            if (k0 + kk < K) {
                b0 = *(const float4*)(B + (size_t)(k0 + kk) * 64 + c);
                b1v = *(const float4*)(B + (size_t)(k0 + kk) * 64 + c + 4);
            } else {
                b0 = make_float4(0.f, 0.f, 0.f, 0.f);
                b1v = b0;
            }
            *(float4*)&Bs[kk][c] = b0;
            *(float4*)&Bs[kk][c + 4] = b1v;
        }
        __syncthreads();

        #pragma unroll
        for (int k = 0; k < 32; ++k) {
            float4 a = *(const float4*)&As[k][ty * 4];
            float4 b = *(const float4*)&Bs[k][tx * 4];
            acc[0][0] = fmaf(a.x, b.x, acc[0][0]);
            acc[0][1] = fmaf(a.x, b.y, acc[0][1]);
            acc[0][2] = fmaf(a.x, b.z, acc[0][2]);
            acc[0][3] = fmaf(a.x, b.w, acc[0][3]);
            acc[1][0] = fmaf(a.y, b.x, acc[1][0]);
            acc[1][1] = fmaf(a.y, b.y, acc[1][1]);
            acc[1][2] = fmaf(a.y, b.z, acc[1][2]);
            acc[1][3] = fmaf(a.y, b.w, acc[1][3]);
            acc[2][0] = fmaf(a.z, b.x, acc[2][0]);
            acc[2][1] = fmaf(a.z, b.y, acc[2][1]);
            acc[2][2] = fmaf(a.z, b.z, acc[2][2]);
            acc[2][3] = fmaf(a.z, b.w, acc[2][3]);
            acc[3][0] = fmaf(a.w, b.x, acc[3][0]);
            acc[3][1] = fmaf(a.w, b.y, acc[3][1]);
            acc[3][2] = fmaf(a.w, b.z, acc[3][2]);
            acc[3][3] = fmaf(a.w, b.w, acc[3][3]);
        }
        __syncthreads();
    }

    float4 bv = *(const float4*)(bias + tx * 4);
    #pragma unroll
    for (int i = 0; i < 4; ++i) {
        int rr = row0 + ty * 4 + i;
        if (rr < nrows) {
            float o0 = acc[i][0] + bv.x;
            float o1 = acc[i][1] + bv.y;
            float o2 = acc[i][2] + bv.z;
            float o3 = acc[i][3] + bv.w;
            if (OBF16) {
                __hip_bfloat16* Cb = (__hip_bfloat16*)Cv;
                __hip_bfloat162 lo = __float22bfloat162_rn(make_float2(o0, o1));
                __hip_bfloat162 hi = __float22bfloat162_rn(make_float2(o2, o3));
                *(__hip_bfloat162*)(Cb + (size_t)rr * 64 + tx * 4) = lo;
                *(__hip_bfloat162*)(Cb + (size_t)rr * 64 + tx * 4 + 2) = hi;
            } else {
                float* C = (float*)Cv;
                *(float4*)(C + (size_t)rr * 64 + tx * 4) =
                    make_float4(o0, o1, o2, o3);
            }
        }
    }
}

// ---------------------------------------------------------------------------
// Radix partition pass 1: per-block private bucket histogram (LDS only).
// ---------------------------------------------------------------------------
__global__ __launch_bounds__(1024) void part_count(
    const int* __restrict__ ei1, const int* __restrict__ ei2,
    const int* __restrict__ ei3, int* __restrict__ cnt)
{
    __shared__ int lc[NBK];
    const int t = threadIdx.x;
    for (int j = t; j < NBK; j += 1024) lc[j] = 0;
    __syncthreads();

    const int chunk = (3 * EE + NBLK_P - 1) / NBLK_P;
    const int b0 = blockIdx.x * chunk;
    int b1 = b0 + chunk;
    if (b1 > 3 * EE) b1 = 3 * EE;

    for (int i = b0 + t; i < b1; i += 1024) {
        int s = i / EE;
        int e = i - s * EE;
        const int* ei = (s == 0) ? ei1 : (s == 1) ? ei2 : ei3;
        atomicAdd(&lc[s * NB + (ei[EE + e] >> 7)], 1);
    }
    __syncthreads();
    for (int j = t; j < NBK; j += 1024)
        cnt[j * NBLK_P + blockIdx.x] = lc[j];
}

// ---------------------------------------------------------------------------
// Exclusive scan over M2 counters.
// ---------------------------------------------------------------------------
__global__ __launch_bounds__(1024) void scan_a(
    const int* __restrict__ cnt, int* __restrict__ off,
    int* __restrict__ partials, int M)
{
    __shared__ int sh[1024];
    int t = threadIdx.x;
    int i = blockIdx.x * 1024 + t;
    int v = (i < M) ? cnt[i] : 0;
    sh[t] = v;
    __syncthreads();
    #pragma unroll
    for (int o = 1; o < 1024; o <<= 1) {
        int add = (t >= o) ? sh[t - o] : 0;
        __syncthreads();
        sh[t] += add;
        __syncthreads();
    }
    if (i < M) off[i] = sh[t] - v;
    if (t == 1023) partials[blockIdx.x] = sh[1023];
}

__global__ __launch_bounds__(512) void scan_b(int* __restrict__ partials, int P)
{
    __shared__ int sh[512];
    int t = threadIdx.x;
    int v = (t < P) ? partials[t] : 0;
    sh[t] = v;
    __syncthreads();
    #pragma unroll
    for (int o = 1; o < 512; o <<= 1) {
        int add = (t >= o) ? sh[t - o] : 0;
        __syncthreads();
        sh[t] += add;
        __syncthreads();
    }
    if (t < P) partials[t] = sh[t] - v;
}

__global__ __launch_bounds__(256) void scan_c(
    int* __restrict__ off, int* __restrict__ off_b,
    const int* __restrict__ partials, int M)
{
    int i = blockIdx.x * 256 + threadIdx.x;
    if (i < M) {
        int v = off[i] + partials[i >> 10];
        off[i] = v;
        if ((i & (NBLK_P - 1)) == 0) off_b[i / NBLK_P] = v;
    }
    if (i == 0) off_b[NBK] = 3 * EE;
}

// ---------------------------------------------------------------------------
// Radix partition pass 2: place records via LDS cursors.
// ---------------------------------------------------------------------------
__global__ __launch_bounds__(1024) void part_scatter(
    const int* __restrict__ ei1, const float* __restrict__ ea1,
    const int* __restrict__ ei2, const float* __restrict__ ea2,
    const int* __restrict__ ei3, const float* __restrict__ ea3,
    const int* __restrict__ offp, int2* __restrict__ brec)
{
    __shared__ int lcur[NBK];
    const int t = threadIdx.x;
    for (int j = t; j < NBK; j += 1024)
        lcur[j] = offp[j * NBLK_P + blockIdx.x];
    __syncthreads();

    const int chunk = (3 * EE + NBLK_P - 1) / NBLK_P;
    const int b0 = blockIdx.x * chunk;
    int b1 = b0 + chunk;
    if (b1 > 3 * EE) b1 = 3 * EE;

    for (int i = b0 + t; i < b1; i += 1024) {
        int s = i / EE;
        int e = i - s * EE;
        const int* ei = (s == 0) ? ei1 : (s == 1) ? ei2 : ei3;
        const float* ea = (s == 0) ? ea1 : (s == 1) ? ea2 : ea3;
        int src = ei[e];
        int dst = ei[EE + e];
        float w = ea[e];
        int pos = atomicAdd(&lcur[s * NB + (dst >> 7)], 1);
        brec[pos] = make_int2(src | ((dst & 127) << 17), __float_as_int(w));
    }
}

// ---------------------------------------------------------------------------
// Bucket refine: one block per bucket; LDS counting sort of 128 local dsts.
// ---------------------------------------------------------------------------
__global__ __launch_bounds__(256) void bucket_refine(
    const int2* __restrict__ brec,
    const int* __restrict__ off_b,      // [NBK+1]
    int* __restrict__ node_off,         // [3N+1]
    int2* __restrict__ pairs)
{
    __shared__ int hist[128];
    __shared__ int curls[128];
    const int t = threadIdx.x;
    const int bk = blockIdx.x;
    const int s = bk / NB;
    const int b = bk - s * NB;
    const int n0 = b << 7;
    const int beg = off_b[bk];
    const int end = off_b[bk + 1];

    if (bk == 0 && t == 0) node_off[3 * NN] = 3 * EE;
    if (t < 128) hist[t] = 0;
    __syncthreads();

    for (int p = beg + t; p < end; p += 256)
        atomicAdd(&hist[(brec[p].x >> 17) & 127], 1);
    __syncthreads();

    int cnt = (t < 128) ? hist[t] : 0;
    #pragma unroll
    for (int o = 1; o < 128; o <<= 1) {
        int add = (t < 128 && t >= o) ? hist[t - o] : 0;
        __syncthreads();
        if (t < 128) hist[t] += add;
        __syncthreads();
    }
    if (t < 128) {
        int excl = beg + hist[t] - cnt;
        curls[t] = excl;
        if (n0 + t < NN) node_off[s * NN + n0 + t] = excl;
    }
    __syncthreads();

    for (int p = beg + t; p < end; p += 256) {
        int2 r = brec[p];
        int pos = atomicAdd(&curls[(r.x >> 17) & 127], 1);
        pairs[pos] = make_int2(r.x & 0x1FFFF, r.y);
    }
}

// ---------------------------------------------------------------------------
// Segmented gather, 2-cols-per-lane: one wave per (node, scale).
// Lane l: col pair c=(l&31) -> cols {2c, 2c+1}; half = l>>5 processes edges
// beg+half, beg+half+2, ... (two edges of the segment in flight per wave).
// h row = 64 bf16 = 32 dwords; lane loads 1 packed dword (2 bf16).
// Epilogue: acc += shfl_xor(acc, 32); half 0 stores float2.
// ---------------------------------------------------------------------------
__global__ __launch_bounds__(256) void ufg_gather(
    const __hip_bfloat16* __restrict__ h,   // [N][64] bf16
    const int* __restrict__ off,            // [3N+1]
    const int2* __restrict__ pairs,         // [3E]
    const float* __restrict__ f1, const float* __restrict__ f2,
    const float* __restrict__ f3,
    float* __restrict__ agg)                // [N][192]
{
    const int lane = threadIdx.x & 63;
    const int c = lane & 31;                // column pair index
    const int half = lane >> 5;             // 0 or 1
    const int wid = blockIdx.x * 4 + (threadIdx.x >> 6);
    if (wid >= 3 * NN) return;
    const int s = wid / NN;
    const int n = wid - s * NN;

    const float* fp = (s == 0) ? f1 : (s == 1) ? f2 : f3;
    const float2 fv = *(const float2*)(fp + 2 * c);
    const unsigned* hw = (const unsigned*)h + c;   // + src*32 per row

    const int beg = off[wid];
    const int end = off[wid + 1];

    float acc0 = 0.f, acc1 = 0.f;
    int p = beg + half;

    // 4-deep unroll per half = 8 edges in flight per wave
    for (; p + 6 < end; p += 8) {
        int2 q0 = pairs[p + 0];
        int2 q1 = pairs[p + 2];
        int2 q2 = pairs[p + 4];
        int2 q3 = pairs[p + 6];
        unsigned u0 = hw[(size_t)q0.x * 32];
        unsigned u1 = hw[(size_t)q1.x * 32];
        unsigned u2 = hw[(size_t)q2.x * 32];
        unsigned u3 = hw[(size_t)q3.x * 32];
        float w0 = __int_as_float(q0.y);
        float w1 = __int_as_float(q1.y);
        float w2 = __int_as_float(q2.y);
        float w3 = __int_as_float(q3.y);
        acc0 = fmaf(w0, __uint_as_float(u0 << 16), acc0);
        acc1 = fmaf(w0, __uint_as_float(u0 & 0xFFFF0000u), acc1);
        acc0 = fmaf(w1, __uint_as_float(u1 << 16), acc0);
        acc1 = fmaf(w1, __uint_as_float(u1 & 0xFFFF0000u), acc1);
        acc0 = fmaf(w2, __uint_as_float(u2 << 16), acc0);
        acc1 = fmaf(w2, __uint_as_float(u2 & 0xFFFF0000u), acc1);
        acc0 = fmaf(w3, __uint_as_float(u3 << 16), acc0);
        acc1 = fmaf(w3, __uint_as_float(u3 & 0xFFFF0000u), acc1);
    }
    for (; p < end; p += 2) {
        int2 q = pairs[p];
        unsigned u = hw[(size_t)q.x * 32];
        float w = __int_as_float(q.y);
        acc0 = fmaf(w, __uint_as_float(u << 16), acc0);
        acc1 = fmaf(w, __uint_as_float(u & 0xFFFF0000u), acc1);
    }

    // merge halves (each half summed a disjoint subset of the segment)
    acc0 += __shfl_xor(acc0, 32, 64);
    acc1 += __shfl_xor(acc1, 32, 64);

    if (half == 0) {
        *(float2*)(agg + (size_t)n * 192 + s * 64 + 2 * c) =
            make_float2(acc0 * fv.x, acc1 * fv.y);
    }
}

// ---------------------------------------------------------------------------
// mlp1 + log_softmax, tiled: 64 rows x 40 cols (padded to 64) per block.
// ---------------------------------------------------------------------------
__global__ __launch_bounds__(256) void gemm40_softmax(
    const float* __restrict__ A,      // [N][192]
    const float* __restrict__ B,      // [192][40]
    const float* __restrict__ bias,   // [40]
    float* __restrict__ out,          // [N][40]
    int nrows)
{
    __shared__ float As[32][68];
    __shared__ float Bs[32][64];

    const int tid = threadIdx.x;
    const int tx = tid & 15;
    const int ty = tid >> 4;
    const int row0 = blockIdx.x * 64;

    float acc[4][4] = {{0.f, 0.f, 0.f, 0.f}, {0.f, 0.f, 0.f, 0.f},
                       {0.f, 0.f, 0.f, 0.f}, {0.f, 0.f, 0.f, 0.f}};

    const int r = tid >> 2;
    const int koff = (tid & 3) * 8;
    const bool rowok = (row0 + r) < nrows;

    for (int k0 = 0; k0 < 192; k0 += 32) {
        float av[8];
        const float* ap = A + (size_t)(row0 + r) * 192 + (k0 + koff);
        if (rowok) {
            float4 v0 = *(const float4*)(ap);
            float4 v1 = *(const float4*)(ap + 4);
            av[0] = v0.x; av[1] = v0.y; av[2] = v0.z; av[3] = v0.w;
            av[4] = v1.x; av[5] = v1.y; av[6] = v1.z; av[7] = v1.w;
        } else {
            #pragma unroll
            for (int j = 0; j < 8; ++j) av[j] = 0.f;
        }
        #pragma unroll
        for (int j = 0; j < 8; ++j) As[koff + j][r] = fmaxf(av[j], 0.f);

        {
            int flat = tid * 8;
            int kk = flat >> 6;
            int c0 = flat & 63;
            #pragma unroll
            for (int j = 0; j < 8; ++j) {
                int cc = c0 + j;
                Bs[kk][cc] = (cc < 40) ? B[(size_t)(k0 + kk) * 40 + cc] : 0.f;
            }
        }
        __syncthreads();

        #pragma unroll
        for (int k = 0; k < 32; ++k) {
            float4 a = *(const float4*)&As[k][ty * 4];
            float4 b = *(const float4*)&Bs[k][tx * 4];
            acc[0][0] = fmaf(a.x, b.x, acc[0][0]);
            acc[0][1] = fmaf(a.x, b.y, acc[0][1]);
            acc[0][2] = fmaf(a.x, b.z, acc[0][2]);
            acc[0][3] = fmaf(a.x, b.w, acc[0][3]);
            acc[1][0] = fmaf(a.y, b.x, acc[1][0]);
            acc[1][1] = fmaf(a.y, b.y, acc[1][1]);
            acc[1][2] = fmaf(a.y, b.z, acc[1][2]);
            acc[1][3] = fmaf(a.y, b.w, acc[1][3]);
            acc[2][0] = fmaf(a.z, b.x, acc[2][0]);
            acc[2][1] = fmaf(a.z, b.y, acc[2][1]);
            acc[2][2] = fmaf(a.z, b.z, acc[2][2]);
            acc[2][3] = fmaf(a.z, b.w, acc[2][3]);
            acc[3][0] = fmaf(a.w, b.x, acc[3][0]);
            acc[3][1] = fmaf(a.w, b.y, acc[3][1]);
            acc[3][2] = fmaf(a.w, b.z, acc[3][2]);
            acc[3][3] = fmaf(a.w, b.w, acc[3][3]);
        }
        __syncthreads();
    }

    float bv[4];
    #pragma unroll
    for (int j = 0; j < 4; ++j) {
        int cc = tx * 4 + j;
        bv[j] = (cc < 40) ? bias[cc] : 0.f;
    }
    const bool colok = (tx < 10);

    #pragma unroll
    for (int i = 0; i < 4; ++i) {
        float v0 = colok ? acc[i][0] + bv[0] : -1e30f;
        float v1 = colok ? acc[i][1] + bv[1] : -1e30f;
        float v2 = colok ? acc[i][2] + bv[2] : -1e30f;
        float v3 = colok ? acc[i][3] + bv[3] : -1e30f;

        float mx = fmaxf(fmaxf(v0, v1), fmaxf(v2, v3));
        #pragma unroll
        for (int o = 1; o < 16; o <<= 1)
            mx = fmaxf(mx, __shfl_xor(mx, o, 64));

        float s = __expf(v0 - mx) + __expf(v1 - mx) +
                  __expf(v2 - mx) + __expf(v3 - mx);
        #pragma unroll
        for (int o = 1; o < 16; o <<= 1)
            s += __shfl_xor(s, o, 64);

        int rr = row0 + ty * 4 + i;
        if (rr < nrows && colok) {
            float ls = mx + __logf(s);
            *(float4*)(out + (size_t)rr * 40 + tx * 4) =
                make_float4(v0 - ls, v1 - ls, v2 - ls, v3 - ls);
        }
    }
}

// ---------------------------------------------------------------------------
extern "C" void kernel_launch(void* const* d_in, const int* in_sizes, int n_in,
                              void* d_out, int out_size, void* d_ws, size_t ws_size,
                              hipStream_t stream)
{
    const float* x    = (const float*)d_in[0];
    const int*   ei1  = (const int*)d_in[1];
    const float* ea1  = (const float*)d_in[2];
    const int*   ei2  = (const int*)d_in[3];
    const float* ea2  = (const float*)d_in[4];
    const int*   ei3  = (const int*)d_in[5];
    const float* ea3  = (const float*)d_in[6];
    const float* W1   = (const float*)d_in[7];
    const float* b1   = (const float*)d_in[8];
    const float* f1_1 = (const float*)d_in[9];
    const float* f2_1 = (const float*)d_in[10];
    const float* f1_2 = (const float*)d_in[11];
    const float* f2_2 = (const float*)d_in[12];
    const float* f1_3 = (const float*)d_in[13];
    const float* f2_3 = (const float*)d_in[14];
    const float* Wm2  = (const float*)d_in[15];
    const float* bm2  = (const float*)d_in[16];
    const float* Wm1  = (const float*)d_in[17];
    const float* bm1  = (const float*)d_in[18];
    float* out = (float*)d_out;

    // ws layout. brec aliases agg: brec is dead before agg's first write.
    float* agg  = (float*)d_ws;                              // N*192 f32
    int2*  brec = (int2*)d_ws;                               // 3E int2 (alias)
    char*  base = (char*)d_ws + (size_t)NN * 192 * 4;
    __hip_bfloat16* hbuf = (__hip_bfloat16*)base;            // N*64 bf16
    int*   cnt  = (int*)(base + (size_t)NN * 64 * 2);        // M2
    int*   offp = cnt + M2;                                  // M2
    int*   part = offp + M2;                                 // 512
    int*   off_b = part + 512;                               // NBK+1 (+pad)
    int*   node_off = off_b + NBK + 2;                       // 3N+1 (+pad)
    int2*  pairs = (int2*)(node_off + 3 * NN + 2);           // 3E int2

    const int gemm_grid = (NN + 63) / 64;
    const int P = (M2 + 1023) / 1024;    // 294

    // ---- dst-sort edges: atomic-free radix partition + per-bucket refine
    part_count<<<NBLK_P, 1024, 0, stream>>>(ei1, ei2, ei3, cnt);
    scan_a<<<P, 1024, 0, stream>>>(cnt, offp, part, M2);
    scan_b<<<1, 512, 0, stream>>>(part, P);
    scan_c<<<(M2 + 255) / 256, 256, 0, stream>>>(offp, off_b, part, M2);
    part_scatter<<<NBLK_P, 1024, 0, stream>>>(ei1, ea1, ei2, ea2, ei3, ea3,
                                              offp, brec);
    bucket_refine<<<NBK, 256, 0, stream>>>(brec, off_b, node_off, pairs);

    // ---- block 1 ----
    gemm_n64<FF, false, true><<<gemm_grid, 256, 0, stream>>>(x, W1, b1,
                                                             hbuf, NN);
    ufg_gather<<<(3 * NN + 3) / 4, 256, 0, stream>>>(hbuf, node_off, pairs,
                                                     f1_1, f1_2, f1_3, agg);
    gemm_n64<192, true, true><<<gemm_grid, 256, 0, stream>>>(agg, Wm2, bm2,
                                                             hbuf, NN);

    // ---- block 2 ----
    ufg_gather<<<(3 * NN + 3) / 4, 256, 0, stream>>>(hbuf, node_off, pairs,
                                                     f2_1, f2_2, f2_3, agg);
    gemm40_softmax<<<gemm_grid, 256, 0, stream>>>(agg, Wm1, bm1, out, NN);
}

// Round 9
// 523.291 us; speedup vs baseline: 1.0636x; 1.0636x over previous
//
#include <hip/hip_runtime.h>
#include <hip/hip_bf16.h>

#define NN 100000
#define FF 500
#define HH 64
#define CC 40
#define EE 1000000
#define NB 782            // buckets per scale: ceil(100000/128)
#define NBK 2346          // 3*NB
#define NBLK_P 128        // partition blocks
#define M2 (NBK * NBLK_P) // 300288 counters

// ---------------------------------------------------------------------------
// GEMM: C[N][64] = (opt relu)(A[N][K]) @ B[K][64] + bias[64]
// ABF16: A is bf16 (unpack in staging). OBF16: write output as bf16.
// ---------------------------------------------------------------------------
template <int K, bool RELU, bool ABF16, bool OBF16>
__global__ __launch_bounds__(256) void gemm_n64(
    const void* __restrict__ Av,
    const float* __restrict__ B,
    const float* __restrict__ bias,
    void* __restrict__ Cv,
    int nrows)
{
    __shared__ float As[32][68];
    __shared__ float Bs[32][64];

    const int tid = threadIdx.x;
    const int tx = tid & 15;
    const int ty = tid >> 4;
    const int row0 = blockIdx.x * 64;

    float acc[4][4] = {{0.f, 0.f, 0.f, 0.f}, {0.f, 0.f, 0.f, 0.f},
                       {0.f, 0.f, 0.f, 0.f}, {0.f, 0.f, 0.f, 0.f}};

    const int r = tid >> 2;
    const int koff = (tid & 3) * 8;
    const bool rowok = (row0 + r) < nrows;

    for (int k0 = 0; k0 < K; k0 += 32) {
        float av[8];
        if (ABF16) {
            const __hip_bfloat16* ap =
                (const __hip_bfloat16*)Av + (size_t)(row0 + r) * K + (k0 + koff);
            if (rowok) {
                uint4 u = *(const uint4*)ap;     // 8 bf16
                av[0] = __uint_as_float(u.x << 16);
                av[1] = __uint_as_float(u.x & 0xFFFF0000u);
                av[2] = __uint_as_float(u.y << 16);
                av[3] = __uint_as_float(u.y & 0xFFFF0000u);
                av[4] = __uint_as_float(u.z << 16);
                av[5] = __uint_as_float(u.z & 0xFFFF0000u);
                av[6] = __uint_as_float(u.w << 16);
                av[7] = __uint_as_float(u.w & 0xFFFF0000u);
            } else {
                #pragma unroll
                for (int j = 0; j < 8; ++j) av[j] = 0.f;
            }
        } else {
            const float* ap = (const float*)Av + (size_t)(row0 + r) * K + (k0 + koff);
            if (rowok && ((K % 32 == 0) || (k0 + 32 <= K))) {
                float4 v0 = *(const float4*)(ap);
                float4 v1 = *(const float4*)(ap + 4);
                av[0] = v0.x; av[1] = v0.y; av[2] = v0.z; av[3] = v0.w;
                av[4] = v1.x; av[5] = v1.y; av[6] = v1.z; av[7] = v1.w;
            } else {
                #pragma unroll
                for (int j = 0; j < 8; ++j) {
                    int kk = k0 + koff + j;
                    av[j] = (rowok && kk < K) ? ap[j] : 0.f;
                }
            }
        }
        if (RELU) {
            #pragma unroll
            for (int j = 0; j < 8; ++j) av[j] = fmaxf(av[j], 0.f);
        }
        #pragma unroll
        for (int j = 0; j < 8; ++j) As[koff + j][r] = av[j];

        {
            int flat = tid * 8;
            int kk = flat >> 6;
            int c = flat & 63;
            float4 b0, b1v;
            if (k0 + kk < K) {
                b0 = *(const float4*)(B + (size_t)(k0 + kk) * 64 + c);
                b1v = *(const float4*)(B + (size_t)(k0 + kk) * 64 + c + 4);
            } else {
                b0 = make_float4(0.f, 0.f, 0.f, 0.f);
                b1v = b0;
            }
            *(float4*)&Bs[kk][c] = b0;
            *(float4*)&Bs[kk][c + 4] = b1v;
        }
        __syncthreads();

        #pragma unroll
        for (int k = 0; k < 32; ++k) {
            float4 a = *(const float4*)&As[k][ty * 4];
            float4 b = *(const float4*)&Bs[k][tx * 4];
            acc[0][0] = fmaf(a.x, b.x, acc[0][0]);
            acc[0][1] = fmaf(a.x, b.y, acc[0][1]);
            acc[0][2] = fmaf(a.x, b.z, acc[0][2]);
            acc[0][3] = fmaf(a.x, b.w, acc[0][3]);
            acc[1][0] = fmaf(a.y, b.x, acc[1][0]);
            acc[1][1] = fmaf(a.y, b.y, acc[1][1]);
            acc[1][2] = fmaf(a.y, b.z, acc[1][2]);
            acc[1][3] = fmaf(a.y, b.w, acc[1][3]);
            acc[2][0] = fmaf(a.z, b.x, acc[2][0]);
            acc[2][1] = fmaf(a.z, b.y, acc[2][1]);
            acc[2][2] = fmaf(a.z, b.z, acc[2][2]);
            acc[2][3] = fmaf(a.z, b.w, acc[2][3]);
            acc[3][0] = fmaf(a.w, b.x, acc[3][0]);
            acc[3][1] = fmaf(a.w, b.y, acc[3][1]);
            acc[3][2] = fmaf(a.w, b.z, acc[3][2]);
            acc[3][3] = fmaf(a.w, b.w, acc[3][3]);
        }
        __syncthreads();
    }

    float4 bv = *(const float4*)(bias + tx * 4);
    #pragma unroll
    for (int i = 0; i < 4; ++i) {
        int rr = row0 + ty * 4 + i;
        if (rr < nrows) {
            float o0 = acc[i][0] + bv.x;
            float o1 = acc[i][1] + bv.y;
            float o2 = acc[i][2] + bv.z;
            float o3 = acc[i][3] + bv.w;
            if (OBF16) {
                __hip_bfloat16* Cb = (__hip_bfloat16*)Cv;
                __hip_bfloat162 lo = __float22bfloat162_rn(make_float2(o0, o1));
                __hip_bfloat162 hi = __float22bfloat162_rn(make_float2(o2, o3));
                *(__hip_bfloat162*)(Cb + (size_t)rr * 64 + tx * 4) = lo;
                *(__hip_bfloat162*)(Cb + (size_t)rr * 64 + tx * 4 + 2) = hi;
            } else {
                float* C = (float*)Cv;
                *(float4*)(C + (size_t)rr * 64 + tx * 4) =
                    make_float4(o0, o1, o2, o3);
            }
        }
    }
}

// ---------------------------------------------------------------------------
// Radix partition pass 1: per-block private bucket histogram (LDS only).
// ---------------------------------------------------------------------------
__global__ __launch_bounds__(1024) void part_count(
    const int* __restrict__ ei1, const int* __restrict__ ei2,
    const int* __restrict__ ei3, int* __restrict__ cnt)
{
    __shared__ int lc[NBK];
    const int t = threadIdx.x;
    for (int j = t; j < NBK; j += 1024) lc[j] = 0;
    __syncthreads();

    const int chunk = (3 * EE + NBLK_P - 1) / NBLK_P;
    const int b0 = blockIdx.x * chunk;
    int b1 = b0 + chunk;
    if (b1 > 3 * EE) b1 = 3 * EE;

    for (int i = b0 + t; i < b1; i += 1024) {
        int s = i / EE;
        int e = i - s * EE;
        const int* ei = (s == 0) ? ei1 : (s == 1) ? ei2 : ei3;
        atomicAdd(&lc[s * NB + (ei[EE + e] >> 7)], 1);
    }
    __syncthreads();
    for (int j = t; j < NBK; j += 1024)
        cnt[j * NBLK_P + blockIdx.x] = lc[j];
}

// ---------------------------------------------------------------------------
// Exclusive scan over M2 counters.
// ---------------------------------------------------------------------------
__global__ __launch_bounds__(1024) void scan_a(
    const int* __restrict__ cnt, int* __restrict__ off,
    int* __restrict__ partials, int M)
{
    __shared__ int sh[1024];
    int t = threadIdx.x;
    int i = blockIdx.x * 1024 + t;
    int v = (i < M) ? cnt[i] : 0;
    sh[t] = v;
    __syncthreads();
    #pragma unroll
    for (int o = 1; o < 1024; o <<= 1) {
        int add = (t >= o) ? sh[t - o] : 0;
        __syncthreads();
        sh[t] += add;
        __syncthreads();
    }
    if (i < M) off[i] = sh[t] - v;
    if (t == 1023) partials[blockIdx.x] = sh[1023];
}

__global__ __launch_bounds__(512) void scan_b(int* __restrict__ partials, int P)
{
    __shared__ int sh[512];
    int t = threadIdx.x;
    int v = (t < P) ? partials[t] : 0;
    sh[t] = v;
    __syncthreads();
    #pragma unroll
    for (int o = 1; o < 512; o <<= 1) {
        int add = (t >= o) ? sh[t - o] : 0;
        __syncthreads();
        sh[t] += add;
        __syncthreads();
    }
    if (t < P) partials[t] = sh[t] - v;
}

__global__ __launch_bounds__(256) void scan_c(
    int* __restrict__ off, int* __restrict__ off_b,
    const int* __restrict__ partials, int M)
{
    int i = blockIdx.x * 256 + threadIdx.x;
    if (i < M) {
        int v = off[i] + partials[i >> 10];
        off[i] = v;
        if ((i & (NBLK_P - 1)) == 0) off_b[i / NBLK_P] = v;
    }
    if (i == 0) off_b[NBK] = 3 * EE;
}

// ---------------------------------------------------------------------------
// Radix partition pass 2: place records via LDS cursors.
// ---------------------------------------------------------------------------
__global__ __launch_bounds__(1024) void part_scatter(
    const int* __restrict__ ei1, const float* __restrict__ ea1,
    const int* __restrict__ ei2, const float* __restrict__ ea2,
    const int* __restrict__ ei3, const float* __restrict__ ea3,
    const int* __restrict__ offp, int2* __restrict__ brec)
{
    __shared__ int lcur[NBK];
    const int t = threadIdx.x;
    for (int j = t; j < NBK; j += 1024)
        lcur[j] = offp[j * NBLK_P + blockIdx.x];
    __syncthreads();

    const int chunk = (3 * EE + NBLK_P - 1) / NBLK_P;
    const int b0 = blockIdx.x * chunk;
    int b1 = b0 + chunk;
    if (b1 > 3 * EE) b1 = 3 * EE;

    for (int i = b0 + t; i < b1; i += 1024) {
        int s = i / EE;
        int e = i - s * EE;
        const int* ei = (s == 0) ? ei1 : (s == 1) ? ei2 : ei3;
        const float* ea = (s == 0) ? ea1 : (s == 1) ? ea2 : ea3;
        int src = ei[e];
        int dst = ei[EE + e];
        float w = ea[e];
        int pos = atomicAdd(&lcur[s * NB + (dst >> 7)], 1);
        brec[pos] = make_int2(src | ((dst & 127) << 17), __float_as_int(w));
    }
}

// ---------------------------------------------------------------------------
// Bucket refine: one block per bucket; LDS counting sort of 128 local dsts.
// ---------------------------------------------------------------------------
__global__ __launch_bounds__(256) void bucket_refine(
    const int2* __restrict__ brec,
    const int* __restrict__ off_b,      // [NBK+1]
    int* __restrict__ node_off,         // [3N+1]
    int2* __restrict__ pairs)
{
    __shared__ int hist[128];
    __shared__ int curls[128];
    const int t = threadIdx.x;
    const int bk = blockIdx.x;
    const int s = bk / NB;
    const int b = bk - s * NB;
    const int n0 = b << 7;
    const int beg = off_b[bk];
    const int end = off_b[bk + 1];

    if (bk == 0 && t == 0) node_off[3 * NN] = 3 * EE;
    if (t < 128) hist[t] = 0;
    __syncthreads();

    for (int p = beg + t; p < end; p += 256)
        atomicAdd(&hist[(brec[p].x >> 17) & 127], 1);
    __syncthreads();

    int cnt = (t < 128) ? hist[t] : 0;
    #pragma unroll
    for (int o = 1; o < 128; o <<= 1) {
        int add = (t < 128 && t >= o) ? hist[t - o] : 0;
        __syncthreads();
        if (t < 128) hist[t] += add;
        __syncthreads();
    }
    if (t < 128) {
        int excl = beg + hist[t] - cnt;
        curls[t] = excl;
        if (n0 + t < NN) node_off[s * NN + n0 + t] = excl;
    }
    __syncthreads();

    for (int p = beg + t; p < end; p += 256) {
        int2 r = brec[p];
        int pos = atomicAdd(&curls[(r.x >> 17) & 127], 1);
        pairs[pos] = make_int2(r.x & 0x1FFFF, r.y);
    }
}

// ---------------------------------------------------------------------------
// Segmented gather (round-7 structure, bf16 h, bf16 agg out): one wave per
// (node, scale); lane = column; 8-deep ILP.
// ---------------------------------------------------------------------------
__global__ __launch_bounds__(256) void ufg_gather(
    const __hip_bfloat16* __restrict__ h,   // [N][64] bf16
    const int* __restrict__ off,            // [3N+1]
    const int2* __restrict__ pairs,         // [3E]
    const float* __restrict__ f1, const float* __restrict__ f2,
    const float* __restrict__ f3,
    __hip_bfloat16* __restrict__ agg)       // [N][192] bf16
{
    const int lane = threadIdx.x & 63;
    const int wid = blockIdx.x * 4 + (threadIdx.x >> 6);
    if (wid >= 3 * NN) return;
    const int s = wid / NN;
    const int n = wid - s * NN;

    const float* fp = (s == 0) ? f1 : (s == 1) ? f2 : f3;
    const float fv = fp[lane];
    const __hip_bfloat16* hl = h + lane;

    const int beg = off[wid];
    const int end = off[wid + 1];

    float acc0 = 0.f, acc1 = 0.f;
    int p = beg;

    for (; p + 8 <= end; p += 8) {
        int2 q0 = pairs[p + 0];
        int2 q1 = pairs[p + 1];
        int2 q2 = pairs[p + 2];
        int2 q3 = pairs[p + 3];
        int2 q4 = pairs[p + 4];
        int2 q5 = pairs[p + 5];
        int2 q6 = pairs[p + 6];
        int2 q7 = pairs[p + 7];
        float v0 = __bfloat162float(hl[(size_t)q0.x * 64]);
        float v1 = __bfloat162float(hl[(size_t)q1.x * 64]);
        float v2 = __bfloat162float(hl[(size_t)q2.x * 64]);
        float v3 = __bfloat162float(hl[(size_t)q3.x * 64]);
        float v4 = __bfloat162float(hl[(size_t)q4.x * 64]);
        float v5 = __bfloat162float(hl[(size_t)q5.x * 64]);
        float v6 = __bfloat162float(hl[(size_t)q6.x * 64]);
        float v7 = __bfloat162float(hl[(size_t)q7.x * 64]);
        acc0 = fmaf(__int_as_float(q0.y), v0, acc0);
        acc1 = fmaf(__int_as_float(q1.y), v1, acc1);
        acc0 = fmaf(__int_as_float(q2.y), v2, acc0);
        acc1 = fmaf(__int_as_float(q3.y), v3, acc1);
        acc0 = fmaf(__int_as_float(q4.y), v4, acc0);
        acc1 = fmaf(__int_as_float(q5.y), v5, acc1);
        acc0 = fmaf(__int_as_float(q6.y), v6, acc0);
        acc1 = fmaf(__int_as_float(q7.y), v7, acc1);
    }
    if (p + 4 <= end) {
        int2 q0 = pairs[p + 0];
        int2 q1 = pairs[p + 1];
        int2 q2 = pairs[p + 2];
        int2 q3 = pairs[p + 3];
        float v0 = __bfloat162float(hl[(size_t)q0.x * 64]);
        float v1 = __bfloat162float(hl[(size_t)q1.x * 64]);
        float v2 = __bfloat162float(hl[(size_t)q2.x * 64]);
        float v3 = __bfloat162float(hl[(size_t)q3.x * 64]);
        acc0 = fmaf(__int_as_float(q0.y), v0, acc0);
        acc1 = fmaf(__int_as_float(q1.y), v1, acc1);
        acc0 = fmaf(__int_as_float(q2.y), v2, acc0);
        acc1 = fmaf(__int_as_float(q3.y), v3, acc1);
        p += 4;
    }
    if (p + 2 <= end) {
        int2 q0 = pairs[p + 0];
        int2 q1 = pairs[p + 1];
        float v0 = __bfloat162float(hl[(size_t)q0.x * 64]);
        float v1 = __bfloat162float(hl[(size_t)q1.x * 64]);
        acc0 = fmaf(__int_as_float(q0.y), v0, acc0);
        acc1 = fmaf(__int_as_float(q1.y), v1, acc1);
        p += 2;
    }
    if (p < end) {
        int2 q = pairs[p];
        acc0 = fmaf(__int_as_float(q.y),
                    __bfloat162float(hl[(size_t)q.x * 64]), acc0);
    }

    agg[(size_t)n * 192 + s * 64 + lane] =
        __float2bfloat16((acc0 + acc1) * fv);
}

// ---------------------------------------------------------------------------
// mlp1 + log_softmax, tiled: 64 rows x 40 cols (padded to 64) per block.
// A is bf16 [N][192], relu fused in staging.
// ---------------------------------------------------------------------------
__global__ __launch_bounds__(256) void gemm40_softmax(
    const __hip_bfloat16* __restrict__ A, // [N][192] bf16
    const float* __restrict__ B,          // [192][40]
    const float* __restrict__ bias,       // [40]
    float* __restrict__ out,              // [N][40]
    int nrows)
{
    __shared__ float As[32][68];
    __shared__ float Bs[32][64];

    const int tid = threadIdx.x;
    const int tx = tid & 15;
    const int ty = tid >> 4;
    const int row0 = blockIdx.x * 64;

    float acc[4][4] = {{0.f, 0.f, 0.f, 0.f}, {0.f, 0.f, 0.f, 0.f},
                       {0.f, 0.f, 0.f, 0.f}, {0.f, 0.f, 0.f, 0.f}};

    const int r = tid >> 2;
    const int koff = (tid & 3) * 8;
    const bool rowok = (row0 + r) < nrows;

    for (int k0 = 0; k0 < 192; k0 += 32) {
        float av[8];
        const __hip_bfloat16* ap = A + (size_t)(row0 + r) * 192 + (k0 + koff);
        if (rowok) {
            uint4 u = *(const uint4*)ap;     // 8 bf16
            av[0] = __uint_as_float(u.x << 16);
            av[1] = __uint_as_float(u.x & 0xFFFF0000u);
            av[2] = __uint_as_float(u.y << 16);
            av[3] = __uint_as_float(u.y & 0xFFFF0000u);
            av[4] = __uint_as_float(u.z << 16);
            av[5] = __uint_as_float(u.z & 0xFFFF0000u);
            av[6] = __uint_as_float(u.w << 16);
            av[7] = __uint_as_float(u.w & 0xFFFF0000u);
        } else {
            #pragma unroll
            for (int j = 0; j < 8; ++j) av[j] = 0.f;
        }
        #pragma unroll
        for (int j = 0; j < 8; ++j) As[koff + j][r] = fmaxf(av[j], 0.f);

        {
            int flat = tid * 8;
            int kk = flat >> 6;
            int c0 = flat & 63;
            #pragma unroll
            for (int j = 0; j < 8; ++j) {
                int cc = c0 + j;
                Bs[kk][cc] = (cc < 40) ? B[(size_t)(k0 + kk) * 40 + cc] : 0.f;
            }
        }
        __syncthreads();

        #pragma unroll
        for (int k = 0; k < 32; ++k) {
            float4 a = *(const float4*)&As[k][ty * 4];
            float4 b = *(const float4*)&Bs[k][tx * 4];
            acc[0][0] = fmaf(a.x, b.x, acc[0][0]);
            acc[0][1] = fmaf(a.x, b.y, acc[0][1]);
            acc[0][2] = fmaf(a.x, b.z, acc[0][2]);
            acc[0][3] = fmaf(a.x, b.w, acc[0][3]);
            acc[1][0] = fmaf(a.y, b.x, acc[1][0]);
            acc[1][1] = fmaf(a.y, b.y, acc[1][1]);
            acc[1][2] = fmaf(a.y, b.z, acc[1][2]);
            acc[1][3] = fmaf(a.y, b.w, acc[1][3]);
            acc[2][0] = fmaf(a.z, b.x, acc[2][0]);
            acc[2][1] = fmaf(a.z, b.y, acc[2][1]);
            acc[2][2] = fmaf(a.z, b.z, acc[2][2]);
            acc[2][3] = fmaf(a.z, b.w, acc[2][3]);
            acc[3][0] = fmaf(a.w, b.x, acc[3][0]);
            acc[3][1] = fmaf(a.w, b.y, acc[3][1]);
            acc[3][2] = fmaf(a.w, b.z, acc[3][2]);
            acc[3][3] = fmaf(a.w, b.w, acc[3][3]);
        }
        __syncthreads();
    }

    float bv[4];
    #pragma unroll
    for (int j = 0; j < 4; ++j) {
        int cc = tx * 4 + j;
        bv[j] = (cc < 40) ? bias[cc] : 0.f;
    }
    const bool colok = (tx < 10);

    #pragma unroll
    for (int i = 0; i < 4; ++i) {
        float v0 = colok ? acc[i][0] + bv[0] : -1e30f;
        float v1 = colok ? acc[i][1] + bv[1] : -1e30f;
        float v2 = colok ? acc[i][2] + bv[2] : -1e30f;
        float v3 = colok ? acc[i][3] + bv[3] : -1e30f;

        float mx = fmaxf(fmaxf(v0, v1), fmaxf(v2, v3));
        #pragma unroll
        for (int o = 1; o < 16; o <<= 1)
            mx = fmaxf(mx, __shfl_xor(mx, o, 64));

        float s = __expf(v0 - mx) + __expf(v1 - mx) +
                  __expf(v2 - mx) + __expf(v3 - mx);
        #pragma unroll
        for (int o = 1; o < 16; o <<= 1)
            s += __shfl_xor(s, o, 64);

        int rr = row0 + ty * 4 + i;
        if (rr < nrows && colok) {
            float ls = mx + __logf(s);
            *(float4*)(out + (size_t)rr * 40 + tx * 4) =
                make_float4(v0 - ls, v1 - ls, v2 - ls, v3 - ls);
        }
    }
}

// ---------------------------------------------------------------------------
extern "C" void kernel_launch(void* const* d_in, const int* in_sizes, int n_in,
                              void* d_out, int out_size, void* d_ws, size_t ws_size,
                              hipStream_t stream)
{
    const float* x    = (const float*)d_in[0];
    const int*   ei1  = (const int*)d_in[1];
    const float* ea1  = (const float*)d_in[2];
    const int*   ei2  = (const int*)d_in[3];
    const float* ea2  = (const float*)d_in[4];
    const int*   ei3  = (const int*)d_in[5];
    const float* ea3  = (const float*)d_in[6];
    const float* W1   = (const float*)d_in[7];
    const float* b1   = (const float*)d_in[8];
    const float* f1_1 = (const float*)d_in[9];
    const float* f2_1 = (const float*)d_in[10];
    const float* f1_2 = (const float*)d_in[11];
    const float* f2_2 = (const float*)d_in[12];
    const float* f1_3 = (const float*)d_in[13];
    const float* f2_3 = (const float*)d_in[14];
    const float* Wm2  = (const float*)d_in[15];
    const float* bm2  = (const float*)d_in[16];
    const float* Wm1  = (const float*)d_in[17];
    const float* bm1  = (const float*)d_in[18];
    float* out = (float*)d_out;

    // ws layout. agg is now bf16 [N][192] (38.4 MB); brec (24 MB) aliases it
    // (brec dead before agg's first write).
    __hip_bfloat16* agg = (__hip_bfloat16*)d_ws;             // N*192 bf16
    int2*  brec = (int2*)d_ws;                               // 3E int2 (alias)
    char*  base = (char*)d_ws + (size_t)NN * 192 * 2;
    __hip_bfloat16* hbuf = (__hip_bfloat16*)base;            // N*64 bf16
    int*   cnt  = (int*)(base + (size_t)NN * 64 * 2);        // M2
    int*   offp = cnt + M2;                                  // M2
    int*   part = offp + M2;                                 // 512
    int*   off_b = part + 512;                               // NBK+1 (+pad)
    int*   node_off = off_b + NBK + 2;                       // 3N+1 (+pad)
    int2*  pairs = (int2*)(node_off + 3 * NN + 2);           // 3E int2

    const int gemm_grid = (NN + 63) / 64;
    const int P = (M2 + 1023) / 1024;    // 294

    // ---- dst-sort edges: atomic-free radix partition + per-bucket refine
    part_count<<<NBLK_P, 1024, 0, stream>>>(ei1, ei2, ei3, cnt);
    scan_a<<<P, 1024, 0, stream>>>(cnt, offp, part, M2);
    scan_b<<<1, 512, 0, stream>>>(part, P);
    scan_c<<<(M2 + 255) / 256, 256, 0, stream>>>(offp, off_b, part, M2);
    part_scatter<<<NBLK_P, 1024, 0, stream>>>(ei1, ea1, ei2, ea2, ei3, ea3,
                                              offp, brec);
    bucket_refine<<<NBK, 256, 0, stream>>>(brec, off_b, node_off, pairs);

    // ---- block 1 ----
    gemm_n64<FF, false, false, true><<<gemm_grid, 256, 0, stream>>>(
        x, W1, b1, hbuf, NN);
    ufg_gather<<<(3 * NN + 3) / 4, 256, 0, stream>>>(hbuf, node_off, pairs,
                                                     f1_1, f1_2, f1_3, agg);
    gemm_n64<192, true, true, true><<<gemm_grid, 256, 0, stream>>>(
        agg, Wm2, bm2, hbuf, NN);

    // ---- block 2 ----
    ufg_gather<<<(3 * NN + 3) / 4, 256, 0, stream>>>(hbuf, node_off, pairs,
                                                     f2_1, f2_2, f2_3, agg);
    gemm40_softmax<<<gemm_grid, 256, 0, stream>>>(agg, Wm1, bm1, out, NN);
}

// Round 10
// 480.781 us; speedup vs baseline: 1.1577x; 1.0884x over previous
//
#include <hip/hip_runtime.h>
#include <hip/hip_bf16.h>

#define NN 100000
#define FF 500
#define HH 64
#define CC 40
#define EE 1000000
#define NB 782            // buckets per scale: ceil(100000/128)
#define NBK 2346          // 3*NB
#define NBLK_P 128        // partition blocks
#define M2 (NBK * NBLK_P) // 300288 counters

// ---------------------------------------------------------------------------
// GEMM: C[N][64] = (opt relu)(A[N][K]) @ B[K][64] + bias[64]
// ABF16: A is bf16 (unpack in staging). OBF16: write output as bf16.
// ---------------------------------------------------------------------------
template <int K, bool RELU, bool ABF16, bool OBF16>
__global__ __launch_bounds__(256) void gemm_n64(
    const void* __restrict__ Av,
    const float* __restrict__ B,
    const float* __restrict__ bias,
    void* __restrict__ Cv,
    int nrows)
{
    __shared__ float As[32][68];
    __shared__ float Bs[32][64];

    const int tid = threadIdx.x;
    const int tx = tid & 15;
    const int ty = tid >> 4;
    const int row0 = blockIdx.x * 64;

    float acc[4][4] = {{0.f, 0.f, 0.f, 0.f}, {0.f, 0.f, 0.f, 0.f},
                       {0.f, 0.f, 0.f, 0.f}, {0.f, 0.f, 0.f, 0.f}};

    const int r = tid >> 2;
    const int koff = (tid & 3) * 8;
    const bool rowok = (row0 + r) < nrows;

    for (int k0 = 0; k0 < K; k0 += 32) {
        float av[8];
        if (ABF16) {
            const __hip_bfloat16* ap =
                (const __hip_bfloat16*)Av + (size_t)(row0 + r) * K + (k0 + koff);
            if (rowok) {
                uint4 u = *(const uint4*)ap;     // 8 bf16
                av[0] = __uint_as_float(u.x << 16);
                av[1] = __uint_as_float(u.x & 0xFFFF0000u);
                av[2] = __uint_as_float(u.y << 16);
                av[3] = __uint_as_float(u.y & 0xFFFF0000u);
                av[4] = __uint_as_float(u.z << 16);
                av[5] = __uint_as_float(u.z & 0xFFFF0000u);
                av[6] = __uint_as_float(u.w << 16);
                av[7] = __uint_as_float(u.w & 0xFFFF0000u);
            } else {
                #pragma unroll
                for (int j = 0; j < 8; ++j) av[j] = 0.f;
            }
        } else {
            const float* ap = (const float*)Av + (size_t)(row0 + r) * K + (k0 + koff);
            if (rowok && ((K % 32 == 0) || (k0 + 32 <= K))) {
                float4 v0 = *(const float4*)(ap);
                float4 v1 = *(const float4*)(ap + 4);
                av[0] = v0.x; av[1] = v0.y; av[2] = v0.z; av[3] = v0.w;
                av[4] = v1.x; av[5] = v1.y; av[6] = v1.z; av[7] = v1.w;
            } else {
                #pragma unroll
                for (int j = 0; j < 8; ++j) {
                    int kk = k0 + koff + j;
                    av[j] = (rowok && kk < K) ? ap[j] : 0.f;
                }
            }
        }
        if (RELU) {
            #pragma unroll
            for (int j = 0; j < 8; ++j) av[j] = fmaxf(av[j], 0.f);
        }
        #pragma unroll
        for (int j = 0; j < 8; ++j) As[koff + j][r] = av[j];

        {
            int flat = tid * 8;
            int kk = flat >> 6;
            int c = flat & 63;
            float4 b0, b1v;
            if (k0 + kk < K) {
                b0 = *(const float4*)(B + (size_t)(k0 + kk) * 64 + c);
                b1v = *(const float4*)(B + (size_t)(k0 + kk) * 64 + c + 4);
            } else {
                b0 = make_float4(0.f, 0.f, 0.f, 0.f);
                b1v = b0;
            }
            *(float4*)&Bs[kk][c] = b0;
            *(float4*)&Bs[kk][c + 4] = b1v;
        }
        __syncthreads();

        #pragma unroll
        for (int k = 0; k < 32; ++k) {
            float4 a = *(const float4*)&As[k][ty * 4];
            float4 b = *(const float4*)&Bs[k][tx * 4];
            acc[0][0] = fmaf(a.x, b.x, acc[0][0]);
            acc[0][1] = fmaf(a.x, b.y, acc[0][1]);
            acc[0][2] = fmaf(a.x, b.z, acc[0][2]);
            acc[0][3] = fmaf(a.x, b.w, acc[0][3]);
            acc[1][0] = fmaf(a.y, b.x, acc[1][0]);
            acc[1][1] = fmaf(a.y, b.y, acc[1][1]);
            acc[1][2] = fmaf(a.y, b.z, acc[1][2]);
            acc[1][3] = fmaf(a.y, b.w, acc[1][3]);
            acc[2][0] = fmaf(a.z, b.x, acc[2][0]);
            acc[2][1] = fmaf(a.z, b.y, acc[2][1]);
            acc[2][2] = fmaf(a.z, b.z, acc[2][2]);
            acc[2][3] = fmaf(a.z, b.w, acc[2][3]);
            acc[3][0] = fmaf(a.w, b.x, acc[3][0]);
            acc[3][1] = fmaf(a.w, b.y, acc[3][1]);
            acc[3][2] = fmaf(a.w, b.z, acc[3][2]);
            acc[3][3] = fmaf(a.w, b.w, acc[3][3]);
        }
        __syncthreads();
    }

    float4 bv = *(const float4*)(bias + tx * 4);
    #pragma unroll
    for (int i = 0; i < 4; ++i) {
        int rr = row0 + ty * 4 + i;
        if (rr < nrows) {
            float o0 = acc[i][0] + bv.x;
            float o1 = acc[i][1] + bv.y;
            float o2 = acc[i][2] + bv.z;
            float o3 = acc[i][3] + bv.w;
            if (OBF16) {
                __hip_bfloat16* Cb = (__hip_bfloat16*)Cv;
                __hip_bfloat162 lo = __float22bfloat162_rn(make_float2(o0, o1));
                __hip_bfloat162 hi = __float22bfloat162_rn(make_float2(o2, o3));
                *(__hip_bfloat162*)(Cb + (size_t)rr * 64 + tx * 4) = lo;
                *(__hip_bfloat162*)(Cb + (size_t)rr * 64 + tx * 4 + 2) = hi;
            } else {
                float* C = (float*)Cv;
                *(float4*)(C + (size_t)rr * 64 + tx * 4) =
                    make_float4(o0, o1, o2, o3);
            }
        }
    }
}

// ---------------------------------------------------------------------------
// Radix partition pass 1: per-block private bucket histogram (LDS only).
// ---------------------------------------------------------------------------
__global__ __launch_bounds__(1024) void part_count(
    const int* __restrict__ ei1, const int* __restrict__ ei2,
    const int* __restrict__ ei3, int* __restrict__ cnt)
{
    __shared__ int lc[NBK];
    const int t = threadIdx.x;
    for (int j = t; j < NBK; j += 1024) lc[j] = 0;
    __syncthreads();

    const int chunk = (3 * EE + NBLK_P - 1) / NBLK_P;
    const int b0 = blockIdx.x * chunk;
    int b1 = b0 + chunk;
    if (b1 > 3 * EE) b1 = 3 * EE;

    for (int i = b0 + t; i < b1; i += 1024) {
        int s = i / EE;
        int e = i - s * EE;
        const int* ei = (s == 0) ? ei1 : (s == 1) ? ei2 : ei3;
        atomicAdd(&lc[s * NB + (ei[EE + e] >> 7)], 1);
    }
    __syncthreads();
    for (int j = t; j < NBK; j += 1024)
        cnt[j * NBLK_P + blockIdx.x] = lc[j];
}

// ---------------------------------------------------------------------------
// Exclusive scan over M2 counters.
// ---------------------------------------------------------------------------
__global__ __launch_bounds__(1024) void scan_a(
    const int* __restrict__ cnt, int* __restrict__ off,
    int* __restrict__ partials, int M)
{
    __shared__ int sh[1024];
    int t = threadIdx.x;
    int i = blockIdx.x * 1024 + t;
    int v = (i < M) ? cnt[i] : 0;
    sh[t] = v;
    __syncthreads();
    #pragma unroll
    for (int o = 1; o < 1024; o <<= 1) {
        int add = (t >= o) ? sh[t - o] : 0;
        __syncthreads();
        sh[t] += add;
        __syncthreads();
    }
    if (i < M) off[i] = sh[t] - v;
    if (t == 1023) partials[blockIdx.x] = sh[1023];
}

__global__ __launch_bounds__(512) void scan_b(int* __restrict__ partials, int P)
{
    __shared__ int sh[512];
    int t = threadIdx.x;
    int v = (t < P) ? partials[t] : 0;
    sh[t] = v;
    __syncthreads();
    #pragma unroll
    for (int o = 1; o < 512; o <<= 1) {
        int add = (t >= o) ? sh[t - o] : 0;
        __syncthreads();
        sh[t] += add;
        __syncthreads();
    }
    if (t < P) partials[t] = sh[t] - v;
}

__global__ __launch_bounds__(256) void scan_c(
    int* __restrict__ off, int* __restrict__ off_b,
    const int* __restrict__ partials, int M)
{
    int i = blockIdx.x * 256 + threadIdx.x;
    if (i < M) {
        int v = off[i] + partials[i >> 10];
        off[i] = v;
        if ((i & (NBLK_P - 1)) == 0) off_b[i / NBLK_P] = v;
    }
    if (i == 0) off_b[NBK] = 3 * EE;
}

// ---------------------------------------------------------------------------
// Radix partition pass 2: place records via LDS cursors.
// ---------------------------------------------------------------------------
__global__ __launch_bounds__(1024) void part_scatter(
    const int* __restrict__ ei1, const float* __restrict__ ea1,
    const int* __restrict__ ei2, const float* __restrict__ ea2,
    const int* __restrict__ ei3, const float* __restrict__ ea3,
    const int* __restrict__ offp, int2* __restrict__ brec)
{
    __shared__ int lcur[NBK];
    const int t = threadIdx.x;
    for (int j = t; j < NBK; j += 1024)
        lcur[j] = offp[j * NBLK_P + blockIdx.x];
    __syncthreads();

    const int chunk = (3 * EE + NBLK_P - 1) / NBLK_P;
    const int b0 = blockIdx.x * chunk;
    int b1 = b0 + chunk;
    if (b1 > 3 * EE) b1 = 3 * EE;

    for (int i = b0 + t; i < b1; i += 1024) {
        int s = i / EE;
        int e = i - s * EE;
        const int* ei = (s == 0) ? ei1 : (s == 1) ? ei2 : ei3;
        const float* ea = (s == 0) ? ea1 : (s == 1) ? ea2 : ea3;
        int src = ei[e];
        int dst = ei[EE + e];
        float w = ea[e];
        int pos = atomicAdd(&lcur[s * NB + (dst >> 7)], 1);
        brec[pos] = make_int2(src | ((dst & 127) << 17), __float_as_int(w));
    }
}

// ---------------------------------------------------------------------------
// Bucket refine: one block per bucket; LDS counting sort of 128 local dsts.
// ---------------------------------------------------------------------------
__global__ __launch_bounds__(256) void bucket_refine(
    const int2* __restrict__ brec,
    const int* __restrict__ off_b,      // [NBK+1]
    int* __restrict__ node_off,         // [3N+1]
    int2* __restrict__ pairs)
{
    __shared__ int hist[128];
    __shared__ int curls[128];
    const int t = threadIdx.x;
    const int bk = blockIdx.x;
    const int s = bk / NB;
    const int b = bk - s * NB;
    const int n0 = b << 7;
    const int beg = off_b[bk];
    const int end = off_b[bk + 1];

    if (bk == 0 && t == 0) node_off[3 * NN] = 3 * EE;
    if (t < 128) hist[t] = 0;
    __syncthreads();

    for (int p = beg + t; p < end; p += 256)
        atomicAdd(&hist[(brec[p].x >> 17) & 127], 1);
    __syncthreads();

    int cnt = (t < 128) ? hist[t] : 0;
    #pragma unroll
    for (int o = 1; o < 128; o <<= 1) {
        int add = (t < 128 && t >= o) ? hist[t - o] : 0;
        __syncthreads();
        if (t < 128) hist[t] += add;
        __syncthreads();
    }
    if (t < 128) {
        int excl = beg + hist[t] - cnt;
        curls[t] = excl;
        if (n0 + t < NN) node_off[s * NN + n0 + t] = excl;
    }
    __syncthreads();

    for (int p = beg + t; p < end; p += 256) {
        int2 r = brec[p];
        int pos = atomicAdd(&curls[(r.x >> 17) & 127], 1);
        pairs[pos] = make_int2(r.x & 0x1FFFF, r.y);
    }
}

// ---------------------------------------------------------------------------
// Segmented gather, scalarized: wid forced wave-uniform via readfirstlane so
// off[wid] / pairs[p] become s_loads (scalar pipe); h addressed as uniform
// SGPR base + 32-bit offset ((src<<6)|lane). Per edge: ~3 VALU + 1 VMEM.
// ---------------------------------------------------------------------------
__global__ __launch_bounds__(256) void ufg_gather(
    const __hip_bfloat16* __restrict__ h,   // [N][64] bf16
    const int* __restrict__ off,            // [3N+1]
    const int2* __restrict__ pairs,         // [3E]
    const float* __restrict__ f1, const float* __restrict__ f2,
    const float* __restrict__ f3,
    __hip_bfloat16* __restrict__ agg)       // [N][192] bf16
{
    const unsigned lane = threadIdx.x & 63;
    int wid0 = blockIdx.x * 4 + (threadIdx.x >> 6);
    const int wid = __builtin_amdgcn_readfirstlane(wid0);   // wave-uniform
    if (wid >= 3 * NN) return;
    const int s = wid / NN;
    const int n = wid - s * NN;

    const float* fp = (s == 0) ? f1 : (s == 1) ? f2 : f3;
    const float fv = fp[lane];

    const int beg = off[wid];       // s_load
    const int end = off[wid + 1];   // s_load

    float acc0 = 0.f, acc1 = 0.f;
    int p = beg;

    for (; p + 8 <= end; p += 8) {
        int2 q0 = pairs[p + 0];     // s_load_dwordx2 (uniform)
        int2 q1 = pairs[p + 1];
        int2 q2 = pairs[p + 2];
        int2 q3 = pairs[p + 3];
        int2 q4 = pairs[p + 4];
        int2 q5 = pairs[p + 5];
        int2 q6 = pairs[p + 6];
        int2 q7 = pairs[p + 7];
        float v0 = __bfloat162float(h[((unsigned)q0.x << 6) | lane]);
        float v1 = __bfloat162float(h[((unsigned)q1.x << 6) | lane]);
        float v2 = __bfloat162float(h[((unsigned)q2.x << 6) | lane]);
        float v3 = __bfloat162float(h[((unsigned)q3.x << 6) | lane]);
        float v4 = __bfloat162float(h[((unsigned)q4.x << 6) | lane]);
        float v5 = __bfloat162float(h[((unsigned)q5.x << 6) | lane]);
        float v6 = __bfloat162float(h[((unsigned)q6.x << 6) | lane]);
        float v7 = __bfloat162float(h[((unsigned)q7.x << 6) | lane]);
        acc0 = fmaf(__int_as_float(q0.y), v0, acc0);
        acc1 = fmaf(__int_as_float(q1.y), v1, acc1);
        acc0 = fmaf(__int_as_float(q2.y), v2, acc0);
        acc1 = fmaf(__int_as_float(q3.y), v3, acc1);
        acc0 = fmaf(__int_as_float(q4.y), v4, acc0);
        acc1 = fmaf(__int_as_float(q5.y), v5, acc1);
        acc0 = fmaf(__int_as_float(q6.y), v6, acc0);
        acc1 = fmaf(__int_as_float(q7.y), v7, acc1);
    }
    if (p + 4 <= end) {
        int2 q0 = pairs[p + 0];
        int2 q1 = pairs[p + 1];
        int2 q2 = pairs[p + 2];
        int2 q3 = pairs[p + 3];
        float v0 = __bfloat162float(h[((unsigned)q0.x << 6) | lane]);
        float v1 = __bfloat162float(h[((unsigned)q1.x << 6) | lane]);
        float v2 = __bfloat162float(h[((unsigned)q2.x << 6) | lane]);
        float v3 = __bfloat162float(h[((unsigned)q3.x << 6) | lane]);
        acc0 = fmaf(__int_as_float(q0.y), v0, acc0);
        acc1 = fmaf(__int_as_float(q1.y), v1, acc1);
        acc0 = fmaf(__int_as_float(q2.y), v2, acc0);
        acc1 = fmaf(__int_as_float(q3.y), v3, acc1);
        p += 4;
    }
    if (p + 2 <= end) {
        int2 q0 = pairs[p + 0];
        int2 q1 = pairs[p + 1];
        float v0 = __bfloat162float(h[((unsigned)q0.x << 6) | lane]);
        float v1 = __bfloat162float(h[((unsigned)q1.x << 6) | lane]);
        acc0 = fmaf(__int_as_float(q0.y), v0, acc0);
        acc1 = fmaf(__int_as_float(q1.y), v1, acc1);
        p += 2;
    }
    if (p < end) {
        int2 q = pairs[p];
        acc0 = fmaf(__int_as_float(q.y),
                    __bfloat162float(h[((unsigned)q.x << 6) | lane]), acc0);
    }

    agg[(size_t)n * 192 + s * 64 + lane] =
        __float2bfloat16((acc0 + acc1) * fv);
}

// ---------------------------------------------------------------------------
// mlp1 + log_softmax, tiled: 64 rows x 40 cols (padded to 64) per block.
// A is bf16 [N][192], relu fused in staging.
// ---------------------------------------------------------------------------
__global__ __launch_bounds__(256) void gemm40_softmax(
    const __hip_bfloat16* __restrict__ A, // [N][192] bf16
    const float* __restrict__ B,          // [192][40]
    const float* __restrict__ bias,       // [40]
    float* __restrict__ out,              // [N][40]
    int nrows)
{
    __shared__ float As[32][68];
    __shared__ float Bs[32][64];

    const int tid = threadIdx.x;
    const int tx = tid & 15;
    const int ty = tid >> 4;
    const int row0 = blockIdx.x * 64;

    float acc[4][4] = {{0.f, 0.f, 0.f, 0.f}, {0.f, 0.f, 0.f, 0.f},
                       {0.f, 0.f, 0.f, 0.f}, {0.f, 0.f, 0.f, 0.f}};

    const int r = tid >> 2;
    const int koff = (tid & 3) * 8;
    const bool rowok = (row0 + r) < nrows;

    for (int k0 = 0; k0 < 192; k0 += 32) {
        float av[8];
        const __hip_bfloat16* ap = A + (size_t)(row0 + r) * 192 + (k0 + koff);
        if (rowok) {
            uint4 u = *(const uint4*)ap;     // 8 bf16
            av[0] = __uint_as_float(u.x << 16);
            av[1] = __uint_as_float(u.x & 0xFFFF0000u);
            av[2] = __uint_as_float(u.y << 16);
            av[3] = __uint_as_float(u.y & 0xFFFF0000u);
            av[4] = __uint_as_float(u.z << 16);
            av[5] = __uint_as_float(u.z & 0xFFFF0000u);
            av[6] = __uint_as_float(u.w << 16);
            av[7] = __uint_as_float(u.w & 0xFFFF0000u);
        } else {
            #pragma unroll
            for (int j = 0; j < 8; ++j) av[j] = 0.f;
        }
        #pragma unroll
        for (int j = 0; j < 8; ++j) As[koff + j][r] = fmaxf(av[j], 0.f);

        {
            int flat = tid * 8;
            int kk = flat >> 6;
            int c0 = flat & 63;
            #pragma unroll
            for (int j = 0; j < 8; ++j) {
                int cc = c0 + j;
                Bs[kk][cc] = (cc < 40) ? B[(size_t)(k0 + kk) * 40 + cc] : 0.f;
            }
        }
        __syncthreads();

        #pragma unroll
        for (int k = 0; k < 32; ++k) {
            float4 a = *(const float4*)&As[k][ty * 4];
            float4 b = *(const float4*)&Bs[k][tx * 4];
            acc[0][0] = fmaf(a.x, b.x, acc[0][0]);
            acc[0][1] = fmaf(a.x, b.y, acc[0][1]);
            acc[0][2] = fmaf(a.x, b.z, acc[0][2]);
            acc[0][3] = fmaf(a.x, b.w, acc[0][3]);
            acc[1][0] = fmaf(a.y, b.x, acc[1][0]);
            acc[1][1] = fmaf(a.y, b.y, acc[1][1]);
            acc[1][2] = fmaf(a.y, b.z, acc[1][2]);
            acc[1][3] = fmaf(a.y, b.w, acc[1][3]);
            acc[2][0] = fmaf(a.z, b.x, acc[2][0]);
            acc[2][1] = fmaf(a.z, b.y, acc[2][1]);
            acc[2][2] = fmaf(a.z, b.z, acc[2][2]);
            acc[2][3] = fmaf(a.z, b.w, acc[2][3]);
            acc[3][0] = fmaf(a.w, b.x, acc[3][0]);
            acc[3][1] = fmaf(a.w, b.y, acc[3][1]);
            acc[3][2] = fmaf(a.w, b.z, acc[3][2]);
            acc[3][3] = fmaf(a.w, b.w, acc[3][3]);
        }
        __syncthreads();
    }

    float bv[4];
    #pragma unroll
    for (int j = 0; j < 4; ++j) {
        int cc = tx * 4 + j;
        bv[j] = (cc < 40) ? bias[cc] : 0.f;
    }
    const bool colok = (tx < 10);

    #pragma unroll
    for (int i = 0; i < 4; ++i) {
        float v0 = colok ? acc[i][0] + bv[0] : -1e30f;
        float v1 = colok ? acc[i][1] + bv[1] : -1e30f;
        float v2 = colok ? acc[i][2] + bv[2] : -1e30f;
        float v3 = colok ? acc[i][3] + bv[3] : -1e30f;

        float mx = fmaxf(fmaxf(v0, v1), fmaxf(v2, v3));
        #pragma unroll
        for (int o = 1; o < 16; o <<= 1)
            mx = fmaxf(mx, __shfl_xor(mx, o, 64));

        float s = __expf(v0 - mx) + __expf(v1 - mx) +
                  __expf(v2 - mx) + __expf(v3 - mx);
        #pragma unroll
        for (int o = 1; o < 16; o <<= 1)
            s += __shfl_xor(s, o, 64);

        int rr = row0 + ty * 4 + i;
        if (rr < nrows && colok) {
            float ls = mx + __logf(s);
            *(float4*)(out + (size_t)rr * 40 + tx * 4) =
                make_float4(v0 - ls, v1 - ls, v2 - ls, v3 - ls);
        }
    }
}

// ---------------------------------------------------------------------------
extern "C" void kernel_launch(void* const* d_in, const int* in_sizes, int n_in,
                              void* d_out, int out_size, void* d_ws, size_t ws_size,
                              hipStream_t stream)
{
    const float* x    = (const float*)d_in[0];
    const int*   ei1  = (const int*)d_in[1];
    const float* ea1  = (const float*)d_in[2];
    const int*   ei2  = (const int*)d_in[3];
    const float* ea2  = (const float*)d_in[4];
    const int*   ei3  = (const int*)d_in[5];
    const float* ea3  = (const float*)d_in[6];
    const float* W1   = (const float*)d_in[7];
    const float* b1   = (const float*)d_in[8];
    const float* f1_1 = (const float*)d_in[9];
    const float* f2_1 = (const float*)d_in[10];
    const float* f1_2 = (const float*)d_in[11];
    const float* f2_2 = (const float*)d_in[12];
    const float* f1_3 = (const float*)d_in[13];
    const float* f2_3 = (const float*)d_in[14];
    const float* Wm2  = (const float*)d_in[15];
    const float* bm2  = (const float*)d_in[16];
    const float* Wm1  = (const float*)d_in[17];
    const float* bm1  = (const float*)d_in[18];
    float* out = (float*)d_out;

    // ws layout. agg is bf16 [N][192]; brec (24 MB) aliases it.
    __hip_bfloat16* agg = (__hip_bfloat16*)d_ws;             // N*192 bf16
    int2*  brec = (int2*)d_ws;                               // 3E int2 (alias)
    char*  base = (char*)d_ws + (size_t)NN * 192 * 2;
    __hip_bfloat16* hbuf = (__hip_bfloat16*)base;            // N*64 bf16
    int*   cnt  = (int*)(base + (size_t)NN * 64 * 2);        // M2
    int*   offp = cnt + M2;                                  // M2
    int*   part = offp + M2;                                 // 512
    int*   off_b = part + 512;                               // NBK+1 (+pad)
    int*   node_off = off_b + NBK + 2;                       // 3N+1 (+pad)
    int2*  pairs = (int2*)(node_off + 3 * NN + 2);           // 3E int2

    const int gemm_grid = (NN + 63) / 64;
    const int P = (M2 + 1023) / 1024;    // 294

    // ---- dst-sort edges: atomic-free radix partition + per-bucket refine
    part_count<<<NBLK_P, 1024, 0, stream>>>(ei1, ei2, ei3, cnt);
    scan_a<<<P, 1024, 0, stream>>>(cnt, offp, part, M2);
    scan_b<<<1, 512, 0, stream>>>(part, P);
    scan_c<<<(M2 + 255) / 256, 256, 0, stream>>>(offp, off_b, part, M2);
    part_scatter<<<NBLK_P, 1024, 0, stream>>>(ei1, ea1, ei2, ea2, ei3, ea3,
                                              offp, brec);
    bucket_refine<<<NBK, 256, 0, stream>>>(brec, off_b, node_off, pairs);

    // ---- block 1 ----
    gemm_n64<FF, false, false, true><<<gemm_grid, 256, 0, stream>>>(
        x, W1, b1, hbuf, NN);
    ufg_gather<<<(3 * NN + 3) / 4, 256, 0, stream>>>(hbuf, node_off, pairs,
                                                     f1_1, f1_2, f1_3, agg);
    gemm_n64<192, true, true, true><<<gemm_grid, 256, 0, stream>>>(
        agg, Wm2, bm2, hbuf, NN);

    // ---- block 2 ----
    ufg_gather<<<(3 * NN + 3) / 4, 256, 0, stream>>>(hbuf, node_off, pairs,
                                                     f2_1, f2_2, f2_3, agg);
    gemm40_softmax<<<gemm_grid, 256, 0, stream>>>(agg, Wm1, bm1, out, NN);
}

// Round 11
// 457.392 us; speedup vs baseline: 1.2169x; 1.0511x over previous
//
#include <hip/hip_runtime.h>
#include <hip/hip_bf16.h>

#define NN 100000
#define FF 500
#define HH 64
#define CC 40
#define EE 1000000
#define NB 782            // buckets per scale: ceil(100000/128)
#define NBK 2346          // 3*NB
#define NBLK_P 128        // partition blocks
#define M2 (NBK * NBLK_P) // 300288 counters

typedef __attribute__((ext_vector_type(8))) short short8v;   // 8 bf16
typedef __attribute__((ext_vector_type(4))) float f32x4;

// ---------------------------------------------------------------------------
// W1 -> W1t: [500][64] f32 -> [64][512] bf16 (transposed, k zero-padded)
// ---------------------------------------------------------------------------
__global__ __launch_bounds__(256) void build_w1t(
    const float* __restrict__ W1, __hip_bfloat16* __restrict__ W1t)
{
    int idx = blockIdx.x * 256 + threadIdx.x;
    if (idx >= 64 * 512) return;
    int col = idx >> 9;
    int k = idx & 511;
    W1t[idx] = (k < FF) ? __float2bfloat16(W1[(size_t)k * 64 + col])
                        : __float2bfloat16(0.f);
}

// ---------------------------------------------------------------------------
// gemm1 via MFMA: H[N][64] = bf16(X[N][500] @ W1[500][64] + b1)
// 128x64 tile / block, 4 waves, wave tile 32x64 (2x4 16x16x32 frags).
// A staged f32->bf16 inline; B from pre-built W1t (contiguous-k frags).
// ---------------------------------------------------------------------------
__global__ __launch_bounds__(256) void gemm1_mfma(
    const float* __restrict__ X,
    const __hip_bfloat16* __restrict__ W1t,   // [64][512]
    const float* __restrict__ bias,           // [64]
    __hip_bfloat16* __restrict__ H,           // [N][64]
    int nrows)
{
    __shared__ __hip_bfloat16 As[128][40];    // rows x k (pad 32->40, 80B)
    __shared__ __hip_bfloat16 Bs[64][40];     // cols x k

    const int t = threadIdx.x;
    const int lane = t & 63;
    const int w = t >> 6;
    const int row0 = blockIdx.x * 128;
    const int wrow = w * 32;
    const int kg = lane >> 4;     // 0..3 -> k-offset kg*8
    const int lr = lane & 15;

    f32x4 acc[2][4] = {};

    const int arow = t >> 1;      // 0..127
    const int akh = t & 1;        // k-half (16 f32)
    const int bcol = t >> 2;      // 0..63
    const int bkq = t & 3;        // 8 k each

    for (int k0 = 0; k0 < FF; k0 += 32) {
        // ---- stage A (f32 -> bf16)
        {
            int grow = row0 + arow;
            int gr = grow < nrows ? grow : nrows - 1;
            const float* xp = X + (size_t)gr * FF + k0 + akh * 16;
            float v[16];
            if (k0 + 32 <= FF) {
                float4 a0 = *(const float4*)(xp);
                float4 a1 = *(const float4*)(xp + 4);
                float4 a2 = *(const float4*)(xp + 8);
                float4 a3 = *(const float4*)(xp + 12);
                v[0]=a0.x; v[1]=a0.y; v[2]=a0.z; v[3]=a0.w;
                v[4]=a1.x; v[5]=a1.y; v[6]=a1.z; v[7]=a1.w;
                v[8]=a2.x; v[9]=a2.y; v[10]=a2.z; v[11]=a2.w;
                v[12]=a3.x; v[13]=a3.y; v[14]=a3.z; v[15]=a3.w;
            } else {
                #pragma unroll
                for (int j = 0; j < 16; ++j) {
                    int kk = k0 + akh * 16 + j;
                    v[j] = (kk < FF) ? xp[j] : 0.f;
                }
            }
            unsigned q[8];
            #pragma unroll
            for (int i = 0; i < 8; ++i) {
                __hip_bfloat162 pp =
                    __float22bfloat162_rn(make_float2(v[2*i], v[2*i+1]));
                q[i] = *(unsigned*)&pp;
            }
            *(uint4*)&As[arow][akh * 16]     = make_uint4(q[0],q[1],q[2],q[3]);
            *(uint4*)&As[arow][akh * 16 + 8] = make_uint4(q[4],q[5],q[6],q[7]);
        }
        // ---- stage B (bf16 copy from W1t)
        *(uint4*)&Bs[bcol][bkq * 8] =
            *(const uint4*)(W1t + (size_t)bcol * 512 + k0 + bkq * 8);
        __syncthreads();

        // ---- fragments + 8 MFMAs (full BK=32 per call)
        short8v a0 = *(const short8v*)&As[wrow + lr][kg * 8];
        short8v a1 = *(const short8v*)&As[wrow + 16 + lr][kg * 8];
        short8v b0 = *(const short8v*)&Bs[lr][kg * 8];
        short8v b1 = *(const short8v*)&Bs[16 + lr][kg * 8];
        short8v b2 = *(const short8v*)&Bs[32 + lr][kg * 8];
        short8v b3 = *(const short8v*)&Bs[48 + lr][kg * 8];
        acc[0][0] = __builtin_amdgcn_mfma_f32_16x16x32_bf16(a0, b0, acc[0][0], 0, 0, 0);
        acc[0][1] = __builtin_amdgcn_mfma_f32_16x16x32_bf16(a0, b1, acc[0][1], 0, 0, 0);
        acc[0][2] = __builtin_amdgcn_mfma_f32_16x16x32_bf16(a0, b2, acc[0][2], 0, 0, 0);
        acc[0][3] = __builtin_amdgcn_mfma_f32_16x16x32_bf16(a0, b3, acc[0][3], 0, 0, 0);
        acc[1][0] = __builtin_amdgcn_mfma_f32_16x16x32_bf16(a1, b0, acc[1][0], 0, 0, 0);
        acc[1][1] = __builtin_amdgcn_mfma_f32_16x16x32_bf16(a1, b1, acc[1][1], 0, 0, 0);
        acc[1][2] = __builtin_amdgcn_mfma_f32_16x16x32_bf16(a1, b2, acc[1][2], 0, 0, 0);
        acc[1][3] = __builtin_amdgcn_mfma_f32_16x16x32_bf16(a1, b3, acc[1][3], 0, 0, 0);
        __syncthreads();
    }

    // ---- epilogue: + bias, bf16 store
    float bv[4];
    #pragma unroll
    for (int n = 0; n < 4; ++n) bv[n] = bias[n * 16 + lr];

    #pragma unroll
    for (int m = 0; m < 2; ++m) {
        #pragma unroll
        for (int n = 0; n < 4; ++n) {
            #pragma unroll
            for (int r = 0; r < 4; ++r) {
                int row = row0 + wrow + m * 16 + kg * 4 + r;
                if (row < nrows)
                    H[(size_t)row * 64 + n * 16 + lr] =
                        __float2bfloat16(acc[m][n][r] + bv[n]);
            }
        }
    }
}

// ---------------------------------------------------------------------------
// GEMM: C[N][64] = (opt relu)(A[N][K]) @ B[K][64] + bias[64]   (f32 FMA path,
// used for mlp2 K=192). ABF16: A bf16. OBF16: output bf16.
// ---------------------------------------------------------------------------
template <int K, bool RELU, bool ABF16, bool OBF16>
__global__ __launch_bounds__(256) void gemm_n64(
    const void* __restrict__ Av,
    const float* __restrict__ B,
    const float* __restrict__ bias,
    void* __restrict__ Cv,
    int nrows)
{
    __shared__ float As[32][68];
    __shared__ float Bs[32][64];

    const int tid = threadIdx.x;
    const int tx = tid & 15;
    const int ty = tid >> 4;
    const int row0 = blockIdx.x * 64;

    float acc[4][4] = {{0.f, 0.f, 0.f, 0.f}, {0.f, 0.f, 0.f, 0.f},
                       {0.f, 0.f, 0.f, 0.f}, {0.f, 0.f, 0.f, 0.f}};

    const int r = tid >> 2;
    const int koff = (tid & 3) * 8;
    const bool rowok = (row0 + r) < nrows;

    for (int k0 = 0; k0 < K; k0 += 32) {
        float av[8];
        if (ABF16) {
            const __hip_bfloat16* ap =
                (const __hip_bfloat16*)Av + (size_t)(row0 + r) * K + (k0 + koff);
            if (rowok) {
                uint4 u = *(const uint4*)ap;
                av[0] = __uint_as_float(u.x << 16);
                av[1] = __uint_as_float(u.x & 0xFFFF0000u);
                av[2] = __uint_as_float(u.y << 16);
                av[3] = __uint_as_float(u.y & 0xFFFF0000u);
                av[4] = __uint_as_float(u.z << 16);
                av[5] = __uint_as_float(u.z & 0xFFFF0000u);
                av[6] = __uint_as_float(u.w << 16);
                av[7] = __uint_as_float(u.w & 0xFFFF0000u);
            } else {
                #pragma unroll
                for (int j = 0; j < 8; ++j) av[j] = 0.f;
            }
        } else {
            const float* ap = (const float*)Av + (size_t)(row0 + r) * K + (k0 + koff);
            if (rowok && ((K % 32 == 0) || (k0 + 32 <= K))) {
                float4 v0 = *(const float4*)(ap);
                float4 v1 = *(const float4*)(ap + 4);
                av[0] = v0.x; av[1] = v0.y; av[2] = v0.z; av[3] = v0.w;
                av[4] = v1.x; av[5] = v1.y; av[6] = v1.z; av[7] = v1.w;
            } else {
                #pragma unroll
                for (int j = 0; j < 8; ++j) {
                    int kk = k0 + koff + j;
                    av[j] = (rowok && kk < K) ? ap[j] : 0.f;
                }
            }
        }
        if (RELU) {
            #pragma unroll
            for (int j = 0; j < 8; ++j) av[j] = fmaxf(av[j], 0.f);
        }
        #pragma unroll
        for (int j = 0; j < 8; ++j) As[koff + j][r] = av[j];

        {
            int flat = tid * 8;
            int kk = flat >> 6;
            int c = flat & 63;
            float4 b0, b1v;
            if (k0 + kk < K) {
                b0 = *(const float4*)(B + (size_t)(k0 + kk) * 64 + c);
                b1v = *(const float4*)(B + (size_t)(k0 + kk) * 64 + c + 4);
            } else {
                b0 = make_float4(0.f, 0.f, 0.f, 0.f);
                b1v = b0;
            }
            *(float4*)&Bs[kk][c] = b0;
            *(float4*)&Bs[kk][c + 4] = b1v;
        }
        __syncthreads();

        #pragma unroll
        for (int k = 0; k < 32; ++k) {
            float4 a = *(const float4*)&As[k][ty * 4];
            float4 b = *(const float4*)&Bs[k][tx * 4];
            acc[0][0] = fmaf(a.x, b.x, acc[0][0]);
            acc[0][1] = fmaf(a.x, b.y, acc[0][1]);
            acc[0][2] = fmaf(a.x, b.z, acc[0][2]);
            acc[0][3] = fmaf(a.x, b.w, acc[0][3]);
            acc[1][0] = fmaf(a.y, b.x, acc[1][0]);
            acc[1][1] = fmaf(a.y, b.y, acc[1][1]);
            acc[1][2] = fmaf(a.y, b.z, acc[1][2]);
            acc[1][3] = fmaf(a.y, b.w, acc[1][3]);
            acc[2][0] = fmaf(a.z, b.x, acc[2][0]);
            acc[2][1] = fmaf(a.z, b.y, acc[2][1]);
            acc[2][2] = fmaf(a.z, b.z, acc[2][2]);
            acc[2][3] = fmaf(a.z, b.w, acc[2][3]);
            acc[3][0] = fmaf(a.w, b.x, acc[3][0]);
            acc[3][1] = fmaf(a.w, b.y, acc[3][1]);
            acc[3][2] = fmaf(a.w, b.z, acc[3][2]);
            acc[3][3] = fmaf(a.w, b.w, acc[3][3]);
        }
        __syncthreads();
    }

    float4 bv = *(const float4*)(bias + tx * 4);
    #pragma unroll
    for (int i = 0; i < 4; ++i) {
        int rr = row0 + ty * 4 + i;
        if (rr < nrows) {
            float o0 = acc[i][0] + bv.x;
            float o1 = acc[i][1] + bv.y;
            float o2 = acc[i][2] + bv.z;
            float o3 = acc[i][3] + bv.w;
            if (OBF16) {
                __hip_bfloat16* Cb = (__hip_bfloat16*)Cv;
                __hip_bfloat162 lo = __float22bfloat162_rn(make_float2(o0, o1));
                __hip_bfloat162 hi = __float22bfloat162_rn(make_float2(o2, o3));
                *(__hip_bfloat162*)(Cb + (size_t)rr * 64 + tx * 4) = lo;
                *(__hip_bfloat162*)(Cb + (size_t)rr * 64 + tx * 4 + 2) = hi;
            } else {
                float* C = (float*)Cv;
                *(float4*)(C + (size_t)rr * 64 + tx * 4) =
                    make_float4(o0, o1, o2, o3);
            }
        }
    }
}

// ---------------------------------------------------------------------------
// Radix partition pass 1
// ---------------------------------------------------------------------------
__global__ __launch_bounds__(1024) void part_count(
    const int* __restrict__ ei1, const int* __restrict__ ei2,
    const int* __restrict__ ei3, int* __restrict__ cnt)
{
    __shared__ int lc[NBK];
    const int t = threadIdx.x;
    for (int j = t; j < NBK; j += 1024) lc[j] = 0;
    __syncthreads();

    const int chunk = (3 * EE + NBLK_P - 1) / NBLK_P;
    const int b0 = blockIdx.x * chunk;
    int b1 = b0 + chunk;
    if (b1 > 3 * EE) b1 = 3 * EE;

    for (int i = b0 + t; i < b1; i += 1024) {
        int s = i / EE;
        int e = i - s * EE;
        const int* ei = (s == 0) ? ei1 : (s == 1) ? ei2 : ei3;
        atomicAdd(&lc[s * NB + (ei[EE + e] >> 7)], 1);
    }
    __syncthreads();
    for (int j = t; j < NBK; j += 1024)
        cnt[j * NBLK_P + blockIdx.x] = lc[j];
}

__global__ __launch_bounds__(1024) void scan_a(
    const int* __restrict__ cnt, int* __restrict__ off,
    int* __restrict__ partials, int M)
{
    __shared__ int sh[1024];
    int t = threadIdx.x;
    int i = blockIdx.x * 1024 + t;
    int v = (i < M) ? cnt[i] : 0;
    sh[t] = v;
    __syncthreads();
    #pragma unroll
    for (int o = 1; o < 1024; o <<= 1) {
        int add = (t >= o) ? sh[t - o] : 0;
        __syncthreads();
        sh[t] += add;
        __syncthreads();
    }
    if (i < M) off[i] = sh[t] - v;
    if (t == 1023) partials[blockIdx.x] = sh[1023];
}

__global__ __launch_bounds__(512) void scan_b(int* __restrict__ partials, int P)
{
    __shared__ int sh[512];
    int t = threadIdx.x;
    int v = (t < P) ? partials[t] : 0;
    sh[t] = v;
    __syncthreads();
    #pragma unroll
    for (int o = 1; o < 512; o <<= 1) {
        int add = (t >= o) ? sh[t - o] : 0;
        __syncthreads();
        sh[t] += add;
        __syncthreads();
    }
    if (t < P) partials[t] = sh[t] - v;
}

__global__ __launch_bounds__(256) void scan_c(
    int* __restrict__ off, int* __restrict__ off_b,
    const int* __restrict__ partials, int M)
{
    int i = blockIdx.x * 256 + threadIdx.x;
    if (i < M) {
        int v = off[i] + partials[i >> 10];
        off[i] = v;
        if ((i & (NBLK_P - 1)) == 0) off_b[i / NBLK_P] = v;
    }
    if (i == 0) off_b[NBK] = 3 * EE;
}

__global__ __launch_bounds__(1024) void part_scatter(
    const int* __restrict__ ei1, const float* __restrict__ ea1,
    const int* __restrict__ ei2, const float* __restrict__ ea2,
    const int* __restrict__ ei3, const float* __restrict__ ea3,
    const int* __restrict__ offp, int2* __restrict__ brec)
{
    __shared__ int lcur[NBK];
    const int t = threadIdx.x;
    for (int j = t; j < NBK; j += 1024)
        lcur[j] = offp[j * NBLK_P + blockIdx.x];
    __syncthreads();

    const int chunk = (3 * EE + NBLK_P - 1) / NBLK_P;
    const int b0 = blockIdx.x * chunk;
    int b1 = b0 + chunk;
    if (b1 > 3 * EE) b1 = 3 * EE;

    for (int i = b0 + t; i < b1; i += 1024) {
        int s = i / EE;
        int e = i - s * EE;
        const int* ei = (s == 0) ? ei1 : (s == 1) ? ei2 : ei3;
        const float* ea = (s == 0) ? ea1 : (s == 1) ? ea2 : ea3;
        int src = ei[e];
        int dst = ei[EE + e];
        float w = ea[e];
        int pos = atomicAdd(&lcur[s * NB + (dst >> 7)], 1);
        brec[pos] = make_int2(src | ((dst & 127) << 17), __float_as_int(w));
    }
}

__global__ __launch_bounds__(256) void bucket_refine(
    const int2* __restrict__ brec,
    const int* __restrict__ off_b,
    int* __restrict__ node_off,
    int2* __restrict__ pairs)
{
    __shared__ int hist[128];
    __shared__ int curls[128];
    const int t = threadIdx.x;
    const int bk = blockIdx.x;
    const int s = bk / NB;
    const int b = bk - s * NB;
    const int n0 = b << 7;
    const int beg = off_b[bk];
    const int end = off_b[bk + 1];

    if (bk == 0 && t == 0) node_off[3 * NN] = 3 * EE;
    if (t < 128) hist[t] = 0;
    __syncthreads();

    for (int p = beg + t; p < end; p += 256)
        atomicAdd(&hist[(brec[p].x >> 17) & 127], 1);
    __syncthreads();

    int cnt = (t < 128) ? hist[t] : 0;
    #pragma unroll
    for (int o = 1; o < 128; o <<= 1) {
        int add = (t < 128 && t >= o) ? hist[t - o] : 0;
        __syncthreads();
        if (t < 128) hist[t] += add;
        __syncthreads();
    }
    if (t < 128) {
        int excl = beg + hist[t] - cnt;
        curls[t] = excl;
        if (n0 + t < NN) node_off[s * NN + n0 + t] = excl;
    }
    __syncthreads();

    for (int p = beg + t; p < end; p += 256) {
        int2 r = brec[p];
        int pos = atomicAdd(&curls[(r.x >> 17) & 127], 1);
        pairs[pos] = make_int2(r.x & 0x1FFFF, r.y);
    }
}

// ---------------------------------------------------------------------------
// Segmented gather (scalarized, round-10 structure)
// ---------------------------------------------------------------------------
__global__ __launch_bounds__(256) void ufg_gather(
    const __hip_bfloat16* __restrict__ h,
    const int* __restrict__ off,
    const int2* __restrict__ pairs,
    const float* __restrict__ f1, const float* __restrict__ f2,
    const float* __restrict__ f3,
    __hip_bfloat16* __restrict__ agg)
{
    const unsigned lane = threadIdx.x & 63;
    int wid0 = blockIdx.x * 4 + (threadIdx.x >> 6);
    const int wid = __builtin_amdgcn_readfirstlane(wid0);
    if (wid >= 3 * NN) return;
    const int s = wid / NN;
    const int n = wid - s * NN;

    const float* fp = (s == 0) ? f1 : (s == 1) ? f2 : f3;
    const float fv = fp[lane];

    const int beg = off[wid];
    const int end = off[wid + 1];

    float acc0 = 0.f, acc1 = 0.f;
    int p = beg;

    for (; p + 8 <= end; p += 8) {
        int2 q0 = pairs[p + 0];
        int2 q1 = pairs[p + 1];
        int2 q2 = pairs[p + 2];
        int2 q3 = pairs[p + 3];
        int2 q4 = pairs[p + 4];
        int2 q5 = pairs[p + 5];
        int2 q6 = pairs[p + 6];
        int2 q7 = pairs[p + 7];
        float v0 = __bfloat162float(h[((unsigned)q0.x << 6) | lane]);
        float v1 = __bfloat162float(h[((unsigned)q1.x << 6) | lane]);
        float v2 = __bfloat162float(h[((unsigned)q2.x << 6) | lane]);
        float v3 = __bfloat162float(h[((unsigned)q3.x << 6) | lane]);
        float v4 = __bfloat162float(h[((unsigned)q4.x << 6) | lane]);
        float v5 = __bfloat162float(h[((unsigned)q5.x << 6) | lane]);
        float v6 = __bfloat162float(h[((unsigned)q6.x << 6) | lane]);
        float v7 = __bfloat162float(h[((unsigned)q7.x << 6) | lane]);
        acc0 = fmaf(__int_as_float(q0.y), v0, acc0);
        acc1 = fmaf(__int_as_float(q1.y), v1, acc1);
        acc0 = fmaf(__int_as_float(q2.y), v2, acc0);
        acc1 = fmaf(__int_as_float(q3.y), v3, acc1);
        acc0 = fmaf(__int_as_float(q4.y), v4, acc0);
        acc1 = fmaf(__int_as_float(q5.y), v5, acc1);
        acc0 = fmaf(__int_as_float(q6.y), v6, acc0);
        acc1 = fmaf(__int_as_float(q7.y), v7, acc1);
    }
    if (p + 4 <= end) {
        int2 q0 = pairs[p + 0];
        int2 q1 = pairs[p + 1];
        int2 q2 = pairs[p + 2];
        int2 q3 = pairs[p + 3];
        float v0 = __bfloat162float(h[((unsigned)q0.x << 6) | lane]);
        float v1 = __bfloat162float(h[((unsigned)q1.x << 6) | lane]);
        float v2 = __bfloat162float(h[((unsigned)q2.x << 6) | lane]);
        float v3 = __bfloat162float(h[((unsigned)q3.x << 6) | lane]);
        acc0 = fmaf(__int_as_float(q0.y), v0, acc0);
        acc1 = fmaf(__int_as_float(q1.y), v1, acc1);
        acc0 = fmaf(__int_as_float(q2.y), v2, acc0);
        acc1 = fmaf(__int_as_float(q3.y), v3, acc1);
        p += 4;
    }
    if (p + 2 <= end) {
        int2 q0 = pairs[p + 0];
        int2 q1 = pairs[p + 1];
        float v0 = __bfloat162float(h[((unsigned)q0.x << 6) | lane]);
        float v1 = __bfloat162float(h[((unsigned)q1.x << 6) | lane]);
        acc0 = fmaf(__int_as_float(q0.y), v0, acc0);
        acc1 = fmaf(__int_as_float(q1.y), v1, acc1);
        p += 2;
    }
    if (p < end) {
        int2 q = pairs[p];
        acc0 = fmaf(__int_as_float(q.y),
                    __bfloat162float(h[((unsigned)q.x << 6) | lane]), acc0);
    }

    agg[(size_t)n * 192 + s * 64 + lane] =
        __float2bfloat16((acc0 + acc1) * fv);
}

// ---------------------------------------------------------------------------
// mlp1 + log_softmax (bf16 A)
// ---------------------------------------------------------------------------
__global__ __launch_bounds__(256) void gemm40_softmax(
    const __hip_bfloat16* __restrict__ A,
    const float* __restrict__ B,
    const float* __restrict__ bias,
    float* __restrict__ out,
    int nrows)
{
    __shared__ float As[32][68];
    __shared__ float Bs[32][64];

    const int tid = threadIdx.x;
    const int tx = tid & 15;
    const int ty = tid >> 4;
    const int row0 = blockIdx.x * 64;

    float acc[4][4] = {{0.f, 0.f, 0.f, 0.f}, {0.f, 0.f, 0.f, 0.f},
                       {0.f, 0.f, 0.f, 0.f}, {0.f, 0.f, 0.f, 0.f}};

    const int r = tid >> 2;
    const int koff = (tid & 3) * 8;
    const bool rowok = (row0 + r) < nrows;

    for (int k0 = 0; k0 < 192; k0 += 32) {
        float av[8];
        const __hip_bfloat16* ap = A + (size_t)(row0 + r) * 192 + (k0 + koff);
        if (rowok) {
            uint4 u = *(const uint4*)ap;
            av[0] = __uint_as_float(u.x << 16);
            av[1] = __uint_as_float(u.x & 0xFFFF0000u);
            av[2] = __uint_as_float(u.y << 16);
            av[3] = __uint_as_float(u.y & 0xFFFF0000u);
            av[4] = __uint_as_float(u.z << 16);
            av[5] = __uint_as_float(u.z & 0xFFFF0000u);
            av[6] = __uint_as_float(u.w << 16);
            av[7] = __uint_as_float(u.w & 0xFFFF0000u);
        } else {
            #pragma unroll
            for (int j = 0; j < 8; ++j) av[j] = 0.f;
        }
        #pragma unroll
        for (int j = 0; j < 8; ++j) As[koff + j][r] = fmaxf(av[j], 0.f);

        {
            int flat = tid * 8;
            int kk = flat >> 6;
            int c0 = flat & 63;
            #pragma unroll
            for (int j = 0; j < 8; ++j) {
                int cc = c0 + j;
                Bs[kk][cc] = (cc < 40) ? B[(size_t)(k0 + kk) * 40 + cc] : 0.f;
            }
        }
        __syncthreads();

        #pragma unroll
        for (int k = 0; k < 32; ++k) {
            float4 a = *(const float4*)&As[k][ty * 4];
            float4 b = *(const float4*)&Bs[k][tx * 4];
            acc[0][0] = fmaf(a.x, b.x, acc[0][0]);
            acc[0][1] = fmaf(a.x, b.y, acc[0][1]);
            acc[0][2] = fmaf(a.x, b.z, acc[0][2]);
            acc[0][3] = fmaf(a.x, b.w, acc[0][3]);
            acc[1][0] = fmaf(a.y, b.x, acc[1][0]);
            acc[1][1] = fmaf(a.y, b.y, acc[1][1]);
            acc[1][2] = fmaf(a.y, b.z, acc[1][2]);
            acc[1][3] = fmaf(a.y, b.w, acc[1][3]);
            acc[2][0] = fmaf(a.z, b.x, acc[2][0]);
            acc[2][1] = fmaf(a.z, b.y, acc[2][1]);
            acc[2][2] = fmaf(a.z, b.z, acc[2][2]);
            acc[2][3] = fmaf(a.z, b.w, acc[2][3]);
            acc[3][0] = fmaf(a.w, b.x, acc[3][0]);
            acc[3][1] = fmaf(a.w, b.y, acc[3][1]);
            acc[3][2] = fmaf(a.w, b.z, acc[3][2]);
            acc[3][3] = fmaf(a.w, b.w, acc[3][3]);
        }
        __syncthreads();
    }

    float bv[4];
    #pragma unroll
    for (int j = 0; j < 4; ++j) {
        int cc = tx * 4 + j;
        bv[j] = (cc < 40) ? bias[cc] : 0.f;
    }
    const bool colok = (tx < 10);

    #pragma unroll
    for (int i = 0; i < 4; ++i) {
        float v0 = colok ? acc[i][0] + bv[0] : -1e30f;
        float v1 = colok ? acc[i][1] + bv[1] : -1e30f;
        float v2 = colok ? acc[i][2] + bv[2] : -1e30f;
        float v3 = colok ? acc[i][3] + bv[3] : -1e30f;

        float mx = fmaxf(fmaxf(v0, v1), fmaxf(v2, v3));
        #pragma unroll
        for (int o = 1; o < 16; o <<= 1)
            mx = fmaxf(mx, __shfl_xor(mx, o, 64));

        float s = __expf(v0 - mx) + __expf(v1 - mx) +
                  __expf(v2 - mx) + __expf(v3 - mx);
        #pragma unroll
        for (int o = 1; o < 16; o <<= 1)
            s += __shfl_xor(s, o, 64);

        int rr = row0 + ty * 4 + i;
        if (rr < nrows && colok) {
            float ls = mx + __logf(s);
            *(float4*)(out + (size_t)rr * 40 + tx * 4) =
                make_float4(v0 - ls, v1 - ls, v2 - ls, v3 - ls);
        }
    }
}

// ---------------------------------------------------------------------------
extern "C" void kernel_launch(void* const* d_in, const int* in_sizes, int n_in,
                              void* d_out, int out_size, void* d_ws, size_t ws_size,
                              hipStream_t stream)
{
    const float* x    = (const float*)d_in[0];
    const int*   ei1  = (const int*)d_in[1];
    const float* ea1  = (const float*)d_in[2];
    const int*   ei2  = (const int*)d_in[3];
    const float* ea2  = (const float*)d_in[4];
    const int*   ei3  = (const int*)d_in[5];
    const float* ea3  = (const float*)d_in[6];
    const float* W1   = (const float*)d_in[7];
    const float* b1   = (const float*)d_in[8];
    const float* f1_1 = (const float*)d_in[9];
    const float* f2_1 = (const float*)d_in[10];
    const float* f1_2 = (const float*)d_in[11];
    const float* f2_2 = (const float*)d_in[12];
    const float* f1_3 = (const float*)d_in[13];
    const float* f2_3 = (const float*)d_in[14];
    const float* Wm2  = (const float*)d_in[15];
    const float* bm2  = (const float*)d_in[16];
    const float* Wm1  = (const float*)d_in[17];
    const float* bm1  = (const float*)d_in[18];
    float* out = (float*)d_out;

    // ws layout. agg bf16 [N][192]; brec aliases it.
    __hip_bfloat16* agg = (__hip_bfloat16*)d_ws;             // N*192 bf16
    int2*  brec = (int2*)d_ws;                               // 3E int2 (alias)
    char*  base = (char*)d_ws + (size_t)NN * 192 * 2;
    __hip_bfloat16* hbuf = (__hip_bfloat16*)base;            // N*64 bf16
    int*   cnt  = (int*)(base + (size_t)NN * 64 * 2);        // M2
    int*   offp = cnt + M2;                                  // M2
    int*   part = offp + M2;                                 // 512
    int*   off_b = part + 512;                               // NBK+1 (+pad)
    int*   node_off = off_b + NBK + 2;                       // 3N+1 (+pad)
    int2*  pairs = (int2*)(node_off + 3 * NN + 2);           // 3E int2
    __hip_bfloat16* w1t = (__hip_bfloat16*)
        (((uintptr_t)(pairs + 3 * EE) + 15) & ~(uintptr_t)15); // 64*512 bf16

    const int gemm_grid = (NN + 63) / 64;
    const int mfma_grid = (NN + 127) / 128;   // 782
    const int P = (M2 + 1023) / 1024;         // 294

    // ---- prep: W1 transpose/convert + dst-sort edges
    build_w1t<<<128, 256, 0, stream>>>(W1, w1t);
    part_count<<<NBLK_P, 1024, 0, stream>>>(ei1, ei2, ei3, cnt);
    scan_a<<<P, 1024, 0, stream>>>(cnt, offp, part, M2);
    scan_b<<<1, 512, 0, stream>>>(part, P);
    scan_c<<<(M2 + 255) / 256, 256, 0, stream>>>(offp, off_b, part, M2);
    part_scatter<<<NBLK_P, 1024, 0, stream>>>(ei1, ea1, ei2, ea2, ei3, ea3,
                                              offp, brec);
    bucket_refine<<<NBK, 256, 0, stream>>>(brec, off_b, node_off, pairs);

    // ---- block 1 ----
    gemm1_mfma<<<mfma_grid, 256, 0, stream>>>(x, w1t, b1, hbuf, NN);
    ufg_gather<<<(3 * NN + 3) / 4, 256, 0, stream>>>(hbuf, node_off, pairs,
                                                     f1_1, f1_2, f1_3, agg);
    gemm_n64<192, true, true, true><<<gemm_grid, 256, 0, stream>>>(
        agg, Wm2, bm2, hbuf, NN);

    // ---- block 2 ----
    ufg_gather<<<(3 * NN + 3) / 4, 256, 0, stream>>>(hbuf, node_off, pairs,
                                                     f2_1, f2_2, f2_3, agg);
    gemm40_softmax<<<gemm_grid, 256, 0, stream>>>(agg, Wm1, bm1, out, NN);
}

// Round 12
// 424.938 us; speedup vs baseline: 1.3098x; 1.0764x over previous
//
#include <hip/hip_runtime.h>
#include <hip/hip_bf16.h>

#define NN 100000
#define FF 500
#define HH 64
#define CC 40
#define EE 1000000
#define NB 782            // buckets per scale: ceil(100000/128)
#define NBK 2346          // 3*NB
#define NBLK_P 256        // partition blocks (256 -> all CUs busy)
#define M2 (NBK * NBLK_P) // 600576 counters

typedef __attribute__((ext_vector_type(8))) short short8v;   // 8 bf16
typedef __attribute__((ext_vector_type(4))) float f32x4;

// relu on 2 packed bf16 (sign-mask select)
__device__ inline unsigned relu2bf16(unsigned u)
{
    unsigned r = (u & 0x00008000u) ? (u & 0xFFFF0000u) : u;
    return (r & 0x80000000u) ? (r & 0x0000FFFFu) : r;
}

// ---------------------------------------------------------------------------
// W1 -> W1t: [500][64] f32 -> [64][512] bf16 (transposed, k zero-padded)
// ---------------------------------------------------------------------------
__global__ __launch_bounds__(256) void build_w1t(
    const float* __restrict__ W1, __hip_bfloat16* __restrict__ W1t)
{
    int idx = blockIdx.x * 256 + threadIdx.x;
    if (idx >= 64 * 512) return;
    int col = idx >> 9;
    int k = idx & 511;
    W1t[idx] = (k < FF) ? __float2bfloat16(W1[(size_t)k * 64 + col])
                        : __float2bfloat16(0.f);
}

// Wm2 -> Wm2t: [192][64] f32 -> [64][192] bf16
__global__ __launch_bounds__(256) void build_wm2t(
    const float* __restrict__ Wm2, __hip_bfloat16* __restrict__ Wm2t)
{
    int idx = blockIdx.x * 256 + threadIdx.x;
    if (idx >= 64 * 192) return;
    int col = idx / 192;
    int k = idx - col * 192;
    Wm2t[idx] = __float2bfloat16(Wm2[(size_t)k * 64 + col]);
}

// ---------------------------------------------------------------------------
// gemm1 via MFMA: H[N][64] = bf16(X[N][500] @ W1[500][64] + b1)
// ---------------------------------------------------------------------------
__global__ __launch_bounds__(256) void gemm1_mfma(
    const float* __restrict__ X,
    const __hip_bfloat16* __restrict__ W1t,   // [64][512]
    const float* __restrict__ bias,           // [64]
    __hip_bfloat16* __restrict__ H,           // [N][64]
    int nrows)
{
    __shared__ __hip_bfloat16 As[128][40];
    __shared__ __hip_bfloat16 Bs[64][40];

    const int t = threadIdx.x;
    const int lane = t & 63;
    const int w = t >> 6;
    const int row0 = blockIdx.x * 128;
    const int wrow = w * 32;
    const int kg = lane >> 4;
    const int lr = lane & 15;

    f32x4 acc[2][4] = {};

    const int arow = t >> 1;
    const int akh = t & 1;
    const int bcol = t >> 2;
    const int bkq = t & 3;

    for (int k0 = 0; k0 < FF; k0 += 32) {
        {
            int grow = row0 + arow;
            int gr = grow < nrows ? grow : nrows - 1;
            const float* xp = X + (size_t)gr * FF + k0 + akh * 16;
            float v[16];
            if (k0 + 32 <= FF) {
                float4 a0 = *(const float4*)(xp);
                float4 a1 = *(const float4*)(xp + 4);
                float4 a2 = *(const float4*)(xp + 8);
                float4 a3 = *(const float4*)(xp + 12);
                v[0]=a0.x; v[1]=a0.y; v[2]=a0.z; v[3]=a0.w;
                v[4]=a1.x; v[5]=a1.y; v[6]=a1.z; v[7]=a1.w;
                v[8]=a2.x; v[9]=a2.y; v[10]=a2.z; v[11]=a2.w;
                v[12]=a3.x; v[13]=a3.y; v[14]=a3.z; v[15]=a3.w;
            } else {
                #pragma unroll
                for (int j = 0; j < 16; ++j) {
                    int kk = k0 + akh * 16 + j;
                    v[j] = (kk < FF) ? xp[j] : 0.f;
                }
            }
            unsigned q[8];
            #pragma unroll
            for (int i = 0; i < 8; ++i) {
                __hip_bfloat162 pp =
                    __float22bfloat162_rn(make_float2(v[2*i], v[2*i+1]));
                q[i] = *(unsigned*)&pp;
            }
            *(uint4*)&As[arow][akh * 16]     = make_uint4(q[0],q[1],q[2],q[3]);
            *(uint4*)&As[arow][akh * 16 + 8] = make_uint4(q[4],q[5],q[6],q[7]);
        }
        *(uint4*)&Bs[bcol][bkq * 8] =
            *(const uint4*)(W1t + (size_t)bcol * 512 + k0 + bkq * 8);
        __syncthreads();

        short8v a0 = *(const short8v*)&As[wrow + lr][kg * 8];
        short8v a1 = *(const short8v*)&As[wrow + 16 + lr][kg * 8];
        short8v b0 = *(const short8v*)&Bs[lr][kg * 8];
        short8v b1 = *(const short8v*)&Bs[16 + lr][kg * 8];
        short8v b2 = *(const short8v*)&Bs[32 + lr][kg * 8];
        short8v b3 = *(const short8v*)&Bs[48 + lr][kg * 8];
        acc[0][0] = __builtin_amdgcn_mfma_f32_16x16x32_bf16(a0, b0, acc[0][0], 0, 0, 0);
        acc[0][1] = __builtin_amdgcn_mfma_f32_16x16x32_bf16(a0, b1, acc[0][1], 0, 0, 0);
        acc[0][2] = __builtin_amdgcn_mfma_f32_16x16x32_bf16(a0, b2, acc[0][2], 0, 0, 0);
        acc[0][3] = __builtin_amdgcn_mfma_f32_16x16x32_bf16(a0, b3, acc[0][3], 0, 0, 0);
        acc[1][0] = __builtin_amdgcn_mfma_f32_16x16x32_bf16(a1, b0, acc[1][0], 0, 0, 0);
        acc[1][1] = __builtin_amdgcn_mfma_f32_16x16x32_bf16(a1, b1, acc[1][1], 0, 0, 0);
        acc[1][2] = __builtin_amdgcn_mfma_f32_16x16x32_bf16(a1, b2, acc[1][2], 0, 0, 0);
        acc[1][3] = __builtin_amdgcn_mfma_f32_16x16x32_bf16(a1, b3, acc[1][3], 0, 0, 0);
        __syncthreads();
    }

    float bv[4];
    #pragma unroll
    for (int n = 0; n < 4; ++n) bv[n] = bias[n * 16 + lr];

    #pragma unroll
    for (int m = 0; m < 2; ++m) {
        #pragma unroll
        for (int n = 0; n < 4; ++n) {
            #pragma unroll
            for (int r = 0; r < 4; ++r) {
                int row = row0 + wrow + m * 16 + kg * 4 + r;
                if (row < nrows)
                    H[(size_t)row * 64 + n * 16 + lr] =
                        __float2bfloat16(acc[m][n][r] + bv[n]);
            }
        }
    }
}

// ---------------------------------------------------------------------------
// mlp2 via MFMA: H[N][64] = bf16(relu(A[N][192]) @ Wm2[192][64] + bm2)
// A bf16 (agg); relu folded into LDS staging; B from pre-built Wm2t.
// ---------------------------------------------------------------------------
__global__ __launch_bounds__(256) void gemm2_mfma(
    const __hip_bfloat16* __restrict__ A,     // [N][192]
    const __hip_bfloat16* __restrict__ Bt,    // [64][192]
    const float* __restrict__ bias,           // [64]
    __hip_bfloat16* __restrict__ H,           // [N][64]
    int nrows)
{
    __shared__ __hip_bfloat16 As[128][40];
    __shared__ __hip_bfloat16 Bs[64][40];

    const int t = threadIdx.x;
    const int lane = t & 63;
    const int w = t >> 6;
    const int row0 = blockIdx.x * 128;
    const int wrow = w * 32;
    const int kg = lane >> 4;
    const int lr = lane & 15;

    f32x4 acc[2][4] = {};

    const int arow = t >> 1;
    const int akh = t & 1;
    const int bcol = t >> 2;
    const int bkq = t & 3;

    for (int k0 = 0; k0 < 192; k0 += 32) {
        {
            int grow = row0 + arow;
            int gr = grow < nrows ? grow : nrows - 1;
            const __hip_bfloat16* ap = A + (size_t)gr * 192 + k0 + akh * 16;
            uint4 u0 = *(const uint4*)ap;
            uint4 u1 = *(const uint4*)(ap + 8);
            u0.x = relu2bf16(u0.x); u0.y = relu2bf16(u0.y);
            u0.z = relu2bf16(u0.z); u0.w = relu2bf16(u0.w);
            u1.x = relu2bf16(u1.x); u1.y = relu2bf16(u1.y);
            u1.z = relu2bf16(u1.z); u1.w = relu2bf16(u1.w);
            *(uint4*)&As[arow][akh * 16]     = u0;
            *(uint4*)&As[arow][akh * 16 + 8] = u1;
        }
        *(uint4*)&Bs[bcol][bkq * 8] =
            *(const uint4*)(Bt + (size_t)bcol * 192 + k0 + bkq * 8);
        __syncthreads();

        short8v a0 = *(const short8v*)&As[wrow + lr][kg * 8];
        short8v a1 = *(const short8v*)&As[wrow + 16 + lr][kg * 8];
        short8v b0 = *(const short8v*)&Bs[lr][kg * 8];
        short8v b1 = *(const short8v*)&Bs[16 + lr][kg * 8];
        short8v b2 = *(const short8v*)&Bs[32 + lr][kg * 8];
        short8v b3 = *(const short8v*)&Bs[48 + lr][kg * 8];
        acc[0][0] = __builtin_amdgcn_mfma_f32_16x16x32_bf16(a0, b0, acc[0][0], 0, 0, 0);
        acc[0][1] = __builtin_amdgcn_mfma_f32_16x16x32_bf16(a0, b1, acc[0][1], 0, 0, 0);
        acc[0][2] = __builtin_amdgcn_mfma_f32_16x16x32_bf16(a0, b2, acc[0][2], 0, 0, 0);
        acc[0][3] = __builtin_amdgcn_mfma_f32_16x16x32_bf16(a0, b3, acc[0][3], 0, 0, 0);
        acc[1][0] = __builtin_amdgcn_mfma_f32_16x16x32_bf16(a1, b0, acc[1][0], 0, 0, 0);
        acc[1][1] = __builtin_amdgcn_mfma_f32_16x16x32_bf16(a1, b1, acc[1][1], 0, 0, 0);
        acc[1][2] = __builtin_amdgcn_mfma_f32_16x16x32_bf16(a1, b2, acc[1][2], 0, 0, 0);
        acc[1][3] = __builtin_amdgcn_mfma_f32_16x16x32_bf16(a1, b3, acc[1][3], 0, 0, 0);
        __syncthreads();
    }

    float bv[4];
    #pragma unroll
    for (int n = 0; n < 4; ++n) bv[n] = bias[n * 16 + lr];

    #pragma unroll
    for (int m = 0; m < 2; ++m) {
        #pragma unroll
        for (int n = 0; n < 4; ++n) {
            #pragma unroll
            for (int r = 0; r < 4; ++r) {
                int row = row0 + wrow + m * 16 + kg * 4 + r;
                if (row < nrows)
                    H[(size_t)row * 64 + n * 16 + lr] =
                        __float2bfloat16(acc[m][n][r] + bv[n]);
            }
        }
    }
}

// ---------------------------------------------------------------------------
// Radix partition pass 1 (256 blocks -> all CUs)
// ---------------------------------------------------------------------------
__global__ __launch_bounds__(1024) void part_count(
    const int* __restrict__ ei1, const int* __restrict__ ei2,
    const int* __restrict__ ei3, int* __restrict__ cnt)
{
    __shared__ int lc[NBK];
    const int t = threadIdx.x;
    for (int j = t; j < NBK; j += 1024) lc[j] = 0;
    __syncthreads();

    const int chunk = (3 * EE + NBLK_P - 1) / NBLK_P;
    const int b0 = blockIdx.x * chunk;
    int b1 = b0 + chunk;
    if (b1 > 3 * EE) b1 = 3 * EE;

    for (int i = b0 + t; i < b1; i += 1024) {
        int s = i / EE;
        int e = i - s * EE;
        const int* ei = (s == 0) ? ei1 : (s == 1) ? ei2 : ei3;
        atomicAdd(&lc[s * NB + (ei[EE + e] >> 7)], 1);
    }
    __syncthreads();
    for (int j = t; j < NBK; j += 1024)
        cnt[j * NBLK_P + blockIdx.x] = lc[j];
}

__global__ __launch_bounds__(1024) void scan_a(
    const int* __restrict__ cnt, int* __restrict__ off,
    int* __restrict__ partials, int M)
{
    __shared__ int sh[1024];
    int t = threadIdx.x;
    int i = blockIdx.x * 1024 + t;
    int v = (i < M) ? cnt[i] : 0;
    sh[t] = v;
    __syncthreads();
    #pragma unroll
    for (int o = 1; o < 1024; o <<= 1) {
        int add = (t >= o) ? sh[t - o] : 0;
        __syncthreads();
        sh[t] += add;
        __syncthreads();
    }
    if (i < M) off[i] = sh[t] - v;
    if (t == 1023) partials[blockIdx.x] = sh[1023];
}

// single-block scan of partials, P <= 1024
__global__ __launch_bounds__(1024) void scan_b(int* __restrict__ partials, int P)
{
    __shared__ int sh[1024];
    int t = threadIdx.x;
    int v = (t < P) ? partials[t] : 0;
    sh[t] = v;
    __syncthreads();
    #pragma unroll
    for (int o = 1; o < 1024; o <<= 1) {
        int add = (t >= o) ? sh[t - o] : 0;
        __syncthreads();
        sh[t] += add;
        __syncthreads();
    }
    if (t < P) partials[t] = sh[t] - v;
}

__global__ __launch_bounds__(256) void scan_c(
    int* __restrict__ off, int* __restrict__ off_b,
    const int* __restrict__ partials, int M)
{
    int i = blockIdx.x * 256 + threadIdx.x;
    if (i < M) {
        int v = off[i] + partials[i >> 10];
        off[i] = v;
        if ((i & (NBLK_P - 1)) == 0) off_b[i / NBLK_P] = v;
    }
    if (i == 0) off_b[NBK] = 3 * EE;
}

__global__ __launch_bounds__(1024) void part_scatter(
    const int* __restrict__ ei1, const float* __restrict__ ea1,
    const int* __restrict__ ei2, const float* __restrict__ ea2,
    const int* __restrict__ ei3, const float* __restrict__ ea3,
    const int* __restrict__ offp, int2* __restrict__ brec)
{
    __shared__ int lcur[NBK];
    const int t = threadIdx.x;
    for (int j = t; j < NBK; j += 1024)
        lcur[j] = offp[j * NBLK_P + blockIdx.x];
    __syncthreads();

    const int chunk = (3 * EE + NBLK_P - 1) / NBLK_P;
    const int b0 = blockIdx.x * chunk;
    int b1 = b0 + chunk;
    if (b1 > 3 * EE) b1 = 3 * EE;

    for (int i = b0 + t; i < b1; i += 1024) {
        int s = i / EE;
        int e = i - s * EE;
        const int* ei = (s == 0) ? ei1 : (s == 1) ? ei2 : ei3;
        const float* ea = (s == 0) ? ea1 : (s == 1) ? ea2 : ea3;
        int src = ei[e];
        int dst = ei[EE + e];
        float w = ea[e];
        int pos = atomicAdd(&lcur[s * NB + (dst >> 7)], 1);
        brec[pos] = make_int2(src | ((dst & 127) << 17), __float_as_int(w));
    }
}

__global__ __launch_bounds__(256) void bucket_refine(
    const int2* __restrict__ brec,
    const int* __restrict__ off_b,
    int* __restrict__ node_off,
    int2* __restrict__ pairs)
{
    __shared__ int hist[128];
    __shared__ int curls[128];
    const int t = threadIdx.x;
    const int bk = blockIdx.x;
    const int s = bk / NB;
    const int b = bk - s * NB;
    const int n0 = b << 7;
    const int beg = off_b[bk];
    const int end = off_b[bk + 1];

    if (bk == 0 && t == 0) node_off[3 * NN] = 3 * EE;
    if (t < 128) hist[t] = 0;
    __syncthreads();

    for (int p = beg + t; p < end; p += 256)
        atomicAdd(&hist[(brec[p].x >> 17) & 127], 1);
    __syncthreads();

    int cnt = (t < 128) ? hist[t] : 0;
    #pragma unroll
    for (int o = 1; o < 128; o <<= 1) {
        int add = (t < 128 && t >= o) ? hist[t - o] : 0;
        __syncthreads();
        if (t < 128) hist[t] += add;
        __syncthreads();
    }
    if (t < 128) {
        int excl = beg + hist[t] - cnt;
        curls[t] = excl;
        if (n0 + t < NN) node_off[s * NN + n0 + t] = excl;
    }
    __syncthreads();

    for (int p = beg + t; p < end; p += 256) {
        int2 r = brec[p];
        int pos = atomicAdd(&curls[(r.x >> 17) & 127], 1);
        pairs[pos] = make_int2(r.x & 0x1FFFF, r.y);
    }
}

// ---------------------------------------------------------------------------
// Segmented gather (scalarized)
// ---------------------------------------------------------------------------
__global__ __launch_bounds__(256) void ufg_gather(
    const __hip_bfloat16* __restrict__ h,
    const int* __restrict__ off,
    const int2* __restrict__ pairs,
    const float* __restrict__ f1, const float* __restrict__ f2,
    const float* __restrict__ f3,
    __hip_bfloat16* __restrict__ agg)
{
    const unsigned lane = threadIdx.x & 63;
    int wid0 = blockIdx.x * 4 + (threadIdx.x >> 6);
    const int wid = __builtin_amdgcn_readfirstlane(wid0);
    if (wid >= 3 * NN) return;
    const int s = wid / NN;
    const int n = wid - s * NN;

    const float* fp = (s == 0) ? f1 : (s == 1) ? f2 : f3;
    const float fv = fp[lane];

    const int beg = off[wid];
    const int end = off[wid + 1];

    float acc0 = 0.f, acc1 = 0.f;
    int p = beg;

    for (; p + 8 <= end; p += 8) {
        int2 q0 = pairs[p + 0];
        int2 q1 = pairs[p + 1];
        int2 q2 = pairs[p + 2];
        int2 q3 = pairs[p + 3];
        int2 q4 = pairs[p + 4];
        int2 q5 = pairs[p + 5];
        int2 q6 = pairs[p + 6];
        int2 q7 = pairs[p + 7];
        float v0 = __bfloat162float(h[((unsigned)q0.x << 6) | lane]);
        float v1 = __bfloat162float(h[((unsigned)q1.x << 6) | lane]);
        float v2 = __bfloat162float(h[((unsigned)q2.x << 6) | lane]);
        float v3 = __bfloat162float(h[((unsigned)q3.x << 6) | lane]);
        float v4 = __bfloat162float(h[((unsigned)q4.x << 6) | lane]);
        float v5 = __bfloat162float(h[((unsigned)q5.x << 6) | lane]);
        float v6 = __bfloat162float(h[((unsigned)q6.x << 6) | lane]);
        float v7 = __bfloat162float(h[((unsigned)q7.x << 6) | lane]);
        acc0 = fmaf(__int_as_float(q0.y), v0, acc0);
        acc1 = fmaf(__int_as_float(q1.y), v1, acc1);
        acc0 = fmaf(__int_as_float(q2.y), v2, acc0);
        acc1 = fmaf(__int_as_float(q3.y), v3, acc1);
        acc0 = fmaf(__int_as_float(q4.y), v4, acc0);
        acc1 = fmaf(__int_as_float(q5.y), v5, acc1);
        acc0 = fmaf(__int_as_float(q6.y), v6, acc0);
        acc1 = fmaf(__int_as_float(q7.y), v7, acc1);
    }
    if (p + 4 <= end) {
        int2 q0 = pairs[p + 0];
        int2 q1 = pairs[p + 1];
        int2 q2 = pairs[p + 2];
        int2 q3 = pairs[p + 3];
        float v0 = __bfloat162float(h[((unsigned)q0.x << 6) | lane]);
        float v1 = __bfloat162float(h[((unsigned)q1.x << 6) | lane]);
        float v2 = __bfloat162float(h[((unsigned)q2.x << 6) | lane]);
        float v3 = __bfloat162float(h[((unsigned)q3.x << 6) | lane]);
        acc0 = fmaf(__int_as_float(q0.y), v0, acc0);
        acc1 = fmaf(__int_as_float(q1.y), v1, acc1);
        acc0 = fmaf(__int_as_float(q2.y), v2, acc0);
        acc1 = fmaf(__int_as_float(q3.y), v3, acc1);
        p += 4;
    }
    if (p + 2 <= end) {
        int2 q0 = pairs[p + 0];
        int2 q1 = pairs[p + 1];
        float v0 = __bfloat162float(h[((unsigned)q0.x << 6) | lane]);
        float v1 = __bfloat162float(h[((unsigned)q1.x << 6) | lane]);
        acc0 = fmaf(__int_as_float(q0.y), v0, acc0);
        acc1 = fmaf(__int_as_float(q1.y), v1, acc1);
        p += 2;
    }
    if (p < end) {
        int2 q = pairs[p];
        acc0 = fmaf(__int_as_float(q.y),
                    __bfloat162float(h[((unsigned)q.x << 6) | lane]), acc0);
    }

    agg[(size_t)n * 192 + s * 64 + lane] =
        __float2bfloat16((acc0 + acc1) * fv);
}

// ---------------------------------------------------------------------------
// mlp1 + log_softmax (bf16 A)
// ---------------------------------------------------------------------------
__global__ __launch_bounds__(256) void gemm40_softmax(
    const __hip_bfloat16* __restrict__ A,
    const float* __restrict__ B,
    const float* __restrict__ bias,
    float* __restrict__ out,
    int nrows)
{
    __shared__ float As[32][68];
    __shared__ float Bs[32][64];

    const int tid = threadIdx.x;
    const int tx = tid & 15;
    const int ty = tid >> 4;
    const int row0 = blockIdx.x * 64;

    float acc[4][4] = {{0.f, 0.f, 0.f, 0.f}, {0.f, 0.f, 0.f, 0.f},
                       {0.f, 0.f, 0.f, 0.f}, {0.f, 0.f, 0.f, 0.f}};

    const int r = tid >> 2;
    const int koff = (tid & 3) * 8;
    const bool rowok = (row0 + r) < nrows;

    for (int k0 = 0; k0 < 192; k0 += 32) {
        float av[8];
        const __hip_bfloat16* ap = A + (size_t)(row0 + r) * 192 + (k0 + koff);
        if (rowok) {
            uint4 u = *(const uint4*)ap;
            av[0] = __uint_as_float(u.x << 16);
            av[1] = __uint_as_float(u.x & 0xFFFF0000u);
            av[2] = __uint_as_float(u.y << 16);
            av[3] = __uint_as_float(u.y & 0xFFFF0000u);
            av[4] = __uint_as_float(u.z << 16);
            av[5] = __uint_as_float(u.z & 0xFFFF0000u);
            av[6] = __uint_as_float(u.w << 16);
            av[7] = __uint_as_float(u.w & 0xFFFF0000u);
        } else {
            #pragma unroll
            for (int j = 0; j < 8; ++j) av[j] = 0.f;
        }
        #pragma unroll
        for (int j = 0; j < 8; ++j) As[koff + j][r] = fmaxf(av[j], 0.f);

        {
            int flat = tid * 8;
            int kk = flat >> 6;
            int c0 = flat & 63;
            #pragma unroll
            for (int j = 0; j < 8; ++j) {
                int cc = c0 + j;
                Bs[kk][cc] = (cc < 40) ? B[(size_t)(k0 + kk) * 40 + cc] : 0.f;
            }
        }
        __syncthreads();

        #pragma unroll
        for (int k = 0; k < 32; ++k) {
            float4 a = *(const float4*)&As[k][ty * 4];
            float4 b = *(const float4*)&Bs[k][tx * 4];
            acc[0][0] = fmaf(a.x, b.x, acc[0][0]);
            acc[0][1] = fmaf(a.x, b.y, acc[0][1]);
            acc[0][2] = fmaf(a.x, b.z, acc[0][2]);
            acc[0][3] = fmaf(a.x, b.w, acc[0][3]);
            acc[1][0] = fmaf(a.y, b.x, acc[1][0]);
            acc[1][1] = fmaf(a.y, b.y, acc[1][1]);
            acc[1][2] = fmaf(a.y, b.z, acc[1][2]);
            acc[1][3] = fmaf(a.y, b.w, acc[1][3]);
            acc[2][0] = fmaf(a.z, b.x, acc[2][0]);
            acc[2][1] = fmaf(a.z, b.y, acc[2][1]);
            acc[2][2] = fmaf(a.z, b.z, acc[2][2]);
            acc[2][3] = fmaf(a.z, b.w, acc[2][3]);
            acc[3][0] = fmaf(a.w, b.x, acc[3][0]);
            acc[3][1] = fmaf(a.w, b.y, acc[3][1]);
            acc[3][2] = fmaf(a.w, b.z, acc[3][2]);
            acc[3][3] = fmaf(a.w, b.w, acc[3][3]);
        }
        __syncthreads();
    }

    float bv[4];
    #pragma unroll
    for (int j = 0; j < 4; ++j) {
        int cc = tx * 4 + j;
        bv[j] = (cc < 40) ? bias[cc] : 0.f;
    }
    const bool colok = (tx < 10);

    #pragma unroll
    for (int i = 0; i < 4; ++i) {
        float v0 = colok ? acc[i][0] + bv[0] : -1e30f;
        float v1 = colok ? acc[i][1] + bv[1] : -1e30f;
        float v2 = colok ? acc[i][2] + bv[2] : -1e30f;
        float v3 = colok ? acc[i][3] + bv[3] : -1e30f;

        float mx = fmaxf(fmaxf(v0, v1), fmaxf(v2, v3));
        #pragma unroll
        for (int o = 1; o < 16; o <<= 1)
            mx = fmaxf(mx, __shfl_xor(mx, o, 64));

        float s = __expf(v0 - mx) + __expf(v1 - mx) +
                  __expf(v2 - mx) + __expf(v3 - mx);
        #pragma unroll
        for (int o = 1; o < 16; o <<= 1)
            s += __shfl_xor(s, o, 64);

        int rr = row0 + ty * 4 + i;
        if (rr < nrows && colok) {
            float ls = mx + __logf(s);
            *(float4*)(out + (size_t)rr * 40 + tx * 4) =
                make_float4(v0 - ls, v1 - ls, v2 - ls, v3 - ls);
        }
    }
}

// ---------------------------------------------------------------------------
extern "C" void kernel_launch(void* const* d_in, const int* in_sizes, int n_in,
                              void* d_out, int out_size, void* d_ws, size_t ws_size,
                              hipStream_t stream)
{
    const float* x    = (const float*)d_in[0];
    const int*   ei1  = (const int*)d_in[1];
    const float* ea1  = (const float*)d_in[2];
    const int*   ei2  = (const int*)d_in[3];
    const float* ea2  = (const float*)d_in[4];
    const int*   ei3  = (const int*)d_in[5];
    const float* ea3  = (const float*)d_in[6];
    const float* W1   = (const float*)d_in[7];
    const float* b1   = (const float*)d_in[8];
    const float* f1_1 = (const float*)d_in[9];
    const float* f2_1 = (const float*)d_in[10];
    const float* f1_2 = (const float*)d_in[11];
    const float* f2_2 = (const float*)d_in[12];
    const float* f1_3 = (const float*)d_in[13];
    const float* f2_3 = (const float*)d_in[14];
    const float* Wm2  = (const float*)d_in[15];
    const float* bm2  = (const float*)d_in[16];
    const float* Wm1  = (const float*)d_in[17];
    const float* bm1  = (const float*)d_in[18];
    float* out = (float*)d_out;

    // ws layout. agg bf16 [N][192]; brec (24 MB) aliases it.
    __hip_bfloat16* agg = (__hip_bfloat16*)d_ws;             // N*192 bf16
    int2*  brec = (int2*)d_ws;                               // 3E int2 (alias)
    char*  base = (char*)d_ws + (size_t)NN * 192 * 2;
    __hip_bfloat16* hbuf = (__hip_bfloat16*)base;            // N*64 bf16
    int*   cnt  = (int*)(base + (size_t)NN * 64 * 2);        // M2
    int*   offp = cnt + M2;                                  // M2
    int*   part = offp + M2;                                 // 1024
    int*   off_b = part + 1024;                              // NBK+1 (+pad)
    int*   node_off = off_b + NBK + 2;                       // 3N+1 (+pad)
    int2*  pairs = (int2*)(node_off + 3 * NN + 2);           // 3E int2
    __hip_bfloat16* w1t = (__hip_bfloat16*)
        (((uintptr_t)(pairs + 3 * EE) + 15) & ~(uintptr_t)15); // 64*512 bf16
    __hip_bfloat16* wm2t = w1t + 64 * 512;                   // 64*192 bf16

    const int gemm_grid = (NN + 63) / 64;
    const int mfma_grid = (NN + 127) / 128;   // 782
    const int P = (M2 + 1023) / 1024;         // 587

    // ---- prep: weight transposes + dst-sort edges
    build_w1t<<<128, 256, 0, stream>>>(W1, w1t);
    build_wm2t<<<48, 256, 0, stream>>>(Wm2, wm2t);
    part_count<<<NBLK_P, 1024, 0, stream>>>(ei1, ei2, ei3, cnt);
    scan_a<<<P, 1024, 0, stream>>>(cnt, offp, part, M2);
    scan_b<<<1, 1024, 0, stream>>>(part, P);
    scan_c<<<(M2 + 255) / 256, 256, 0, stream>>>(offp, off_b, part, M2);
    part_scatter<<<NBLK_P, 1024, 0, stream>>>(ei1, ea1, ei2, ea2, ei3, ea3,
                                              offp, brec);
    bucket_refine<<<NBK, 256, 0, stream>>>(brec, off_b, node_off, pairs);

    // ---- block 1 ----
    gemm1_mfma<<<mfma_grid, 256, 0, stream>>>(x, w1t, b1, hbuf, NN);
    ufg_gather<<<(3 * NN + 3) / 4, 256, 0, stream>>>(hbuf, node_off, pairs,
                                                     f1_1, f1_2, f1_3, agg);
    gemm2_mfma<<<mfma_grid, 256, 0, stream>>>(agg, wm2t, bm2, hbuf, NN);

    // ---- block 2 ----
    ufg_gather<<<(3 * NN + 3) / 4, 256, 0, stream>>>(hbuf, node_off, pairs,
                                                     f2_1, f2_2, f2_3, agg);
    gemm40_softmax<<<gemm_grid, 256, 0, stream>>>(agg, Wm1, bm1, out, NN);
}

// Round 13
// 410.175 us; speedup vs baseline: 1.3570x; 1.0360x over previous
//
#include <hip/hip_runtime.h>
#include <hip/hip_bf16.h>

#define NN 100000
#define FF 500
#define HH 64
#define CC 40
#define EE 1000000
#define NB 782            // buckets per scale: ceil(100000/128)
#define NBK 2346          // 3*NB
#define NBLK_P 256        // partition blocks
#define M2 (NBK * NBLK_P) // 600576 counters

typedef __attribute__((ext_vector_type(8))) short short8v;   // 8 bf16
typedef __attribute__((ext_vector_type(4))) float f32x4;

// relu on 2 packed bf16 (sign-mask select)
__device__ inline unsigned relu2bf16(unsigned u)
{
    unsigned r = (u & 0x00008000u) ? (u & 0xFFFF0000u) : u;
    return (r & 0x80000000u) ? (r & 0x0000FFFFu) : r;
}

// ---------------------------------------------------------------------------
// W1 -> W1t: [500][64] f32 -> [64][512] bf16 (transposed, k zero-padded)
// ---------------------------------------------------------------------------
__global__ __launch_bounds__(256) void build_w1t(
    const float* __restrict__ W1, __hip_bfloat16* __restrict__ W1t)
{
    int idx = blockIdx.x * 256 + threadIdx.x;
    if (idx >= 64 * 512) return;
    int col = idx >> 9;
    int k = idx & 511;
    W1t[idx] = (k < FF) ? __float2bfloat16(W1[(size_t)k * 64 + col])
                        : __float2bfloat16(0.f);
}

// Wm2 -> Wm2t: [192][64] f32 -> [64][192] bf16
__global__ __launch_bounds__(256) void build_wm2t(
    const float* __restrict__ Wm2, __hip_bfloat16* __restrict__ Wm2t)
{
    int idx = blockIdx.x * 256 + threadIdx.x;
    if (idx >= 64 * 192) return;
    int col = idx / 192;
    int k = idx - col * 192;
    Wm2t[idx] = __float2bfloat16(Wm2[(size_t)k * 64 + col]);
}

// ---------------------------------------------------------------------------
// gemm1 via MFMA, v2: 64-row tiles (grid 2x) + register prefetch of the next
// k-tile so HBM latency overlaps the barrier/ds_read/MFMA chain.
// H[N][64] = bf16(X[N][500] @ W1[500][64] + b1)
// ---------------------------------------------------------------------------
__global__ __launch_bounds__(256) void gemm1_mfma(
    const float* __restrict__ X,
    const __hip_bfloat16* __restrict__ W1t,   // [64][512]
    const float* __restrict__ bias,           // [64]
    __hip_bfloat16* __restrict__ H,           // [N][64]
    int nrows)
{
    __shared__ __hip_bfloat16 As[64][40];     // rows x k (pad 32->40)
    __shared__ __hip_bfloat16 Bs[64][40];     // cols x k

    const int t = threadIdx.x;
    const int lane = t & 63;
    const int w = t >> 6;
    const int row0 = blockIdx.x * 64;
    const int kg = lane >> 4;     // k-group: k = kg*8
    const int lr = lane & 15;

    f32x4 acc[4] = {};

    const int arow = t >> 2;          // 0..63
    const int akq = (t & 3) * 8;      // 8 f32 each
    const int bcol = t >> 2;          // 0..63
    const int bkq = (t & 3) * 8;      // 8 bf16 each

    // clamped row pointer (OOB rows read row nrows-1, never stored)
    int grow = row0 + arow;
    const float* xp = X + (size_t)(grow < nrows ? grow : nrows - 1) * FF;

    float va[8];
    uint4 vb;

    // preload k0 = 0
    {
        float4 a0 = *(const float4*)(xp + akq);
        float4 a1 = *(const float4*)(xp + akq + 4);
        va[0]=a0.x; va[1]=a0.y; va[2]=a0.z; va[3]=a0.w;
        va[4]=a1.x; va[5]=a1.y; va[6]=a1.z; va[7]=a1.w;
        vb = *(const uint4*)(W1t + (size_t)bcol * 512 + bkq);
    }

    for (int k0 = 0; k0 < FF; k0 += 32) {
        // ---- stage current k-tile from registers (f32 -> packed bf16)
        {
            unsigned q[4];
            #pragma unroll
            for (int i = 0; i < 4; ++i) {
                __hip_bfloat162 pp =
                    __float22bfloat162_rn(make_float2(va[2*i], va[2*i+1]));
                q[i] = *(unsigned*)&pp;
            }
            *(uint4*)&As[arow][akq] = make_uint4(q[0], q[1], q[2], q[3]);
            *(uint4*)&Bs[bcol][bkq] = vb;
        }

        // ---- issue next k-tile loads (overlap with sync+mfma+sync)
        const int kn = k0 + 32;
        float va2[8];
        uint4 vb2;
        if (kn < FF) {
            if (kn + 32 <= FF) {
                float4 a0 = *(const float4*)(xp + kn + akq);
                float4 a1 = *(const float4*)(xp + kn + akq + 4);
                va2[0]=a0.x; va2[1]=a0.y; va2[2]=a0.z; va2[3]=a0.w;
                va2[4]=a1.x; va2[5]=a1.y; va2[6]=a1.z; va2[7]=a1.w;
            } else {
                #pragma unroll
                for (int j = 0; j < 8; ++j) {
                    int kk = kn + akq + j;
                    va2[j] = (kk < FF) ? xp[kk] : 0.f;
                }
            }
            vb2 = *(const uint4*)(W1t + (size_t)bcol * 512 + kn + bkq);
        }
        __syncthreads();

        // ---- fragments + 4 MFMAs (wave tile 16x64)
        short8v a0 = *(const short8v*)&As[w * 16 + lr][kg * 8];
        short8v b0 = *(const short8v*)&Bs[lr][kg * 8];
        short8v b1 = *(const short8v*)&Bs[16 + lr][kg * 8];
        short8v b2 = *(const short8v*)&Bs[32 + lr][kg * 8];
        short8v b3 = *(const short8v*)&Bs[48 + lr][kg * 8];
        acc[0] = __builtin_amdgcn_mfma_f32_16x16x32_bf16(a0, b0, acc[0], 0, 0, 0);
        acc[1] = __builtin_amdgcn_mfma_f32_16x16x32_bf16(a0, b1, acc[1], 0, 0, 0);
        acc[2] = __builtin_amdgcn_mfma_f32_16x16x32_bf16(a0, b2, acc[2], 0, 0, 0);
        acc[3] = __builtin_amdgcn_mfma_f32_16x16x32_bf16(a0, b3, acc[3], 0, 0, 0);
        __syncthreads();

        if (kn < FF) {
            #pragma unroll
            for (int j = 0; j < 8; ++j) va[j] = va2[j];
            vb = vb2;
        }
    }

    // ---- epilogue: + bias, bf16 store
    float bv[4];
    #pragma unroll
    for (int n = 0; n < 4; ++n) bv[n] = bias[n * 16 + lr];

    #pragma unroll
    for (int n = 0; n < 4; ++n) {
        #pragma unroll
        for (int r = 0; r < 4; ++r) {
            int row = row0 + w * 16 + kg * 4 + r;
            if (row < nrows)
                H[(size_t)row * 64 + n * 16 + lr] =
                    __float2bfloat16(acc[n][r] + bv[n]);
        }
    }
}

// ---------------------------------------------------------------------------
// mlp2 via MFMA: H[N][64] = bf16(relu(A[N][192]) @ Wm2[192][64] + bm2)
// ---------------------------------------------------------------------------
__global__ __launch_bounds__(256) void gemm2_mfma(
    const __hip_bfloat16* __restrict__ A,     // [N][192]
    const __hip_bfloat16* __restrict__ Bt,    // [64][192]
    const float* __restrict__ bias,           // [64]
    __hip_bfloat16* __restrict__ H,           // [N][64]
    int nrows)
{
    __shared__ __hip_bfloat16 As[128][40];
    __shared__ __hip_bfloat16 Bs[64][40];

    const int t = threadIdx.x;
    const int lane = t & 63;
    const int w = t >> 6;
    const int row0 = blockIdx.x * 128;
    const int wrow = w * 32;
    const int kg = lane >> 4;
    const int lr = lane & 15;

    f32x4 acc[2][4] = {};

    const int arow = t >> 1;
    const int akh = t & 1;
    const int bcol = t >> 2;
    const int bkq = t & 3;

    for (int k0 = 0; k0 < 192; k0 += 32) {
        {
            int grow = row0 + arow;
            int gr = grow < nrows ? grow : nrows - 1;
            const __hip_bfloat16* ap = A + (size_t)gr * 192 + k0 + akh * 16;
            uint4 u0 = *(const uint4*)ap;
            uint4 u1 = *(const uint4*)(ap + 8);
            u0.x = relu2bf16(u0.x); u0.y = relu2bf16(u0.y);
            u0.z = relu2bf16(u0.z); u0.w = relu2bf16(u0.w);
            u1.x = relu2bf16(u1.x); u1.y = relu2bf16(u1.y);
            u1.z = relu2bf16(u1.z); u1.w = relu2bf16(u1.w);
            *(uint4*)&As[arow][akh * 16]     = u0;
            *(uint4*)&As[arow][akh * 16 + 8] = u1;
        }
        *(uint4*)&Bs[bcol][bkq * 8] =
            *(const uint4*)(Bt + (size_t)bcol * 192 + k0 + bkq * 8);
        __syncthreads();

        short8v a0 = *(const short8v*)&As[wrow + lr][kg * 8];
        short8v a1 = *(const short8v*)&As[wrow + 16 + lr][kg * 8];
        short8v b0 = *(const short8v*)&Bs[lr][kg * 8];
        short8v b1 = *(const short8v*)&Bs[16 + lr][kg * 8];
        short8v b2 = *(const short8v*)&Bs[32 + lr][kg * 8];
        short8v b3 = *(const short8v*)&Bs[48 + lr][kg * 8];
        acc[0][0] = __builtin_amdgcn_mfma_f32_16x16x32_bf16(a0, b0, acc[0][0], 0, 0, 0);
        acc[0][1] = __builtin_amdgcn_mfma_f32_16x16x32_bf16(a0, b1, acc[0][1], 0, 0, 0);
        acc[0][2] = __builtin_amdgcn_mfma_f32_16x16x32_bf16(a0, b2, acc[0][2], 0, 0, 0);
        acc[0][3] = __builtin_amdgcn_mfma_f32_16x16x32_bf16(a0, b3, acc[0][3], 0, 0, 0);
        acc[1][0] = __builtin_amdgcn_mfma_f32_16x16x32_bf16(a1, b0, acc[1][0], 0, 0, 0);
        acc[1][1] = __builtin_amdgcn_mfma_f32_16x16x32_bf16(a1, b1, acc[1][1], 0, 0, 0);
        acc[1][2] = __builtin_amdgcn_mfma_f32_16x16x32_bf16(a1, b2, acc[1][2], 0, 0, 0);
        acc[1][3] = __builtin_amdgcn_mfma_f32_16x16x32_bf16(a1, b3, acc[1][3], 0, 0, 0);
        __syncthreads();
    }

    float bv[4];
    #pragma unroll
    for (int n = 0; n < 4; ++n) bv[n] = bias[n * 16 + lr];

    #pragma unroll
    for (int m = 0; m < 2; ++m) {
        #pragma unroll
        for (int n = 0; n < 4; ++n) {
            #pragma unroll
            for (int r = 0; r < 4; ++r) {
                int row = row0 + wrow + m * 16 + kg * 4 + r;
                if (row < nrows)
                    H[(size_t)row * 64 + n * 16 + lr] =
                        __float2bfloat16(acc[m][n][r] + bv[n]);
            }
        }
    }
}

// ---------------------------------------------------------------------------
// Radix partition pass 1 (256 blocks -> all CUs)
// ---------------------------------------------------------------------------
__global__ __launch_bounds__(1024) void part_count(
    const int* __restrict__ ei1, const int* __restrict__ ei2,
    const int* __restrict__ ei3, int* __restrict__ cnt)
{
    __shared__ int lc[NBK];
    const int t = threadIdx.x;
    for (int j = t; j < NBK; j += 1024) lc[j] = 0;
    __syncthreads();

    const int chunk = (3 * EE + NBLK_P - 1) / NBLK_P;
    const int b0 = blockIdx.x * chunk;
    int b1 = b0 + chunk;
    if (b1 > 3 * EE) b1 = 3 * EE;

    for (int i = b0 + t; i < b1; i += 1024) {
        int s = i / EE;
        int e = i - s * EE;
        const int* ei = (s == 0) ? ei1 : (s == 1) ? ei2 : ei3;
        atomicAdd(&lc[s * NB + (ei[EE + e] >> 7)], 1);
    }
    __syncthreads();
    for (int j = t; j < NBK; j += 1024)
        cnt[j * NBLK_P + blockIdx.x] = lc[j];
}

__global__ __launch_bounds__(1024) void scan_a(
    const int* __restrict__ cnt, int* __restrict__ off,
    int* __restrict__ partials, int M)
{
    __shared__ int sh[1024];
    int t = threadIdx.x;
    int i = blockIdx.x * 1024 + t;
    int v = (i < M) ? cnt[i] : 0;
    sh[t] = v;
    __syncthreads();
    #pragma unroll
    for (int o = 1; o < 1024; o <<= 1) {
        int add = (t >= o) ? sh[t - o] : 0;
        __syncthreads();
        sh[t] += add;
        __syncthreads();
    }
    if (i < M) off[i] = sh[t] - v;
    if (t == 1023) partials[blockIdx.x] = sh[1023];
}

__global__ __launch_bounds__(1024) void scan_b(int* __restrict__ partials, int P)
{
    __shared__ int sh[1024];
    int t = threadIdx.x;
    int v = (t < P) ? partials[t] : 0;
    sh[t] = v;
    __syncthreads();
    #pragma unroll
    for (int o = 1; o < 1024; o <<= 1) {
        int add = (t >= o) ? sh[t - o] : 0;
        __syncthreads();
        sh[t] += add;
        __syncthreads();
    }
    if (t < P) partials[t] = sh[t] - v;
}

__global__ __launch_bounds__(256) void scan_c(
    int* __restrict__ off, int* __restrict__ off_b,
    const int* __restrict__ partials, int M)
{
    int i = blockIdx.x * 256 + threadIdx.x;
    if (i < M) {
        int v = off[i] + partials[i >> 10];
        off[i] = v;
        if ((i & (NBLK_P - 1)) == 0) off_b[i / NBLK_P] = v;
    }
    if (i == 0) off_b[NBK] = 3 * EE;
}

__global__ __launch_bounds__(1024) void part_scatter(
    const int* __restrict__ ei1, const float* __restrict__ ea1,
    const int* __restrict__ ei2, const float* __restrict__ ea2,
    const int* __restrict__ ei3, const float* __restrict__ ea3,
    const int* __restrict__ offp, int2* __restrict__ brec)
{
    __shared__ int lcur[NBK];
    const int t = threadIdx.x;
    for (int j = t; j < NBK; j += 1024)
        lcur[j] = offp[j * NBLK_P + blockIdx.x];
    __syncthreads();

    const int chunk = (3 * EE + NBLK_P - 1) / NBLK_P;
    const int b0 = blockIdx.x * chunk;
    int b1 = b0 + chunk;
    if (b1 > 3 * EE) b1 = 3 * EE;

    for (int i = b0 + t; i < b1; i += 1024) {
        int s = i / EE;
        int e = i - s * EE;
        const int* ei = (s == 0) ? ei1 : (s == 1) ? ei2 : ei3;
        const float* ea = (s == 0) ? ea1 : (s == 1) ? ea2 : ea3;
        int src = ei[e];
        int dst = ei[EE + e];
        float w = ea[e];
        int pos = atomicAdd(&lcur[s * NB + (dst >> 7)], 1);
        brec[pos] = make_int2(src | ((dst & 127) << 17), __float_as_int(w));
    }
}

__global__ __launch_bounds__(256) void bucket_refine(
    const int2* __restrict__ brec,
    const int* __restrict__ off_b,
    int* __restrict__ node_off,
    int2* __restrict__ pairs)
{
    __shared__ int hist[128];
    __shared__ int curls[128];
    const int t = threadIdx.x;
    const int bk = blockIdx.x;
    const int s = bk / NB;
    const int b = bk - s * NB;
    const int n0 = b << 7;
    const int beg = off_b[bk];
    const int end = off_b[bk + 1];

    if (bk == 0 && t == 0) node_off[3 * NN] = 3 * EE;
    if (t < 128) hist[t] = 0;
    __syncthreads();

    for (int p = beg + t; p < end; p += 256)
        atomicAdd(&hist[(brec[p].x >> 17) & 127], 1);
    __syncthreads();

    int cnt = (t < 128) ? hist[t] : 0;
    #pragma unroll
    for (int o = 1; o < 128; o <<= 1) {
        int add = (t < 128 && t >= o) ? hist[t - o] : 0;
        __syncthreads();
        if (t < 128) hist[t] += add;
        __syncthreads();
    }
    if (t < 128) {
        int excl = beg + hist[t] - cnt;
        curls[t] = excl;
        if (n0 + t < NN) node_off[s * NN + n0 + t] = excl;
    }
    __syncthreads();

    for (int p = beg + t; p < end; p += 256) {
        int2 r = brec[p];
        int pos = atomicAdd(&curls[(r.x >> 17) & 127], 1);
        pairs[pos] = make_int2(r.x & 0x1FFFF, r.y);
    }
}

// ---------------------------------------------------------------------------
// Segmented gather (scalarized)
// ---------------------------------------------------------------------------
__global__ __launch_bounds__(256) void ufg_gather(
    const __hip_bfloat16* __restrict__ h,
    const int* __restrict__ off,
    const int2* __restrict__ pairs,
    const float* __restrict__ f1, const float* __restrict__ f2,
    const float* __restrict__ f3,
    __hip_bfloat16* __restrict__ agg)
{
    const unsigned lane = threadIdx.x & 63;
    int wid0 = blockIdx.x * 4 + (threadIdx.x >> 6);
    const int wid = __builtin_amdgcn_readfirstlane(wid0);
    if (wid >= 3 * NN) return;
    const int s = wid / NN;
    const int n = wid - s * NN;

    const float* fp = (s == 0) ? f1 : (s == 1) ? f2 : f3;
    const float fv = fp[lane];

    const int beg = off[wid];
    const int end = off[wid + 1];

    float acc0 = 0.f, acc1 = 0.f;
    int p = beg;

    for (; p + 8 <= end; p += 8) {
        int2 q0 = pairs[p + 0];
        int2 q1 = pairs[p + 1];
        int2 q2 = pairs[p + 2];
        int2 q3 = pairs[p + 3];
        int2 q4 = pairs[p + 4];
        int2 q5 = pairs[p + 5];
        int2 q6 = pairs[p + 6];
        int2 q7 = pairs[p + 7];
        float v0 = __bfloat162float(h[((unsigned)q0.x << 6) | lane]);
        float v1 = __bfloat162float(h[((unsigned)q1.x << 6) | lane]);
        float v2 = __bfloat162float(h[((unsigned)q2.x << 6) | lane]);
        float v3 = __bfloat162float(h[((unsigned)q3.x << 6) | lane]);
        float v4 = __bfloat162float(h[((unsigned)q4.x << 6) | lane]);
        float v5 = __bfloat162float(h[((unsigned)q5.x << 6) | lane]);
        float v6 = __bfloat162float(h[((unsigned)q6.x << 6) | lane]);
        float v7 = __bfloat162float(h[((unsigned)q7.x << 6) | lane]);
        acc0 = fmaf(__int_as_float(q0.y), v0, acc0);
        acc1 = fmaf(__int_as_float(q1.y), v1, acc1);
        acc0 = fmaf(__int_as_float(q2.y), v2, acc0);
        acc1 = fmaf(__int_as_float(q3.y), v3, acc1);
        acc0 = fmaf(__int_as_float(q4.y), v4, acc0);
        acc1 = fmaf(__int_as_float(q5.y), v5, acc1);
        acc0 = fmaf(__int_as_float(q6.y), v6, acc0);
        acc1 = fmaf(__int_as_float(q7.y), v7, acc1);
    }
    if (p + 4 <= end) {
        int2 q0 = pairs[p + 0];
        int2 q1 = pairs[p + 1];
        int2 q2 = pairs[p + 2];
        int2 q3 = pairs[p + 3];
        float v0 = __bfloat162float(h[((unsigned)q0.x << 6) | lane]);
        float v1 = __bfloat162float(h[((unsigned)q1.x << 6) | lane]);
        float v2 = __bfloat162float(h[((unsigned)q2.x << 6) | lane]);
        float v3 = __bfloat162float(h[((unsigned)q3.x << 6) | lane]);
        acc0 = fmaf(__int_as_float(q0.y), v0, acc0);
        acc1 = fmaf(__int_as_float(q1.y), v1, acc1);
        acc0 = fmaf(__int_as_float(q2.y), v2, acc0);
        acc1 = fmaf(__int_as_float(q3.y), v3, acc1);
        p += 4;
    }
    if (p + 2 <= end) {
        int2 q0 = pairs[p + 0];
        int2 q1 = pairs[p + 1];
        float v0 = __bfloat162float(h[((unsigned)q0.x << 6) | lane]);
        float v1 = __bfloat162float(h[((unsigned)q1.x << 6) | lane]);
        acc0 = fmaf(__int_as_float(q0.y), v0, acc0);
        acc1 = fmaf(__int_as_float(q1.y), v1, acc1);
        p += 2;
    }
    if (p < end) {
        int2 q = pairs[p];
        acc0 = fmaf(__int_as_float(q.y),
                    __bfloat162float(h[((unsigned)q.x << 6) | lane]), acc0);
    }

    agg[(size_t)n * 192 + s * 64 + lane] =
        __float2bfloat16((acc0 + acc1) * fv);
}

// ---------------------------------------------------------------------------
// mlp1 + log_softmax (bf16 A)
// ---------------------------------------------------------------------------
__global__ __launch_bounds__(256) void gemm40_softmax(
    const __hip_bfloat16* __restrict__ A,
    const float* __restrict__ B,
    const float* __restrict__ bias,
    float* __restrict__ out,
    int nrows)
{
    __shared__ float As[32][68];
    __shared__ float Bs[32][64];

    const int tid = threadIdx.x;
    const int tx = tid & 15;
    const int ty = tid >> 4;
    const int row0 = blockIdx.x * 64;

    float acc[4][4] = {{0.f, 0.f, 0.f, 0.f}, {0.f, 0.f, 0.f, 0.f},
                       {0.f, 0.f, 0.f, 0.f}, {0.f, 0.f, 0.f, 0.f}};

    const int r = tid >> 2;
    const int koff = (tid & 3) * 8;
    const bool rowok = (row0 + r) < nrows;

    for (int k0 = 0; k0 < 192; k0 += 32) {
        float av[8];
        const __hip_bfloat16* ap = A + (size_t)(row0 + r) * 192 + (k0 + koff);
        if (rowok) {
            uint4 u = *(const uint4*)ap;
            av[0] = __uint_as_float(u.x << 16);
            av[1] = __uint_as_float(u.x & 0xFFFF0000u);
            av[2] = __uint_as_float(u.y << 16);
            av[3] = __uint_as_float(u.y & 0xFFFF0000u);
            av[4] = __uint_as_float(u.z << 16);
            av[5] = __uint_as_float(u.z & 0xFFFF0000u);
            av[6] = __uint_as_float(u.w << 16);
            av[7] = __uint_as_float(u.w & 0xFFFF0000u);
        } else {
            #pragma unroll
            for (int j = 0; j < 8; ++j) av[j] = 0.f;
        }
        #pragma unroll
        for (int j = 0; j < 8; ++j) As[koff + j][r] = fmaxf(av[j], 0.f);

        {
            int flat = tid * 8;
            int kk = flat >> 6;
            int c0 = flat & 63;
            #pragma unroll
            for (int j = 0; j < 8; ++j) {
                int cc = c0 + j;
                Bs[kk][cc] = (cc < 40) ? B[(size_t)(k0 + kk) * 40 + cc] : 0.f;
            }
        }
        __syncthreads();

        #pragma unroll
        for (int k = 0; k < 32; ++k) {
            float4 a = *(const float4*)&As[k][ty * 4];
            float4 b = *(const float4*)&Bs[k][tx * 4];
            acc[0][0] = fmaf(a.x, b.x, acc[0][0]);
            acc[0][1] = fmaf(a.x, b.y, acc[0][1]);
            acc[0][2] = fmaf(a.x, b.z, acc[0][2]);
            acc[0][3] = fmaf(a.x, b.w, acc[0][3]);
            acc[1][0] = fmaf(a.y, b.x, acc[1][0]);
            acc[1][1] = fmaf(a.y, b.y, acc[1][1]);
            acc[1][2] = fmaf(a.y, b.z, acc[1][2]);
            acc[1][3] = fmaf(a.y, b.w, acc[1][3]);
            acc[2][0] = fmaf(a.z, b.x, acc[2][0]);
            acc[2][1] = fmaf(a.z, b.y, acc[2][1]);
            acc[2][2] = fmaf(a.z, b.z, acc[2][2]);
            acc[2][3] = fmaf(a.z, b.w, acc[2][3]);
            acc[3][0] = fmaf(a.w, b.x, acc[3][0]);
            acc[3][1] = fmaf(a.w, b.y, acc[3][1]);
            acc[3][2] = fmaf(a.w, b.z, acc[3][2]);
            acc[3][3] = fmaf(a.w, b.w, acc[3][3]);
        }
        __syncthreads();
    }

    float bv[4];
    #pragma unroll
    for (int j = 0; j < 4; ++j) {
        int cc = tx * 4 + j;
        bv[j] = (cc < 40) ? bias[cc] : 0.f;
    }
    const bool colok = (tx < 10);

    #pragma unroll
    for (int i = 0; i < 4; ++i) {
        float v0 = colok ? acc[i][0] + bv[0] : -1e30f;
        float v1 = colok ? acc[i][1] + bv[1] : -1e30f;
        float v2 = colok ? acc[i][2] + bv[2] : -1e30f;
        float v3 = colok ? acc[i][3] + bv[3] : -1e30f;

        float mx = fmaxf(fmaxf(v0, v1), fmaxf(v2, v3));
        #pragma unroll
        for (int o = 1; o < 16; o <<= 1)
            mx = fmaxf(mx, __shfl_xor(mx, o, 64));

        float s = __expf(v0 - mx) + __expf(v1 - mx) +
                  __expf(v2 - mx) + __expf(v3 - mx);
        #pragma unroll
        for (int o = 1; o < 16; o <<= 1)
            s += __shfl_xor(s, o, 64);

        int rr = row0 + ty * 4 + i;
        if (rr < nrows && colok) {
            float ls = mx + __logf(s);
            *(float4*)(out + (size_t)rr * 40 + tx * 4) =
                make_float4(v0 - ls, v1 - ls, v2 - ls, v3 - ls);
        }
    }
}

// ---------------------------------------------------------------------------
extern "C" void kernel_launch(void* const* d_in, const int* in_sizes, int n_in,
                              void* d_out, int out_size, void* d_ws, size_t ws_size,
                              hipStream_t stream)
{
    const float* x    = (const float*)d_in[0];
    const int*   ei1  = (const int*)d_in[1];
    const float* ea1  = (const float*)d_in[2];
    const int*   ei2  = (const int*)d_in[3];
    const float* ea2  = (const float*)d_in[4];
    const int*   ei3  = (const int*)d_in[5];
    const float* ea3  = (const float*)d_in[6];
    const float* W1   = (const float*)d_in[7];
    const float* b1   = (const float*)d_in[8];
    const float* f1_1 = (const float*)d_in[9];
    const float* f2_1 = (const float*)d_in[10];
    const float* f1_2 = (const float*)d_in[11];
    const float* f2_2 = (const float*)d_in[12];
    const float* f1_3 = (const float*)d_in[13];
    const float* f2_3 = (const float*)d_in[14];
    const float* Wm2  = (const float*)d_in[15];
    const float* bm2  = (const float*)d_in[16];
    const float* Wm1  = (const float*)d_in[17];
    const float* bm1  = (const float*)d_in[18];
    float* out = (float*)d_out;

    // ws layout. agg bf16 [N][192]; brec (24 MB) aliases it.
    __hip_bfloat16* agg = (__hip_bfloat16*)d_ws;             // N*192 bf16
    int2*  brec = (int2*)d_ws;                               // 3E int2 (alias)
    char*  base = (char*)d_ws + (size_t)NN * 192 * 2;
    __hip_bfloat16* hbuf = (__hip_bfloat16*)base;            // N*64 bf16
    int*   cnt  = (int*)(base + (size_t)NN * 64 * 2);        // M2
    int*   offp = cnt + M2;                                  // M2
    int*   part = offp + M2;                                 // 1024
    int*   off_b = part + 1024;                              // NBK+1 (+pad)
    int*   node_off = off_b + NBK + 2;                       // 3N+1 (+pad)
    int2*  pairs = (int2*)(node_off + 3 * NN + 2);           // 3E int2
    __hip_bfloat16* w1t = (__hip_bfloat16*)
        (((uintptr_t)(pairs + 3 * EE) + 15) & ~(uintptr_t)15); // 64*512 bf16
    __hip_bfloat16* wm2t = w1t + 64 * 512;                   // 64*192 bf16

    const int gemm_grid = (NN + 63) / 64;     // 1563
    const int mfma2_grid = (NN + 127) / 128;  // 782 (gemm2)
    const int P = (M2 + 1023) / 1024;         // 587

    // ---- prep: weight transposes + dst-sort edges
    build_w1t<<<128, 256, 0, stream>>>(W1, w1t);
    build_wm2t<<<48, 256, 0, stream>>>(Wm2, wm2t);
    part_count<<<NBLK_P, 1024, 0, stream>>>(ei1, ei2, ei3, cnt);
    scan_a<<<P, 1024, 0, stream>>>(cnt, offp, part, M2);
    scan_b<<<1, 1024, 0, stream>>>(part, P);
    scan_c<<<(M2 + 255) / 256, 256, 0, stream>>>(offp, off_b, part, M2);
    part_scatter<<<NBLK_P, 1024, 0, stream>>>(ei1, ea1, ei2, ea2, ei3, ea3,
                                              offp, brec);
    bucket_refine<<<NBK, 256, 0, stream>>>(brec, off_b, node_off, pairs);

    // ---- block 1 ----
    gemm1_mfma<<<gemm_grid, 256, 0, stream>>>(x, w1t, b1, hbuf, NN);
    ufg_gather<<<(3 * NN + 3) / 4, 256, 0, stream>>>(hbuf, node_off, pairs,
                                                     f1_1, f1_2, f1_3, agg);
    gemm2_mfma<<<mfma2_grid, 256, 0, stream>>>(agg, wm2t, bm2, hbuf, NN);

    // ---- block 2 ----
    ufg_gather<<<(3 * NN + 3) / 4, 256, 0, stream>>>(hbuf, node_off, pairs,
                                                     f2_1, f2_2, f2_3, agg);
    gemm40_softmax<<<gemm_grid, 256, 0, stream>>>(agg, Wm1, bm1, out, NN);
}

// Round 14
// 364.850 us; speedup vs baseline: 1.5255x; 1.1242x over previous
//
#include <hip/hip_runtime.h>
#include <hip/hip_bf16.h>

#define NN 100000
#define FF 500
#define HH 64
#define CC 40
#define EE 1000000
#define NB 782            // buckets per scale: ceil(100000/128)
#define NBK 2346          // 3*NB
#define NBLK_P 256        // partition blocks
#define M2 (NBK * NBLK_P) // 600576 counters

typedef __attribute__((ext_vector_type(8))) short short8v;   // 8 bf16
typedef __attribute__((ext_vector_type(4))) float f32x4;

// relu on 2 packed bf16 (sign-mask select)
__device__ inline unsigned relu2bf16(unsigned u)
{
    unsigned r = (u & 0x00008000u) ? (u & 0xFFFF0000u) : u;
    return (r & 0x80000000u) ? (r & 0x0000FFFFu) : r;
}

// ---------------------------------------------------------------------------
// W1 -> W1t: [500][64] f32 -> [64][512] bf16 (transposed, k zero-padded)
// ---------------------------------------------------------------------------
__global__ __launch_bounds__(256) void build_w1t(
    const float* __restrict__ W1, __hip_bfloat16* __restrict__ W1t)
{
    int idx = blockIdx.x * 256 + threadIdx.x;
    if (idx >= 64 * 512) return;
    int col = idx >> 9;
    int k = idx & 511;
    W1t[idx] = (k < FF) ? __float2bfloat16(W1[(size_t)k * 64 + col])
                        : __float2bfloat16(0.f);
}

// Wm2 -> Wm2t: [192][64] f32 -> [64][192] bf16
__global__ __launch_bounds__(256) void build_wm2t(
    const float* __restrict__ Wm2, __hip_bfloat16* __restrict__ Wm2t)
{
    int idx = blockIdx.x * 256 + threadIdx.x;
    if (idx >= 64 * 192) return;
    int col = idx / 192;
    int k = idx - col * 192;
    Wm2t[idx] = __float2bfloat16(Wm2[(size_t)k * 64 + col]);
}

// ---------------------------------------------------------------------------
// gemm1 via MFMA, v2: 64-row tiles + register prefetch of the next k-tile.
// H[N][64] = bf16(X[N][500] @ W1[500][64] + b1)
// ---------------------------------------------------------------------------
__global__ __launch_bounds__(256) void gemm1_mfma(
    const float* __restrict__ X,
    const __hip_bfloat16* __restrict__ W1t,   // [64][512]
    const float* __restrict__ bias,           // [64]
    __hip_bfloat16* __restrict__ H,           // [N][64]
    int nrows)
{
    __shared__ __hip_bfloat16 As[64][40];
    __shared__ __hip_bfloat16 Bs[64][40];

    const int t = threadIdx.x;
    const int lane = t & 63;
    const int w = t >> 6;
    const int row0 = blockIdx.x * 64;
    const int kg = lane >> 4;
    const int lr = lane & 15;

    f32x4 acc[4] = {};

    const int arow = t >> 2;
    const int akq = (t & 3) * 8;
    const int bcol = t >> 2;
    const int bkq = (t & 3) * 8;

    int grow = row0 + arow;
    const float* xp = X + (size_t)(grow < nrows ? grow : nrows - 1) * FF;

    float va[8];
    uint4 vb;
    {
        float4 a0 = *(const float4*)(xp + akq);
        float4 a1 = *(const float4*)(xp + akq + 4);
        va[0]=a0.x; va[1]=a0.y; va[2]=a0.z; va[3]=a0.w;
        va[4]=a1.x; va[5]=a1.y; va[6]=a1.z; va[7]=a1.w;
        vb = *(const uint4*)(W1t + (size_t)bcol * 512 + bkq);
    }

    for (int k0 = 0; k0 < FF; k0 += 32) {
        {
            unsigned q[4];
            #pragma unroll
            for (int i = 0; i < 4; ++i) {
                __hip_bfloat162 pp =
                    __float22bfloat162_rn(make_float2(va[2*i], va[2*i+1]));
                q[i] = *(unsigned*)&pp;
            }
            *(uint4*)&As[arow][akq] = make_uint4(q[0], q[1], q[2], q[3]);
            *(uint4*)&Bs[bcol][bkq] = vb;
        }

        const int kn = k0 + 32;
        float va2[8];
        uint4 vb2;
        if (kn < FF) {
            if (kn + 32 <= FF) {
                float4 a0 = *(const float4*)(xp + kn + akq);
                float4 a1 = *(const float4*)(xp + kn + akq + 4);
                va2[0]=a0.x; va2[1]=a0.y; va2[2]=a0.z; va2[3]=a0.w;
                va2[4]=a1.x; va2[5]=a1.y; va2[6]=a1.z; va2[7]=a1.w;
            } else {
                #pragma unroll
                for (int j = 0; j < 8; ++j) {
                    int kk = kn + akq + j;
                    va2[j] = (kk < FF) ? xp[kk] : 0.f;
                }
            }
            vb2 = *(const uint4*)(W1t + (size_t)bcol * 512 + kn + bkq);
        }
        __syncthreads();

        short8v a0 = *(const short8v*)&As[w * 16 + lr][kg * 8];
        short8v b0 = *(const short8v*)&Bs[lr][kg * 8];
        short8v b1 = *(const short8v*)&Bs[16 + lr][kg * 8];
        short8v b2 = *(const short8v*)&Bs[32 + lr][kg * 8];
        short8v b3 = *(const short8v*)&Bs[48 + lr][kg * 8];
        acc[0] = __builtin_amdgcn_mfma_f32_16x16x32_bf16(a0, b0, acc[0], 0, 0, 0);
        acc[1] = __builtin_amdgcn_mfma_f32_16x16x32_bf16(a0, b1, acc[1], 0, 0, 0);
        acc[2] = __builtin_amdgcn_mfma_f32_16x16x32_bf16(a0, b2, acc[2], 0, 0, 0);
        acc[3] = __builtin_amdgcn_mfma_f32_16x16x32_bf16(a0, b3, acc[3], 0, 0, 0);
        __syncthreads();

        if (kn < FF) {
            #pragma unroll
            for (int j = 0; j < 8; ++j) va[j] = va2[j];
            vb = vb2;
        }
    }

    float bv[4];
    #pragma unroll
    for (int n = 0; n < 4; ++n) bv[n] = bias[n * 16 + lr];

    #pragma unroll
    for (int n = 0; n < 4; ++n) {
        #pragma unroll
        for (int r = 0; r < 4; ++r) {
            int row = row0 + w * 16 + kg * 4 + r;
            if (row < nrows)
                H[(size_t)row * 64 + n * 16 + lr] =
                    __float2bfloat16(acc[n][r] + bv[n]);
        }
    }
}

// ---------------------------------------------------------------------------
// mlp2 via MFMA: H[N][64] = bf16(relu(A[N][192]) @ Wm2[192][64] + bm2)
// ---------------------------------------------------------------------------
__global__ __launch_bounds__(256) void gemm2_mfma(
    const __hip_bfloat16* __restrict__ A,     // [N][192]
    const __hip_bfloat16* __restrict__ Bt,    // [64][192]
    const float* __restrict__ bias,           // [64]
    __hip_bfloat16* __restrict__ H,           // [N][64]
    int nrows)
{
    __shared__ __hip_bfloat16 As[128][40];
    __shared__ __hip_bfloat16 Bs[64][40];

    const int t = threadIdx.x;
    const int lane = t & 63;
    const int w = t >> 6;
    const int row0 = blockIdx.x * 128;
    const int wrow = w * 32;
    const int kg = lane >> 4;
    const int lr = lane & 15;

    f32x4 acc[2][4] = {};

    const int arow = t >> 1;
    const int akh = t & 1;
    const int bcol = t >> 2;
    const int bkq = t & 3;

    for (int k0 = 0; k0 < 192; k0 += 32) {
        {
            int grow = row0 + arow;
            int gr = grow < nrows ? grow : nrows - 1;
            const __hip_bfloat16* ap = A + (size_t)gr * 192 + k0 + akh * 16;
            uint4 u0 = *(const uint4*)ap;
            uint4 u1 = *(const uint4*)(ap + 8);
            u0.x = relu2bf16(u0.x); u0.y = relu2bf16(u0.y);
            u0.z = relu2bf16(u0.z); u0.w = relu2bf16(u0.w);
            u1.x = relu2bf16(u1.x); u1.y = relu2bf16(u1.y);
            u1.z = relu2bf16(u1.z); u1.w = relu2bf16(u1.w);
            *(uint4*)&As[arow][akh * 16]     = u0;
            *(uint4*)&As[arow][akh * 16 + 8] = u1;
        }
        *(uint4*)&Bs[bcol][bkq * 8] =
            *(const uint4*)(Bt + (size_t)bcol * 192 + k0 + bkq * 8);
        __syncthreads();

        short8v a0 = *(const short8v*)&As[wrow + lr][kg * 8];
        short8v a1 = *(const short8v*)&As[wrow + 16 + lr][kg * 8];
        short8v b0 = *(const short8v*)&Bs[lr][kg * 8];
        short8v b1 = *(const short8v*)&Bs[16 + lr][kg * 8];
        short8v b2 = *(const short8v*)&Bs[32 + lr][kg * 8];
        short8v b3 = *(const short8v*)&Bs[48 + lr][kg * 8];
        acc[0][0] = __builtin_amdgcn_mfma_f32_16x16x32_bf16(a0, b0, acc[0][0], 0, 0, 0);
        acc[0][1] = __builtin_amdgcn_mfma_f32_16x16x32_bf16(a0, b1, acc[0][1], 0, 0, 0);
        acc[0][2] = __builtin_amdgcn_mfma_f32_16x16x32_bf16(a0, b2, acc[0][2], 0, 0, 0);
        acc[0][3] = __builtin_amdgcn_mfma_f32_16x16x32_bf16(a0, b3, acc[0][3], 0, 0, 0);
        acc[1][0] = __builtin_amdgcn_mfma_f32_16x16x32_bf16(a1, b0, acc[1][0], 0, 0, 0);
        acc[1][1] = __builtin_amdgcn_mfma_f32_16x16x32_bf16(a1, b1, acc[1][1], 0, 0, 0);
        acc[1][2] = __builtin_amdgcn_mfma_f32_16x16x32_bf16(a1, b2, acc[1][2], 0, 0, 0);
        acc[1][3] = __builtin_amdgcn_mfma_f32_16x16x32_bf16(a1, b3, acc[1][3], 0, 0, 0);
        __syncthreads();
    }

    float bv[4];
    #pragma unroll
    for (int n = 0; n < 4; ++n) bv[n] = bias[n * 16 + lr];

    #pragma unroll
    for (int m = 0; m < 2; ++m) {
        #pragma unroll
        for (int n = 0; n < 4; ++n) {
            #pragma unroll
            for (int r = 0; r < 4; ++r) {
                int row = row0 + wrow + m * 16 + kg * 4 + r;
                if (row < nrows)
                    H[(size_t)row * 64 + n * 16 + lr] =
                        __float2bfloat16(acc[m][n][r] + bv[n]);
            }
        }
    }
}

// ---------------------------------------------------------------------------
// Radix partition pass 1 (256 blocks -> all CUs)
// ---------------------------------------------------------------------------
__global__ __launch_bounds__(1024) void part_count(
    const int* __restrict__ ei1, const int* __restrict__ ei2,
    const int* __restrict__ ei3, int* __restrict__ cnt)
{
    __shared__ int lc[NBK];
    const int t = threadIdx.x;
    for (int j = t; j < NBK; j += 1024) lc[j] = 0;
    __syncthreads();

    const int chunk = (3 * EE + NBLK_P - 1) / NBLK_P;
    const int b0 = blockIdx.x * chunk;
    int b1 = b0 + chunk;
    if (b1 > 3 * EE) b1 = 3 * EE;

    for (int i = b0 + t; i < b1; i += 1024) {
        int s = i / EE;
        int e = i - s * EE;
        const int* ei = (s == 0) ? ei1 : (s == 1) ? ei2 : ei3;
        atomicAdd(&lc[s * NB + (ei[EE + e] >> 7)], 1);
    }
    __syncthreads();
    for (int j = t; j < NBK; j += 1024)
        cnt[j * NBLK_P + blockIdx.x] = lc[j];
}

__global__ __launch_bounds__(1024) void scan_a(
    const int* __restrict__ cnt, int* __restrict__ off,
    int* __restrict__ partials, int M)
{
    __shared__ int sh[1024];
    int t = threadIdx.x;
    int i = blockIdx.x * 1024 + t;
    int v = (i < M) ? cnt[i] : 0;
    sh[t] = v;
    __syncthreads();
    #pragma unroll
    for (int o = 1; o < 1024; o <<= 1) {
        int add = (t >= o) ? sh[t - o] : 0;
        __syncthreads();
        sh[t] += add;
        __syncthreads();
    }
    if (i < M) off[i] = sh[t] - v;
    if (t == 1023) partials[blockIdx.x] = sh[1023];
}

__global__ __launch_bounds__(1024) void scan_b(int* __restrict__ partials, int P)
{
    __shared__ int sh[1024];
    int t = threadIdx.x;
    int v = (t < P) ? partials[t] : 0;
    sh[t] = v;
    __syncthreads();
    #pragma unroll
    for (int o = 1; o < 1024; o <<= 1) {
        int add = (t >= o) ? sh[t - o] : 0;
        __syncthreads();
        sh[t] += add;
        __syncthreads();
    }
    if (t < P) partials[t] = sh[t] - v;
}

__global__ __launch_bounds__(256) void scan_c(
    int* __restrict__ off, int* __restrict__ off_b,
    const int* __restrict__ partials, int M)
{
    int i = blockIdx.x * 256 + threadIdx.x;
    if (i < M) {
        int v = off[i] + partials[i >> 10];
        off[i] = v;
        if ((i & (NBLK_P - 1)) == 0) off_b[i / NBLK_P] = v;
    }
    if (i == 0) off_b[NBK] = 3 * EE;
}

__global__ __launch_bounds__(1024) void part_scatter(
    const int* __restrict__ ei1, const float* __restrict__ ea1,
    const int* __restrict__ ei2, const float* __restrict__ ea2,
    const int* __restrict__ ei3, const float* __restrict__ ea3,
    const int* __restrict__ offp, int2* __restrict__ brec)
{
    __shared__ int lcur[NBK];
    const int t = threadIdx.x;
    for (int j = t; j < NBK; j += 1024)
        lcur[j] = offp[j * NBLK_P + blockIdx.x];
    __syncthreads();

    const int chunk = (3 * EE + NBLK_P - 1) / NBLK_P;
    const int b0 = blockIdx.x * chunk;
    int b1 = b0 + chunk;
    if (b1 > 3 * EE) b1 = 3 * EE;

    for (int i = b0 + t; i < b1; i += 1024) {
        int s = i / EE;
        int e = i - s * EE;
        const int* ei = (s == 0) ? ei1 : (s == 1) ? ei2 : ei3;
        const float* ea = (s == 0) ? ea1 : (s == 1) ? ea2 : ea3;
        int src = ei[e];
        int dst = ei[EE + e];
        float w = ea[e];
        int pos = atomicAdd(&lcur[s * NB + (dst >> 7)], 1);
        brec[pos] = make_int2(src | ((dst & 127) << 17), __float_as_int(w));
    }
}

__global__ __launch_bounds__(256) void bucket_refine(
    const int2* __restrict__ brec,
    const int* __restrict__ off_b,
    int* __restrict__ node_off,
    int2* __restrict__ pairs)
{
    __shared__ int hist[128];
    __shared__ int curls[128];
    const int t = threadIdx.x;
    const int bk = blockIdx.x;
    const int s = bk / NB;
    const int b = bk - s * NB;
    const int n0 = b << 7;
    const int beg = off_b[bk];
    const int end = off_b[bk + 1];

    if (bk == 0 && t == 0) node_off[3 * NN] = 3 * EE;
    if (t < 128) hist[t] = 0;
    __syncthreads();

    for (int p = beg + t; p < end; p += 256)
        atomicAdd(&hist[(brec[p].x >> 17) & 127], 1);
    __syncthreads();

    int cnt = (t < 128) ? hist[t] : 0;
    #pragma unroll
    for (int o = 1; o < 128; o <<= 1) {
        int add = (t < 128 && t >= o) ? hist[t - o] : 0;
        __syncthreads();
        if (t < 128) hist[t] += add;
        __syncthreads();
    }
    if (t < 128) {
        int excl = beg + hist[t] - cnt;
        curls[t] = excl;
        if (n0 + t < NN) node_off[s * NN + n0 + t] = excl;
    }
    __syncthreads();

    for (int p = beg + t; p < end; p += 256) {
        int2 r = brec[p];
        int pos = atomicAdd(&curls[(r.x >> 17) & 127], 1);
        pairs[pos] = make_int2(r.x & 0x1FFFF, r.y);
    }
}

// ---------------------------------------------------------------------------
// Segmented gather v2: TWO segments per wave (2w, 2w+1 — same scale since N
// even). Joint 8+8 / 4+4 batches put up to 16 independent h-loads in flight
// per wave; per-segment drains handle remainders. All pair/offset loads stay
// wave-uniform (scalar pipe).
// ---------------------------------------------------------------------------
__device__ inline void drain_seg(
    const __hip_bfloat16* __restrict__ h, const int2* __restrict__ pairs,
    unsigned lane, int p, int end, float& acc0, float& acc1)
{
    for (; p + 8 <= end; p += 8) {
        int2 q[8];
        #pragma unroll
        for (int i = 0; i < 8; ++i) q[i] = pairs[p + i];
        float v[8];
        #pragma unroll
        for (int i = 0; i < 8; ++i)
            v[i] = __bfloat162float(h[((unsigned)q[i].x << 6) | lane]);
        #pragma unroll
        for (int i = 0; i < 8; i += 2) {
            acc0 = fmaf(__int_as_float(q[i].y), v[i], acc0);
            acc1 = fmaf(__int_as_float(q[i + 1].y), v[i + 1], acc1);
        }
    }
    if (p + 4 <= end) {
        int2 q[4];
        #pragma unroll
        for (int i = 0; i < 4; ++i) q[i] = pairs[p + i];
        float v[4];
        #pragma unroll
        for (int i = 0; i < 4; ++i)
            v[i] = __bfloat162float(h[((unsigned)q[i].x << 6) | lane]);
        acc0 = fmaf(__int_as_float(q[0].y), v[0], acc0);
        acc1 = fmaf(__int_as_float(q[1].y), v[1], acc1);
        acc0 = fmaf(__int_as_float(q[2].y), v[2], acc0);
        acc1 = fmaf(__int_as_float(q[3].y), v[3], acc1);
        p += 4;
    }
    if (p + 2 <= end) {
        int2 q0 = pairs[p];
        int2 q1 = pairs[p + 1];
        float v0 = __bfloat162float(h[((unsigned)q0.x << 6) | lane]);
        float v1 = __bfloat162float(h[((unsigned)q1.x << 6) | lane]);
        acc0 = fmaf(__int_as_float(q0.y), v0, acc0);
        acc1 = fmaf(__int_as_float(q1.y), v1, acc1);
        p += 2;
    }
    if (p < end) {
        int2 q = pairs[p];
        acc0 = fmaf(__int_as_float(q.y),
                    __bfloat162float(h[((unsigned)q.x << 6) | lane]), acc0);
    }
}

__global__ __launch_bounds__(256) void ufg_gather(
    const __hip_bfloat16* __restrict__ h,
    const int* __restrict__ off,
    const int2* __restrict__ pairs,
    const float* __restrict__ f1, const float* __restrict__ f2,
    const float* __restrict__ f3,
    __hip_bfloat16* __restrict__ agg)
{
    const unsigned lane = threadIdx.x & 63;
    int wp0 = blockIdx.x * 4 + (threadIdx.x >> 6);
    const int wp = __builtin_amdgcn_readfirstlane(wp0);
    if (wp >= (3 * NN) / 2) return;
    const int segA = wp * 2;
    const int s = segA / NN;               // same scale for segB (NN even)
    const int nA = segA - s * NN;

    const float* fp = (s == 0) ? f1 : (s == 1) ? f2 : f3;
    const float fv = fp[lane];

    const int begA = off[segA];
    const int endA = off[segA + 1];        // == begB
    const int endB = off[segA + 2];

    float aA0 = 0.f, aA1 = 0.f, aB0 = 0.f, aB1 = 0.f;
    int pA = begA, pB = endA;

    // joint 8+8: 16 independent loads in flight
    while (pA + 8 <= endA && pB + 8 <= endB) {
        int2 qa[8], qb[8];
        #pragma unroll
        for (int i = 0; i < 8; ++i) qa[i] = pairs[pA + i];
        #pragma unroll
        for (int i = 0; i < 8; ++i) qb[i] = pairs[pB + i];
        float va[8], vb[8];
        #pragma unroll
        for (int i = 0; i < 8; ++i)
            va[i] = __bfloat162float(h[((unsigned)qa[i].x << 6) | lane]);
        #pragma unroll
        for (int i = 0; i < 8; ++i)
            vb[i] = __bfloat162float(h[((unsigned)qb[i].x << 6) | lane]);
        #pragma unroll
        for (int i = 0; i < 8; i += 2) {
            aA0 = fmaf(__int_as_float(qa[i].y), va[i], aA0);
            aA1 = fmaf(__int_as_float(qa[i + 1].y), va[i + 1], aA1);
            aB0 = fmaf(__int_as_float(qb[i].y), vb[i], aB0);
            aB1 = fmaf(__int_as_float(qb[i + 1].y), vb[i + 1], aB1);
        }
        pA += 8;
        pB += 8;
    }
    // joint 4+4
    while (pA + 4 <= endA && pB + 4 <= endB) {
        int2 qa[4], qb[4];
        #pragma unroll
        for (int i = 0; i < 4; ++i) qa[i] = pairs[pA + i];
        #pragma unroll
        for (int i = 0; i < 4; ++i) qb[i] = pairs[pB + i];
        float va[4], vb[4];
        #pragma unroll
        for (int i = 0; i < 4; ++i)
            va[i] = __bfloat162float(h[((unsigned)qa[i].x << 6) | lane]);
        #pragma unroll
        for (int i = 0; i < 4; ++i)
            vb[i] = __bfloat162float(h[((unsigned)qb[i].x << 6) | lane]);
        aA0 = fmaf(__int_as_float(qa[0].y), va[0], aA0);
        aA1 = fmaf(__int_as_float(qa[1].y), va[1], aA1);
        aA0 = fmaf(__int_as_float(qa[2].y), va[2], aA0);
        aA1 = fmaf(__int_as_float(qa[3].y), va[3], aA1);
        aB0 = fmaf(__int_as_float(qb[0].y), vb[0], aB0);
        aB1 = fmaf(__int_as_float(qb[1].y), vb[1], aB1);
        aB0 = fmaf(__int_as_float(qb[2].y), vb[2], aB0);
        aB1 = fmaf(__int_as_float(qb[3].y), vb[3], aB1);
        pA += 4;
        pB += 4;
    }
    // per-segment drains
    drain_seg(h, pairs, lane, pA, endA, aA0, aA1);
    drain_seg(h, pairs, lane, pB, endB, aB0, aB1);

    agg[(size_t)nA * 192 + s * 64 + lane] =
        __float2bfloat16((aA0 + aA1) * fv);
    agg[(size_t)(nA + 1) * 192 + s * 64 + lane] =
        __float2bfloat16((aB0 + aB1) * fv);
}

// ---------------------------------------------------------------------------
// mlp1 + log_softmax (bf16 A)
// ---------------------------------------------------------------------------
__global__ __launch_bounds__(256) void gemm40_softmax(
    const __hip_bfloat16* __restrict__ A,
    const float* __restrict__ B,
    const float* __restrict__ bias,
    float* __restrict__ out,
    int nrows)
{
    __shared__ float As[32][68];
    __shared__ float Bs[32][64];

    const int tid = threadIdx.x;
    const int tx = tid & 15;
    const int ty = tid >> 4;
    const int row0 = blockIdx.x * 64;

    float acc[4][4] = {{0.f, 0.f, 0.f, 0.f}, {0.f, 0.f, 0.f, 0.f},
                       {0.f, 0.f, 0.f, 0.f}, {0.f, 0.f, 0.f, 0.f}};

    const int r = tid >> 2;
    const int koff = (tid & 3) * 8;
    const bool rowok = (row0 + r) < nrows;

    for (int k0 = 0; k0 < 192; k0 += 32) {
        float av[8];
        const __hip_bfloat16* ap = A + (size_t)(row0 + r) * 192 + (k0 + koff);
        if (rowok) {
            uint4 u = *(const uint4*)ap;
            av[0] = __uint_as_float(u.x << 16);
            av[1] = __uint_as_float(u.x & 0xFFFF0000u);
            av[2] = __uint_as_float(u.y << 16);
            av[3] = __uint_as_float(u.y & 0xFFFF0000u);
            av[4] = __uint_as_float(u.z << 16);
            av[5] = __uint_as_float(u.z & 0xFFFF0000u);
            av[6] = __uint_as_float(u.w << 16);
            av[7] = __uint_as_float(u.w & 0xFFFF0000u);
        } else {
            #pragma unroll
            for (int j = 0; j < 8; ++j) av[j] = 0.f;
        }
        #pragma unroll
        for (int j = 0; j < 8; ++j) As[koff + j][r] = fmaxf(av[j], 0.f);

        {
            int flat = tid * 8;
            int kk = flat >> 6;
            int c0 = flat & 63;
            #pragma unroll
            for (int j = 0; j < 8; ++j) {
                int cc = c0 + j;
                Bs[kk][cc] = (cc < 40) ? B[(size_t)(k0 + kk) * 40 + cc] : 0.f;
            }
        }
        __syncthreads();

        #pragma unroll
        for (int k = 0; k < 32; ++k) {
            float4 a = *(const float4*)&As[k][ty * 4];
            float4 b = *(const float4*)&Bs[k][tx * 4];
            acc[0][0] = fmaf(a.x, b.x, acc[0][0]);
            acc[0][1] = fmaf(a.x, b.y, acc[0][1]);
            acc[0][2] = fmaf(a.x, b.z, acc[0][2]);
            acc[0][3] = fmaf(a.x, b.w, acc[0][3]);
            acc[1][0] = fmaf(a.y, b.x, acc[1][0]);
            acc[1][1] = fmaf(a.y, b.y, acc[1][1]);
            acc[1][2] = fmaf(a.y, b.z, acc[1][2]);
            acc[1][3] = fmaf(a.y, b.w, acc[1][3]);
            acc[2][0] = fmaf(a.z, b.x, acc[2][0]);
            acc[2][1] = fmaf(a.z, b.y, acc[2][1]);
            acc[2][2] = fmaf(a.z, b.z, acc[2][2]);
            acc[2][3] = fmaf(a.z, b.w, acc[2][3]);
            acc[3][0] = fmaf(a.w, b.x, acc[3][0]);
            acc[3][1] = fmaf(a.w, b.y, acc[3][1]);
            acc[3][2] = fmaf(a.w, b.z, acc[3][2]);
            acc[3][3] = fmaf(a.w, b.w, acc[3][3]);
        }
        __syncthreads();
    }

    float bv[4];
    #pragma unroll
    for (int j = 0; j < 4; ++j) {
        int cc = tx * 4 + j;
        bv[j] = (cc < 40) ? bias[cc] : 0.f;
    }
    const bool colok = (tx < 10);

    #pragma unroll
    for (int i = 0; i < 4; ++i) {
        float v0 = colok ? acc[i][0] + bv[0] : -1e30f;
        float v1 = colok ? acc[i][1] + bv[1] : -1e30f;
        float v2 = colok ? acc[i][2] + bv[2] : -1e30f;
        float v3 = colok ? acc[i][3] + bv[3] : -1e30f;

        float mx = fmaxf(fmaxf(v0, v1), fmaxf(v2, v3));
        #pragma unroll
        for (int o = 1; o < 16; o <<= 1)
            mx = fmaxf(mx, __shfl_xor(mx, o, 64));

        float s = __expf(v0 - mx) + __expf(v1 - mx) +
                  __expf(v2 - mx) + __expf(v3 - mx);
        #pragma unroll
        for (int o = 1; o < 16; o <<= 1)
            s += __shfl_xor(s, o, 64);

        int rr = row0 + ty * 4 + i;
        if (rr < nrows && colok) {
            float ls = mx + __logf(s);
            *(float4*)(out + (size_t)rr * 40 + tx * 4) =
                make_float4(v0 - ls, v1 - ls, v2 - ls, v3 - ls);
        }
    }
}

// ---------------------------------------------------------------------------
extern "C" void kernel_launch(void* const* d_in, const int* in_sizes, int n_in,
                              void* d_out, int out_size, void* d_ws, size_t ws_size,
                              hipStream_t stream)
{
    const float* x    = (const float*)d_in[0];
    const int*   ei1  = (const int*)d_in[1];
    const float* ea1  = (const float*)d_in[2];
    const int*   ei2  = (const int*)d_in[3];
    const float* ea2  = (const float*)d_in[4];
    const int*   ei3  = (const int*)d_in[5];
    const float* ea3  = (const float*)d_in[6];
    const float* W1   = (const float*)d_in[7];
    const float* b1   = (const float*)d_in[8];
    const float* f1_1 = (const float*)d_in[9];
    const float* f2_1 = (const float*)d_in[10];
    const float* f1_2 = (const float*)d_in[11];
    const float* f2_2 = (const float*)d_in[12];
    const float* f1_3 = (const float*)d_in[13];
    const float* f2_3 = (const float*)d_in[14];
    const float* Wm2  = (const float*)d_in[15];
    const float* bm2  = (const float*)d_in[16];
    const float* Wm1  = (const float*)d_in[17];
    const float* bm1  = (const float*)d_in[18];
    float* out = (float*)d_out;

    // ws layout. agg bf16 [N][192]; brec (24 MB) aliases it.
    __hip_bfloat16* agg = (__hip_bfloat16*)d_ws;             // N*192 bf16
    int2*  brec = (int2*)d_ws;                               // 3E int2 (alias)
    char*  base = (char*)d_ws + (size_t)NN * 192 * 2;
    __hip_bfloat16* hbuf = (__hip_bfloat16*)base;            // N*64 bf16
    int*   cnt  = (int*)(base + (size_t)NN * 64 * 2);        // M2
    int*   offp = cnt + M2;                                  // M2
    int*   part = offp + M2;                                 // 1024
    int*   off_b = part + 1024;                              // NBK+1 (+pad)
    int*   node_off = off_b + NBK + 2;                       // 3N+1 (+pad)
    int2*  pairs = (int2*)(node_off + 3 * NN + 2);           // 3E int2
    __hip_bfloat16* w1t = (__hip_bfloat16*)
        (((uintptr_t)(pairs + 3 * EE) + 15) & ~(uintptr_t)15); // 64*512 bf16
    __hip_bfloat16* wm2t = w1t + 64 * 512;                   // 64*192 bf16

    const int gemm_grid = (NN + 63) / 64;     // 1563
    const int mfma2_grid = (NN + 127) / 128;  // 782
    const int gat_grid = ((3 * NN / 2) + 3) / 4;   // 37500
    const int P = (M2 + 1023) / 1024;         // 587

    // ---- prep: weight transposes + dst-sort edges
    build_w1t<<<128, 256, 0, stream>>>(W1, w1t);
    build_wm2t<<<48, 256, 0, stream>>>(Wm2, wm2t);
    part_count<<<NBLK_P, 1024, 0, stream>>>(ei1, ei2, ei3, cnt);
    scan_a<<<P, 1024, 0, stream>>>(cnt, offp, part, M2);
    scan_b<<<1, 1024, 0, stream>>>(part, P);
    scan_c<<<(M2 + 255) / 256, 256, 0, stream>>>(offp, off_b, part, M2);
    part_scatter<<<NBLK_P, 1024, 0, stream>>>(ei1, ea1, ei2, ea2, ei3, ea3,
                                              offp, brec);
    bucket_refine<<<NBK, 256, 0, stream>>>(brec, off_b, node_off, pairs);

    // ---- block 1 ----
    gemm1_mfma<<<gemm_grid, 256, 0, stream>>>(x, w1t, b1, hbuf, NN);
    ufg_gather<<<gat_grid, 256, 0, stream>>>(hbuf, node_off, pairs,
                                             f1_1, f1_2, f1_3, agg);
    gemm2_mfma<<<mfma2_grid, 256, 0, stream>>>(agg, wm2t, bm2, hbuf, NN);

    // ---- block 2 ----
    ufg_gather<<<gat_grid, 256, 0, stream>>>(hbuf, node_off, pairs,
                                             f2_1, f2_2, f2_3, agg);
    gemm40_softmax<<<gemm_grid, 256, 0, stream>>>(agg, Wm1, bm1, out, NN);
}

// Round 15
// 332.787 us; speedup vs baseline: 1.6725x; 1.0963x over previous
//
#include <hip/hip_runtime.h>
#include <hip/hip_bf16.h>

#define NN 100000
#define FF 500
#define HH 64
#define CC 40
#define EE 1000000
#define NB 782            // buckets per scale: ceil(100000/128)
#define NBK 2346          // 3*NB
#define NBLK_P 256        // partition blocks
#define M2 (NBK * NBLK_P) // 600576 counters

typedef __attribute__((ext_vector_type(8))) short short8v;   // 8 bf16
typedef __attribute__((ext_vector_type(4))) float f32x4;

// relu on 2 packed bf16 (sign-mask select)
__device__ inline unsigned relu2bf16(unsigned u)
{
    unsigned r = (u & 0x00008000u) ? (u & 0xFFFF0000u) : u;
    return (r & 0x80000000u) ? (r & 0x0000FFFFu) : r;
}

// ---------------------------------------------------------------------------
// Weight transposes (f32 -> bf16, transposed, padded)
// ---------------------------------------------------------------------------
__global__ __launch_bounds__(256) void build_w1t(
    const float* __restrict__ W1, __hip_bfloat16* __restrict__ W1t)
{
    int idx = blockIdx.x * 256 + threadIdx.x;
    if (idx >= 64 * 512) return;
    int col = idx >> 9;
    int k = idx & 511;
    W1t[idx] = (k < FF) ? __float2bfloat16(W1[(size_t)k * 64 + col])
                        : __float2bfloat16(0.f);
}

__global__ __launch_bounds__(256) void build_wm2t(
    const float* __restrict__ Wm2, __hip_bfloat16* __restrict__ Wm2t)
{
    int idx = blockIdx.x * 256 + threadIdx.x;
    if (idx >= 64 * 192) return;
    int col = idx / 192;
    int k = idx - col * 192;
    Wm2t[idx] = __float2bfloat16(Wm2[(size_t)k * 64 + col]);
}

// Wm1 [192][40] f32 -> [64][192] bf16, cols >= 40 zero
__global__ __launch_bounds__(256) void build_wm1t(
    const float* __restrict__ Wm1, __hip_bfloat16* __restrict__ Wm1t)
{
    int idx = blockIdx.x * 256 + threadIdx.x;
    if (idx >= 64 * 192) return;
    int col = idx / 192;
    int k = idx - col * 192;
    Wm1t[idx] = (col < 40) ? __float2bfloat16(Wm1[(size_t)k * 40 + col])
                           : __float2bfloat16(0.f);
}

// ---------------------------------------------------------------------------
// gemm1 via MFMA: 64-row tiles + register prefetch of the next k-tile.
// H[N][64] = bf16(X[N][500] @ W1[500][64] + b1)
// ---------------------------------------------------------------------------
__global__ __launch_bounds__(256) void gemm1_mfma(
    const float* __restrict__ X,
    const __hip_bfloat16* __restrict__ W1t,   // [64][512]
    const float* __restrict__ bias,           // [64]
    __hip_bfloat16* __restrict__ H,           // [N][64]
    int nrows)
{
    __shared__ __hip_bfloat16 As[64][40];
    __shared__ __hip_bfloat16 Bs[64][40];

    const int t = threadIdx.x;
    const int lane = t & 63;
    const int w = t >> 6;
    const int row0 = blockIdx.x * 64;
    const int kg = lane >> 4;
    const int lr = lane & 15;

    f32x4 acc[4] = {};

    const int arow = t >> 2;
    const int akq = (t & 3) * 8;
    const int bcol = t >> 2;
    const int bkq = (t & 3) * 8;

    int grow = row0 + arow;
    const float* xp = X + (size_t)(grow < nrows ? grow : nrows - 1) * FF;

    float va[8];
    uint4 vb;
    {
        float4 a0 = *(const float4*)(xp + akq);
        float4 a1 = *(const float4*)(xp + akq + 4);
        va[0]=a0.x; va[1]=a0.y; va[2]=a0.z; va[3]=a0.w;
        va[4]=a1.x; va[5]=a1.y; va[6]=a1.z; va[7]=a1.w;
        vb = *(const uint4*)(W1t + (size_t)bcol * 512 + bkq);
    }

    for (int k0 = 0; k0 < FF; k0 += 32) {
        {
            unsigned q[4];
            #pragma unroll
            for (int i = 0; i < 4; ++i) {
                __hip_bfloat162 pp =
                    __float22bfloat162_rn(make_float2(va[2*i], va[2*i+1]));
                q[i] = *(unsigned*)&pp;
            }
            *(uint4*)&As[arow][akq] = make_uint4(q[0], q[1], q[2], q[3]);
            *(uint4*)&Bs[bcol][bkq] = vb;
        }

        const int kn = k0 + 32;
        float va2[8];
        uint4 vb2;
        if (kn < FF) {
            if (kn + 32 <= FF) {
                float4 a0 = *(const float4*)(xp + kn + akq);
                float4 a1 = *(const float4*)(xp + kn + akq + 4);
                va2[0]=a0.x; va2[1]=a0.y; va2[2]=a0.z; va2[3]=a0.w;
                va2[4]=a1.x; va2[5]=a1.y; va2[6]=a1.z; va2[7]=a1.w;
            } else {
                #pragma unroll
                for (int j = 0; j < 8; ++j) {
                    int kk = kn + akq + j;
                    va2[j] = (kk < FF) ? xp[kk] : 0.f;
                }
            }
            vb2 = *(const uint4*)(W1t + (size_t)bcol * 512 + kn + bkq);
        }
        __syncthreads();

        short8v a0 = *(const short8v*)&As[w * 16 + lr][kg * 8];
        short8v b0 = *(const short8v*)&Bs[lr][kg * 8];
        short8v b1 = *(const short8v*)&Bs[16 + lr][kg * 8];
        short8v b2 = *(const short8v*)&Bs[32 + lr][kg * 8];
        short8v b3 = *(const short8v*)&Bs[48 + lr][kg * 8];
        acc[0] = __builtin_amdgcn_mfma_f32_16x16x32_bf16(a0, b0, acc[0], 0, 0, 0);
        acc[1] = __builtin_amdgcn_mfma_f32_16x16x32_bf16(a0, b1, acc[1], 0, 0, 0);
        acc[2] = __builtin_amdgcn_mfma_f32_16x16x32_bf16(a0, b2, acc[2], 0, 0, 0);
        acc[3] = __builtin_amdgcn_mfma_f32_16x16x32_bf16(a0, b3, acc[3], 0, 0, 0);
        __syncthreads();

        if (kn < FF) {
            #pragma unroll
            for (int j = 0; j < 8; ++j) va[j] = va2[j];
            vb = vb2;
        }
    }

    float bv[4];
    #pragma unroll
    for (int n = 0; n < 4; ++n) bv[n] = bias[n * 16 + lr];

    #pragma unroll
    for (int n = 0; n < 4; ++n) {
        #pragma unroll
        for (int r = 0; r < 4; ++r) {
            int row = row0 + w * 16 + kg * 4 + r;
            if (row < nrows)
                H[(size_t)row * 64 + n * 16 + lr] =
                    __float2bfloat16(acc[n][r] + bv[n]);
        }
    }
}

// ---------------------------------------------------------------------------
// mlp2 via MFMA: H[N][64] = bf16(relu(A[N][192]) @ Wm2[192][64] + bm2)
// ---------------------------------------------------------------------------
__global__ __launch_bounds__(256) void gemm2_mfma(
    const __hip_bfloat16* __restrict__ A,     // [N][192]
    const __hip_bfloat16* __restrict__ Bt,    // [64][192]
    const float* __restrict__ bias,           // [64]
    __hip_bfloat16* __restrict__ H,           // [N][64]
    int nrows)
{
    __shared__ __hip_bfloat16 As[128][40];
    __shared__ __hip_bfloat16 Bs[64][40];

    const int t = threadIdx.x;
    const int lane = t & 63;
    const int w = t >> 6;
    const int row0 = blockIdx.x * 128;
    const int wrow = w * 32;
    const int kg = lane >> 4;
    const int lr = lane & 15;

    f32x4 acc[2][4] = {};

    const int arow = t >> 1;
    const int akh = t & 1;
    const int bcol = t >> 2;
    const int bkq = t & 3;

    for (int k0 = 0; k0 < 192; k0 += 32) {
        {
            int grow = row0 + arow;
            int gr = grow < nrows ? grow : nrows - 1;
            const __hip_bfloat16* ap = A + (size_t)gr * 192 + k0 + akh * 16;
            uint4 u0 = *(const uint4*)ap;
            uint4 u1 = *(const uint4*)(ap + 8);
            u0.x = relu2bf16(u0.x); u0.y = relu2bf16(u0.y);
            u0.z = relu2bf16(u0.z); u0.w = relu2bf16(u0.w);
            u1.x = relu2bf16(u1.x); u1.y = relu2bf16(u1.y);
            u1.z = relu2bf16(u1.z); u1.w = relu2bf16(u1.w);
            *(uint4*)&As[arow][akh * 16]     = u0;
            *(uint4*)&As[arow][akh * 16 + 8] = u1;
        }
        *(uint4*)&Bs[bcol][bkq * 8] =
            *(const uint4*)(Bt + (size_t)bcol * 192 + k0 + bkq * 8);
        __syncthreads();

        short8v a0 = *(const short8v*)&As[wrow + lr][kg * 8];
        short8v a1 = *(const short8v*)&As[wrow + 16 + lr][kg * 8];
        short8v b0 = *(const short8v*)&Bs[lr][kg * 8];
        short8v b1 = *(const short8v*)&Bs[16 + lr][kg * 8];
        short8v b2 = *(const short8v*)&Bs[32 + lr][kg * 8];
        short8v b3 = *(const short8v*)&Bs[48 + lr][kg * 8];
        acc[0][0] = __builtin_amdgcn_mfma_f32_16x16x32_bf16(a0, b0, acc[0][0], 0, 0, 0);
        acc[0][1] = __builtin_amdgcn_mfma_f32_16x16x32_bf16(a0, b1, acc[0][1], 0, 0, 0);
        acc[0][2] = __builtin_amdgcn_mfma_f32_16x16x32_bf16(a0, b2, acc[0][2], 0, 0, 0);
        acc[0][3] = __builtin_amdgcn_mfma_f32_16x16x32_bf16(a0, b3, acc[0][3], 0, 0, 0);
        acc[1][0] = __builtin_amdgcn_mfma_f32_16x16x32_bf16(a1, b0, acc[1][0], 0, 0, 0);
        acc[1][1] = __builtin_amdgcn_mfma_f32_16x16x32_bf16(a1, b1, acc[1][1], 0, 0, 0);
        acc[1][2] = __builtin_amdgcn_mfma_f32_16x16x32_bf16(a1, b2, acc[1][2], 0, 0, 0);
        acc[1][3] = __builtin_amdgcn_mfma_f32_16x16x32_bf16(a1, b3, acc[1][3], 0, 0, 0);
        __syncthreads();
    }

    float bv[4];
    #pragma unroll
    for (int n = 0; n < 4; ++n) bv[n] = bias[n * 16 + lr];

    #pragma unroll
    for (int m = 0; m < 2; ++m) {
        #pragma unroll
        for (int n = 0; n < 4; ++n) {
            #pragma unroll
            for (int r = 0; r < 4; ++r) {
                int row = row0 + wrow + m * 16 + kg * 4 + r;
                if (row < nrows)
                    H[(size_t)row * 64 + n * 16 + lr] =
                        __float2bfloat16(acc[m][n][r] + bv[n]);
            }
        }
    }
}

// ---------------------------------------------------------------------------
// mlp1 + log_softmax via MFMA: out[N][40] =
//   log_softmax(relu(A[N][192]) @ Wm1[192][40] + bm1)
// Same tile structure as gemm2; B padded to 64 cols (>=40 zero). Epilogue:
// per-row masked max/sum via 16-lane shfl_xor (row's cols live in 4 n-frags
// x 16 lanes sharing lane>>4).
// ---------------------------------------------------------------------------
__global__ __launch_bounds__(256) void gemm3_mfma(
    const __hip_bfloat16* __restrict__ A,     // [N][192]
    const __hip_bfloat16* __restrict__ Bt,    // [64][192] (cols>=40 zero)
    const float* __restrict__ bias,           // [40]
    float* __restrict__ out,                  // [N][40]
    int nrows)
{
    __shared__ __hip_bfloat16 As[128][40];
    __shared__ __hip_bfloat16 Bs[64][40];

    const int t = threadIdx.x;
    const int lane = t & 63;
    const int w = t >> 6;
    const int row0 = blockIdx.x * 128;
    const int wrow = w * 32;
    const int kg = lane >> 4;
    const int lr = lane & 15;

    f32x4 acc[2][4] = {};

    const int arow = t >> 1;
    const int akh = t & 1;
    const int bcol = t >> 2;
    const int bkq = t & 3;

    for (int k0 = 0; k0 < 192; k0 += 32) {
        {
            int grow = row0 + arow;
            int gr = grow < nrows ? grow : nrows - 1;
            const __hip_bfloat16* ap = A + (size_t)gr * 192 + k0 + akh * 16;
            uint4 u0 = *(const uint4*)ap;
            uint4 u1 = *(const uint4*)(ap + 8);
            u0.x = relu2bf16(u0.x); u0.y = relu2bf16(u0.y);
            u0.z = relu2bf16(u0.z); u0.w = relu2bf16(u0.w);
            u1.x = relu2bf16(u1.x); u1.y = relu2bf16(u1.y);
            u1.z = relu2bf16(u1.z); u1.w = relu2bf16(u1.w);
            *(uint4*)&As[arow][akh * 16]     = u0;
            *(uint4*)&As[arow][akh * 16 + 8] = u1;
        }
        *(uint4*)&Bs[bcol][bkq * 8] =
            *(const uint4*)(Bt + (size_t)bcol * 192 + k0 + bkq * 8);
        __syncthreads();

        short8v a0 = *(const short8v*)&As[wrow + lr][kg * 8];
        short8v a1 = *(const short8v*)&As[wrow + 16 + lr][kg * 8];
        short8v b0 = *(const short8v*)&Bs[lr][kg * 8];
        short8v b1 = *(const short8v*)&Bs[16 + lr][kg * 8];
        short8v b2 = *(const short8v*)&Bs[32 + lr][kg * 8];
        short8v b3 = *(const short8v*)&Bs[48 + lr][kg * 8];
        acc[0][0] = __builtin_amdgcn_mfma_f32_16x16x32_bf16(a0, b0, acc[0][0], 0, 0, 0);
        acc[0][1] = __builtin_amdgcn_mfma_f32_16x16x32_bf16(a0, b1, acc[0][1], 0, 0, 0);
        acc[0][2] = __builtin_amdgcn_mfma_f32_16x16x32_bf16(a0, b2, acc[0][2], 0, 0, 0);
        acc[0][3] = __builtin_amdgcn_mfma_f32_16x16x32_bf16(a0, b3, acc[0][3], 0, 0, 0);
        acc[1][0] = __builtin_amdgcn_mfma_f32_16x16x32_bf16(a1, b0, acc[1][0], 0, 0, 0);
        acc[1][1] = __builtin_amdgcn_mfma_f32_16x16x32_bf16(a1, b1, acc[1][1], 0, 0, 0);
        acc[1][2] = __builtin_amdgcn_mfma_f32_16x16x32_bf16(a1, b2, acc[1][2], 0, 0, 0);
        acc[1][3] = __builtin_amdgcn_mfma_f32_16x16x32_bf16(a1, b3, acc[1][3], 0, 0, 0);
        __syncthreads();
    }

    // bias / validity per n-fragment (col = n*16 + lr)
    float bv[4];
    bool vld[4];
    #pragma unroll
    for (int n = 0; n < 4; ++n) {
        int col = n * 16 + lr;
        vld[n] = col < 40;
        bv[n] = vld[n] ? bias[col] : 0.f;
    }

    #pragma unroll
    for (int m = 0; m < 2; ++m) {
        #pragma unroll
        for (int r = 0; r < 4; ++r) {
            int row = row0 + wrow + m * 16 + kg * 4 + r;
            float v[4];
            #pragma unroll
            for (int n = 0; n < 4; ++n)
                v[n] = vld[n] ? acc[m][n][r] + bv[n] : -1e30f;

            float mx = fmaxf(fmaxf(v[0], v[1]), fmaxf(v[2], v[3]));
            #pragma unroll
            for (int o = 1; o < 16; o <<= 1)
                mx = fmaxf(mx, __shfl_xor(mx, o, 64));

            float sum = 0.f;
            #pragma unroll
            for (int n = 0; n < 4; ++n)
                sum += vld[n] ? __expf(v[n] - mx) : 0.f;
            #pragma unroll
            for (int o = 1; o < 16; o <<= 1)
                sum += __shfl_xor(sum, o, 64);

            if (row < nrows) {
                float ls = mx + __logf(sum);
                #pragma unroll
                for (int n = 0; n < 4; ++n)
                    if (vld[n])
                        out[(size_t)row * 40 + n * 16 + lr] = v[n] - ls;
            }
        }
    }
}

// ---------------------------------------------------------------------------
// Radix partition pass 1 (256 blocks -> all CUs)
// ---------------------------------------------------------------------------
__global__ __launch_bounds__(1024) void part_count(
    const int* __restrict__ ei1, const int* __restrict__ ei2,
    const int* __restrict__ ei3, int* __restrict__ cnt)
{
    __shared__ int lc[NBK];
    const int t = threadIdx.x;
    for (int j = t; j < NBK; j += 1024) lc[j] = 0;
    __syncthreads();

    const int chunk = (3 * EE + NBLK_P - 1) / NBLK_P;
    const int b0 = blockIdx.x * chunk;
    int b1 = b0 + chunk;
    if (b1 > 3 * EE) b1 = 3 * EE;

    for (int i = b0 + t; i < b1; i += 1024) {
        int s = i / EE;
        int e = i - s * EE;
        const int* ei = (s == 0) ? ei1 : (s == 1) ? ei2 : ei3;
        atomicAdd(&lc[s * NB + (ei[EE + e] >> 7)], 1);
    }
    __syncthreads();
    for (int j = t; j < NBK; j += 1024)
        cnt[j * NBLK_P + blockIdx.x] = lc[j];
}

__global__ __launch_bounds__(1024) void scan_a(
    const int* __restrict__ cnt, int* __restrict__ off,
    int* __restrict__ partials, int M)
{
    __shared__ int sh[1024];
    int t = threadIdx.x;
    int i = blockIdx.x * 1024 + t;
    int v = (i < M) ? cnt[i] : 0;
    sh[t] = v;
    __syncthreads();
    #pragma unroll
    for (int o = 1; o < 1024; o <<= 1) {
        int add = (t >= o) ? sh[t - o] : 0;
        __syncthreads();
        sh[t] += add;
        __syncthreads();
    }
    if (i < M) off[i] = sh[t] - v;
    if (t == 1023) partials[blockIdx.x] = sh[1023];
}

__global__ __launch_bounds__(1024) void scan_b(int* __restrict__ partials, int P)
{
    __shared__ int sh[1024];
    int t = threadIdx.x;
    int v = (t < P) ? partials[t] : 0;
    sh[t] = v;
    __syncthreads();
    #pragma unroll
    for (int o = 1; o < 1024; o <<= 1) {
        int add = (t >= o) ? sh[t - o] : 0;
        __syncthreads();
        sh[t] += add;
        __syncthreads();
    }
    if (t < P) partials[t] = sh[t] - v;
}

__global__ __launch_bounds__(256) void scan_c(
    int* __restrict__ off, int* __restrict__ off_b,
    const int* __restrict__ partials, int M)
{
    int i = blockIdx.x * 256 + threadIdx.x;
    if (i < M) {
        int v = off[i] + partials[i >> 10];
        off[i] = v;
        if ((i & (NBLK_P - 1)) == 0) off_b[i / NBLK_P] = v;
    }
    if (i == 0) off_b[NBK] = 3 * EE;
}

__global__ __launch_bounds__(1024) void part_scatter(
    const int* __restrict__ ei1, const float* __restrict__ ea1,
    const int* __restrict__ ei2, const float* __restrict__ ea2,
    const int* __restrict__ ei3, const float* __restrict__ ea3,
    const int* __restrict__ offp, int2* __restrict__ brec)
{
    __shared__ int lcur[NBK];
    const int t = threadIdx.x;
    for (int j = t; j < NBK; j += 1024)
        lcur[j] = offp[j * NBLK_P + blockIdx.x];
    __syncthreads();

    const int chunk = (3 * EE + NBLK_P - 1) / NBLK_P;
    const int b0 = blockIdx.x * chunk;
    int b1 = b0 + chunk;
    if (b1 > 3 * EE) b1 = 3 * EE;

    for (int i = b0 + t; i < b1; i += 1024) {
        int s = i / EE;
        int e = i - s * EE;
        const int* ei = (s == 0) ? ei1 : (s == 1) ? ei2 : ei3;
        const float* ea = (s == 0) ? ea1 : (s == 1) ? ea2 : ea3;
        int src = ei[e];
        int dst = ei[EE + e];
        float w = ea[e];
        int pos = atomicAdd(&lcur[s * NB + (dst >> 7)], 1);
        brec[pos] = make_int2(src | ((dst & 127) << 17), __float_as_int(w));
    }
}

__global__ __launch_bounds__(256) void bucket_refine(
    const int2* __restrict__ brec,
    const int* __restrict__ off_b,
    int* __restrict__ node_off,
    int2* __restrict__ pairs)
{
    __shared__ int hist[128];
    __shared__ int curls[128];
    const int t = threadIdx.x;
    const int bk = blockIdx.x;
    const int s = bk / NB;
    const int b = bk - s * NB;
    const int n0 = b << 7;
    const int beg = off_b[bk];
    const int end = off_b[bk + 1];

    if (bk == 0 && t == 0) node_off[3 * NN] = 3 * EE;
    if (t < 128) hist[t] = 0;
    __syncthreads();

    for (int p = beg + t; p < end; p += 256)
        atomicAdd(&hist[(brec[p].x >> 17) & 127], 1);
    __syncthreads();

    int cnt = (t < 128) ? hist[t] : 0;
    #pragma unroll
    for (int o = 1; o < 128; o <<= 1) {
        int add = (t < 128 && t >= o) ? hist[t - o] : 0;
        __syncthreads();
        if (t < 128) hist[t] += add;
        __syncthreads();
    }
    if (t < 128) {
        int excl = beg + hist[t] - cnt;
        curls[t] = excl;
        if (n0 + t < NN) node_off[s * NN + n0 + t] = excl;
    }
    __syncthreads();

    for (int p = beg + t; p < end; p += 256) {
        int2 r = brec[p];
        int pos = atomicAdd(&curls[(r.x >> 17) & 127], 1);
        pairs[pos] = make_int2(r.x & 0x1FFFF, r.y);
    }
}

// ---------------------------------------------------------------------------
// Segmented gather v3: FOUR segments per wave (4w..4w+3, same scale since
// NN%4==0). Joint 4x4 batches keep 16 independent h-loads in flight for
// nearly all edges (needs only deg>=4 per segment); pair-joints and drains
// handle remainders. Pair/offset loads wave-uniform (scalar pipe).
// ---------------------------------------------------------------------------
__device__ inline void joint44(
    const __hip_bfloat16* __restrict__ h, const int2* __restrict__ pairs,
    unsigned lane, int& pA, int endA, int& pB, int endB,
    float& aA0, float& aA1, float& aB0, float& aB1)
{
    while (pA + 4 <= endA && pB + 4 <= endB) {
        int2 qa[4], qb[4];
        #pragma unroll
        for (int i = 0; i < 4; ++i) qa[i] = pairs[pA + i];
        #pragma unroll
        for (int i = 0; i < 4; ++i) qb[i] = pairs[pB + i];
        float va[4], vb[4];
        #pragma unroll
        for (int i = 0; i < 4; ++i)
            va[i] = __bfloat162float(h[((unsigned)qa[i].x << 6) | lane]);
        #pragma unroll
        for (int i = 0; i < 4; ++i)
            vb[i] = __bfloat162float(h[((unsigned)qb[i].x << 6) | lane]);
        aA0 = fmaf(__int_as_float(qa[0].y), va[0], aA0);
        aA1 = fmaf(__int_as_float(qa[1].y), va[1], aA1);
        aA0 = fmaf(__int_as_float(qa[2].y), va[2], aA0);
        aA1 = fmaf(__int_as_float(qa[3].y), va[3], aA1);
        aB0 = fmaf(__int_as_float(qb[0].y), vb[0], aB0);
        aB1 = fmaf(__int_as_float(qb[1].y), vb[1], aB1);
        aB0 = fmaf(__int_as_float(qb[2].y), vb[2], aB0);
        aB1 = fmaf(__int_as_float(qb[3].y), vb[3], aB1);
        pA += 4;
        pB += 4;
    }
}

__device__ inline void drain_seg(
    const __hip_bfloat16* __restrict__ h, const int2* __restrict__ pairs,
    unsigned lane, int p, int end, float& acc0, float& acc1)
{
    for (; p + 8 <= end; p += 8) {
        int2 q[8];
        #pragma unroll
        for (int i = 0; i < 8; ++i) q[i] = pairs[p + i];
        float v[8];
        #pragma unroll
        for (int i = 0; i < 8; ++i)
            v[i] = __bfloat162float(h[((unsigned)q[i].x << 6) | lane]);
        #pragma unroll
        for (int i = 0; i < 8; i += 2) {
            acc0 = fmaf(__int_as_float(q[i].y), v[i], acc0);
            acc1 = fmaf(__int_as_float(q[i + 1].y), v[i + 1], acc1);
        }
    }
    if (p + 4 <= end) {
        int2 q[4];
        #pragma unroll
        for (int i = 0; i < 4; ++i) q[i] = pairs[p + i];
        float v[4];
        #pragma unroll
        for (int i = 0; i < 4; ++i)
            v[i] = __bfloat162float(h[((unsigned)q[i].x << 6) | lane]);
        acc0 = fmaf(__int_as_float(q[0].y), v[0], acc0);
        acc1 = fmaf(__int_as_float(q[1].y), v[1], acc1);
        acc0 = fmaf(__int_as_float(q[2].y), v[2], acc0);
        acc1 = fmaf(__int_as_float(q[3].y), v[3], acc1);
        p += 4;
    }
    if (p + 2 <= end) {
        int2 q0 = pairs[p];
        int2 q1 = pairs[p + 1];
        float v0 = __bfloat162float(h[((unsigned)q0.x << 6) | lane]);
        float v1 = __bfloat162float(h[((unsigned)q1.x << 6) | lane]);
        acc0 = fmaf(__int_as_float(q0.y), v0, acc0);
        acc1 = fmaf(__int_as_float(q1.y), v1, acc1);
        p += 2;
    }
    if (p < end) {
        int2 q = pairs[p];
        acc0 = fmaf(__int_as_float(q.y),
                    __bfloat162float(h[((unsigned)q.x << 6) | lane]), acc0);
    }
}

__global__ __launch_bounds__(256) void ufg_gather(
    const __hip_bfloat16* __restrict__ h,
    const int* __restrict__ off,
    const int2* __restrict__ pairs,
    const float* __restrict__ f1, const float* __restrict__ f2,
    const float* __restrict__ f3,
    __hip_bfloat16* __restrict__ agg)
{
    const unsigned lane = threadIdx.x & 63;
    int wq0 = blockIdx.x * 4 + (threadIdx.x >> 6);
    const int wq = __builtin_amdgcn_readfirstlane(wq0);
    if (wq >= (3 * NN) / 4) return;
    const int seg0 = wq * 4;
    const int s = seg0 / NN;               // same scale for all 4 (NN%4==0)
    const int n0 = seg0 - s * NN;

    const float* fp = (s == 0) ? f1 : (s == 1) ? f2 : f3;
    const float fv = fp[lane];

    const int o0 = off[seg0];
    const int o1 = off[seg0 + 1];
    const int o2 = off[seg0 + 2];
    const int o3 = off[seg0 + 3];
    const int o4 = off[seg0 + 4];

    float aA0 = 0.f, aA1 = 0.f, aB0 = 0.f, aB1 = 0.f;
    float aC0 = 0.f, aC1 = 0.f, aD0 = 0.f, aD1 = 0.f;
    int pA = o0, pB = o1, pC = o2, pD = o3;

    // joint 4x4x4x4: 16 independent loads in flight
    while (pA + 4 <= o1 && pB + 4 <= o2 && pC + 4 <= o3 && pD + 4 <= o4) {
        int2 q[16];
        #pragma unroll
        for (int i = 0; i < 4; ++i) {
            q[i]      = pairs[pA + i];
            q[4 + i]  = pairs[pB + i];
            q[8 + i]  = pairs[pC + i];
            q[12 + i] = pairs[pD + i];
        }
        float v[16];
        #pragma unroll
        for (int i = 0; i < 16; ++i)
            v[i] = __bfloat162float(h[((unsigned)q[i].x << 6) | lane]);
        aA0 = fmaf(__int_as_float(q[0].y),  v[0],  aA0);
        aA1 = fmaf(__int_as_float(q[1].y),  v[1],  aA1);
        aA0 = fmaf(__int_as_float(q[2].y),  v[2],  aA0);
        aA1 = fmaf(__int_as_float(q[3].y),  v[3],  aA1);
        aB0 = fmaf(__int_as_float(q[4].y),  v[4],  aB0);
        aB1 = fmaf(__int_as_float(q[5].y),  v[5],  aB1);
        aB0 = fmaf(__int_as_float(q[6].y),  v[6],  aB0);
        aB1 = fmaf(__int_as_float(q[7].y),  v[7],  aB1);
        aC0 = fmaf(__int_as_float(q[8].y),  v[8],  aC0);
        aC1 = fmaf(__int_as_float(q[9].y),  v[9],  aC1);
        aC0 = fmaf(__int_as_float(q[10].y), v[10], aC0);
        aC1 = fmaf(__int_as_float(q[11].y), v[11], aC1);
        aD0 = fmaf(__int_as_float(q[12].y), v[12], aD0);
        aD1 = fmaf(__int_as_float(q[13].y), v[13], aD1);
        aD0 = fmaf(__int_as_float(q[14].y), v[14], aD0);
        aD1 = fmaf(__int_as_float(q[15].y), v[15], aD1);
        pA += 4; pB += 4; pC += 4; pD += 4;
    }
    // pairwise joints (8 in flight)
    joint44(h, pairs, lane, pA, o1, pB, o2, aA0, aA1, aB0, aB1);
    joint44(h, pairs, lane, pC, o3, pD, o4, aC0, aC1, aD0, aD1);
    joint44(h, pairs, lane, pA, o1, pC, o3, aA0, aA1, aC0, aC1);
    joint44(h, pairs, lane, pB, o2, pD, o4, aB0, aB1, aD0, aD1);
    // per-segment drains
    drain_seg(h, pairs, lane, pA, o1, aA0, aA1);
    drain_seg(h, pairs, lane, pB, o2, aB0, aB1);
    drain_seg(h, pairs, lane, pC, o3, aC0, aC1);
    drain_seg(h, pairs, lane, pD, o4, aD0, aD1);

    const size_t basei = (size_t)n0 * 192 + s * 64 + lane;
    agg[basei]       = __float2bfloat16((aA0 + aA1) * fv);
    agg[basei + 192] = __float2bfloat16((aB0 + aB1) * fv);
    agg[basei + 384] = __float2bfloat16((aC0 + aC1) * fv);
    agg[basei + 576] = __float2bfloat16((aD0 + aD1) * fv);
}

// ---------------------------------------------------------------------------
extern "C" void kernel_launch(void* const* d_in, const int* in_sizes, int n_in,
                              void* d_out, int out_size, void* d_ws, size_t ws_size,
                              hipStream_t stream)
{
    const float* x    = (const float*)d_in[0];
    const int*   ei1  = (const int*)d_in[1];
    const float* ea1  = (const float*)d_in[2];
    const int*   ei2  = (const int*)d_in[3];
    const float* ea2  = (const float*)d_in[4];
    const int*   ei3  = (const int*)d_in[5];
    const float* ea3  = (const float*)d_in[6];
    const float* W1   = (const float*)d_in[7];
    const float* b1   = (const float*)d_in[8];
    const float* f1_1 = (const float*)d_in[9];
    const float* f2_1 = (const float*)d_in[10];
    const float* f1_2 = (const float*)d_in[11];
    const float* f2_2 = (const float*)d_in[12];
    const float* f1_3 = (const float*)d_in[13];
    const float* f2_3 = (const float*)d_in[14];
    const float* Wm2  = (const float*)d_in[15];
    const float* bm2  = (const float*)d_in[16];
    const float* Wm1  = (const float*)d_in[17];
    const float* bm1  = (const float*)d_in[18];
    float* out = (float*)d_out;

    // ws layout. agg bf16 [N][192]; brec (24 MB) aliases it.
    __hip_bfloat16* agg = (__hip_bfloat16*)d_ws;             // N*192 bf16
    int2*  brec = (int2*)d_ws;                               // 3E int2 (alias)
    char*  base = (char*)d_ws + (size_t)NN * 192 * 2;
    __hip_bfloat16* hbuf = (__hip_bfloat16*)base;            // N*64 bf16
    int*   cnt  = (int*)(base + (size_t)NN * 64 * 2);        // M2
    int*   offp = cnt + M2;                                  // M2
    int*   part = offp + M2;                                 // 1024
    int*   off_b = part + 1024;                              // NBK+1 (+pad)
    int*   node_off = off_b + NBK + 2;                       // 3N+1 (+pad)
    int2*  pairs = (int2*)(node_off + 3 * NN + 2);           // 3E int2
    __hip_bfloat16* w1t = (__hip_bfloat16*)
        (((uintptr_t)(pairs + 3 * EE) + 15) & ~(uintptr_t)15); // 64*512 bf16
    __hip_bfloat16* wm2t = w1t + 64 * 512;                   // 64*192 bf16
    __hip_bfloat16* wm1t = wm2t + 64 * 192;                  // 64*192 bf16

    const int gemm_grid = (NN + 63) / 64;     // 1563
    const int mfma2_grid = (NN + 127) / 128;  // 782
    const int gat_grid = ((3 * NN / 4) + 3) / 4;   // 18750
    const int P = (M2 + 1023) / 1024;         // 587

    // ---- prep: weight transposes + dst-sort edges
    build_w1t<<<128, 256, 0, stream>>>(W1, w1t);
    build_wm2t<<<48, 256, 0, stream>>>(Wm2, wm2t);
    build_wm1t<<<48, 256, 0, stream>>>(Wm1, wm1t);
    part_count<<<NBLK_P, 1024, 0, stream>>>(ei1, ei2, ei3, cnt);
    scan_a<<<P, 1024, 0, stream>>>(cnt, offp, part, M2);
    scan_b<<<1, 1024, 0, stream>>>(part, P);
    scan_c<<<(M2 + 255) / 256, 256, 0, stream>>>(offp, off_b, part, M2);
    part_scatter<<<NBLK_P, 1024, 0, stream>>>(ei1, ea1, ei2, ea2, ei3, ea3,
                                              offp, brec);
    bucket_refine<<<NBK, 256, 0, stream>>>(brec, off_b, node_off, pairs);

    // ---- block 1 ----
    gemm1_mfma<<<gemm_grid, 256, 0, stream>>>(x, w1t, b1, hbuf, NN);
    ufg_gather<<<gat_grid, 256, 0, stream>>>(hbuf, node_off, pairs,
                                             f1_1, f1_2, f1_3, agg);
    gemm2_mfma<<<mfma2_grid, 256, 0, stream>>>(agg, wm2t, bm2, hbuf, NN);

    // ---- block 2 ----
    ufg_gather<<<gat_grid, 256, 0, stream>>>(hbuf, node_off, pairs,
                                             f2_1, f2_2, f2_3, agg);
    gemm3_mfma<<<mfma2_grid, 256, 0, stream>>>(agg, wm1t, bm1, out, NN);
}